// Round 5
// baseline (381.817 us; speedup 1.0000x reference)
//
#include <hip/hip_runtime.h>
#include <hip/hip_bf16.h>
#include <math.h>

typedef __bf16 bf16;
typedef __bf16 bf16x4 __attribute__((ext_vector_type(4)));
typedef __bf16 bf16x8 __attribute__((ext_vector_type(8)));
typedef float f32x4 __attribute__((ext_vector_type(4)));

#define NB 2
#define LSEQ 2048
#define NH 32
#define NKVH 8
#define HD 64
#define DMODEL 2048
#define CONVD 3072
#define NPROJ 5152
#define NPADN 5248
#define NCHUNK 16
#define CHUNK 128
#define ROWS 4096
#define EPSF 1e-5f

__device__ __forceinline__ float fsilu(float x) { return x / (1.0f + __expf(-x)); }
__device__ __forceinline__ float fsoftplus(float raw) {
  return (raw > 20.0f) ? raw : log1pf(__expf(raw));
}

__device__ __forceinline__ void gld_lds16(const void* g, void* l) {
  __builtin_amdgcn_global_load_lds(
      (const __attribute__((address_space(1))) void*)g,
      (__attribute__((address_space(3))) void*)l, 16, 0, 0);
}

// inline-asm ds_read_b128: opaque to the compiler's hazard/waitcnt insertion.
// Caller MUST pair with explicit s_waitcnt lgkmcnt + sched_barrier (rule #18).
__device__ __forceinline__ bf16x8 lds_read_b128(const bf16* p) {
  bf16x8 r;
  unsigned off = (unsigned)(unsigned long)(__attribute__((address_space(3))) bf16*)p;
  asm volatile("ds_read_b128 %0, %1" : "=v"(r) : "v"(off));
  return r;
}
// inline-asm barrier: bypasses compiler-inserted full waitcnt at S_BARRIER.
#define SBAR() asm volatile("s_barrier" ::: "memory")

// xor-chunk swizzle address maps (LDS side). Global tiles are plain row-major;
// the DMA staging permutes the per-lane SOURCE chunk so the LDS image matches.
__device__ __forceinline__ int swz64(int row, int col) {
  return row * 64 + ((((col >> 3) ^ row) & 7) << 3) + (col & 7);
}
__device__ __forceinline__ int swz128(int row, int col) {
  return row * 128 + (((col >> 3) ^ (row & 7)) << 3) + (col & 7);
}

// stage a row-major tile with 64 cols (bf16) into LDS with xor-chunk swizzle
__device__ __forceinline__ void stage64(const bf16* gsrc, bf16* lds, int tid, int nelem) {
  for (int i0 = 0; i0 < nelem; i0 += 2048) {
    int e = i0 + tid * 8;
    int row = e >> 6;
    int sc = ((tid & 7) ^ (row & 7)) << 3;
    gld_lds16((const void*)(gsrc + (row << 6) + sc), (void*)(lds + e));
  }
}
// 128-col variant
__device__ __forceinline__ void stage128(const bf16* gsrc, bf16* lds, int tid, int nelem) {
  for (int i0 = 0; i0 < nelem; i0 += 2048) {
    int e = i0 + tid * 8;
    int row = e >> 7;
    int sc = (((tid & 15) ^ (row & 7))) << 3;
    gld_lds16((const void*)(gsrc + (row << 7) + sc), (void*)(lds + e));
  }
}

// stage one 128row x 64col unit (8192 elems) with 512 threads: 2 gld_lds per thread
__device__ __forceinline__ void stage_unit(const bf16* g, bf16* l, int row0, int ldg, int tid) {
#pragma unroll
  for (int it = 0; it < 2; ++it) {
    int e = it * 4096 + tid * 8;
    int r = row0 + (e >> 6);
    int sc = ((tid & 7) ^ (r & 7)) << 3;
    gld_lds16((const void*)(g + (long)r * ldg + sc), (void*)(l + row0 * 64 + e));
  }
}

// stage one 128row x 64col tile with 256 threads: 4 gld_lds per thread
__device__ __forceinline__ void stage_tileY(const bf16* g, bf16* l, int ldg, int tid) {
#pragma unroll
  for (int it = 0; it < 4; ++it) {
    int e = it * 2048 + tid * 8;
    int r = e >> 6;
    int sc = ((tid & 7) ^ (r & 7)) << 3;
    gld_lds16((const void*)(g + (long)r * ldg + sc), (void*)(l + e));
  }
}

// barrier-free inclusive scan of 128 values (each wave redundantly): a0=scan[lane], a1=scan[64+lane]
__device__ __forceinline__ void wave_scan128(float& a0, float& a1, int lane) {
#pragma unroll
  for (int off = 1; off < 64; off <<= 1) {
    float t0 = __shfl_up(a0, off);
    float t1 = __shfl_up(a1, off);
    if (lane >= off) { a0 += t0; a1 += t1; }
  }
  a1 += __shfl(a0, 63);
}

// ---------------- fused casts: hs, W1 (zero-padded to NPADN rows), Wo ----------------
__global__ __launch_bounds__(256) void cast_all_kernel(
    const float* __restrict__ hs, const float* __restrict__ w1, const float* __restrict__ wo,
    bf16* __restrict__ hs_b, bf16* __restrict__ w1_b, bf16* __restrict__ wo_b) {
  const long n1 = (long)ROWS * DMODEL / 4;
  const long n2 = (long)NPADN * DMODEL / 4;
  const long n3 = (long)DMODEL * DMODEL / 4;
  long total = n1 + n2 + n3;
  long stride = (long)gridDim.x * blockDim.x;
  for (long i = blockIdx.x * (long)blockDim.x + threadIdx.x; i < total; i += stride) {
    if (i < n1) {
      float4 v = ((const float4*)hs)[i];
      ((bf16x4*)hs_b)[i] = bf16x4{(bf16)v.x, (bf16)v.y, (bf16)v.z, (bf16)v.w};
    } else if (i < n1 + n2) {
      long j = i - n1;
      int n = (int)((j * 4) >> 11);
      bf16x4 o = {};
      if (n < NPROJ) {
        float4 v = ((const float4*)w1)[j];
        o = bf16x4{(bf16)v.x, (bf16)v.y, (bf16)v.z, (bf16)v.w};
      }
      ((bf16x4*)w1_b)[j] = o;
    } else {
      long j = i - n1 - n2;
      float4 v = ((const float4*)wo)[j];
      ((bf16x4*)wo_b)[j] = bf16x4{(bf16)v.x, (bf16)v.y, (bf16)v.z, (bf16)v.w};
    }
  }
}

// ---------------- variant X: deep-pipelined GEMM (BM=256, BN=128, 1 block/CU) ----------------
template <typename OutT>
__global__ __launch_bounds__(512, 2) void gemm8_kernel(
    const bf16* __restrict__ A, const bf16* __restrict__ B, OutT* __restrict__ C,
    int M, int N, int K, int ntx) {
  __shared__ __align__(16) bf16 As[3 * 256 * 64];
  __shared__ __align__(16) bf16 Bs[2 * 128 * 64];
  const int tid = threadIdx.x;
  const int lane = tid & 63;
  const int wave = tid >> 6;
  const int wm = wave >> 2, wn = wave & 3;

  const int GM = 8;
  int lid = blockIdx.x;
  {  // bijective XCD-chunk swizzle: XCD x owns contiguous tile-ids
    int nwg = gridDim.x;
    int xcd = lid & 7;
    int q = nwg >> 3, r = nwg & 7;
    lid = (xcd < r ? xcd * (q + 1) : r * (q + 1) + (xcd - r) * q) + (lid >> 3);
  }
  int group = GM * ntx;
  int gid = lid / group;
  int rem = lid - gid * group;
  int bm = gid * GM + (rem % GM);
  int bn = rem / GM;

  const bf16* Ag = A + (long)bm * 256 * K;
  const bf16* Bg = B + (long)bn * 128 * K;
  const int NT = K >> 6;

  // prologue: stage tiles 0 and 1 fully (12 vmem ops)
  stage_unit(Ag, As, 0, K, tid);
  stage_unit(Ag, As, 128, K, tid);
  stage_unit(Bg, Bs, 0, K, tid);
  stage_unit(Ag + 64, As + 16384, 0, K, tid);
  stage_unit(Ag + 64, As + 16384, 128, K, tid);
  stage_unit(Bg + 64, Bs + 8192, 0, K, tid);

  const int fbA = (wm * 128 + (lane & 15)) * 64 + (((lane >> 4) ^ (lane & 7)) << 3);
  const int fbB = (wn * 32 + (lane & 15)) * 64 + (((lane >> 4) ^ (lane & 7)) << 3);

  f32x4 acc[8][2] = {};

  asm volatile("s_waitcnt vmcnt(6)" ::: "memory");   // tile 0 resident; tile 1 in flight
  SBAR();

  int ab = 0;  // A buffer index for tile t (t % 3)
  for (int t = 0; t < NT; ++t) {
    const bf16* At = As + ab * 16384;
    const bf16* Bt = Bs + (t & 1) * 8192;
    int ab2 = ab + 2; if (ab2 >= 3) ab2 -= 3;
    const bool pf = (t + 2) < NT;
    const bf16* Agn = Ag + (t + 2) * 64;
    const bf16* Bgn = Bg + (t + 2) * 64;

    // ---- phase 1: M-half 0 ----
    bf16x8 a0[4][2], bb[2][2];
#pragma unroll
    for (int mi = 0; mi < 4; ++mi)
#pragma unroll
      for (int ks = 0; ks < 2; ++ks)
        a0[mi][ks] = lds_read_b128(At + ((fbA + mi * 1024) ^ (ks << 5)));
#pragma unroll
    for (int ni = 0; ni < 2; ++ni)
#pragma unroll
      for (int ks = 0; ks < 2; ++ks)
        bb[ni][ks] = lds_read_b128(Bt + ((fbB + ni * 1024) ^ (ks << 5)));
    if (pf) stage_unit(Agn, As + ab2 * 16384, 0, K, tid);   // (t+2) A half0
    SBAR();
    asm volatile("s_waitcnt lgkmcnt(0)" ::: "memory");
    __builtin_amdgcn_sched_barrier(0);
    __builtin_amdgcn_s_setprio(1);
#pragma unroll
    for (int mi = 0; mi < 4; ++mi)
#pragma unroll
      for (int ni = 0; ni < 2; ++ni)
#pragma unroll
        for (int ks = 0; ks < 2; ++ks)
          acc[mi][ni] = __builtin_amdgcn_mfma_f32_16x16x32_bf16(a0[mi][ks], bb[ni][ks], acc[mi][ni], 0, 0, 0);
    __builtin_amdgcn_s_setprio(0);
    SBAR();

    // ---- phase 2: M-half 1 ----
    bf16x8 a1[4][2];
#pragma unroll
    for (int mi = 0; mi < 4; ++mi)
#pragma unroll
      for (int ks = 0; ks < 2; ++ks)
        a1[mi][ks] = lds_read_b128(At + ((fbA + 4096 + mi * 1024) ^ (ks << 5)));
    if (pf) {
      stage_unit(Agn, As + ab2 * 16384, 128, K, tid);       // (t+2) A half1
      stage_unit(Bgn, Bs + (t & 1) * 8192, 0, K, tid);      // (t+2) B
    }
    SBAR();
    asm volatile("s_waitcnt lgkmcnt(0)" ::: "memory");
    __builtin_amdgcn_sched_barrier(0);
    __builtin_amdgcn_s_setprio(1);
#pragma unroll
    for (int mi = 0; mi < 4; ++mi)
#pragma unroll
      for (int ni = 0; ni < 2; ++ni)
#pragma unroll
        for (int ks = 0; ks < 2; ++ks)
          acc[4 + mi][ni] = __builtin_amdgcn_mfma_f32_16x16x32_bf16(a1[mi][ks], bb[ni][ks], acc[4 + mi][ni], 0, 0, 0);
    __builtin_amdgcn_s_setprio(0);
    if (pf) asm volatile("s_waitcnt vmcnt(6)" ::: "memory");
    else    asm volatile("s_waitcnt vmcnt(0)" ::: "memory");
    SBAR();

    ab = (ab + 1 == 3) ? 0 : ab + 1;
  }

#pragma unroll
  for (int mi = 0; mi < 8; ++mi) {
    int rbase = bm * 256 + wm * 128 + mi * 16 + (lane >> 4) * 4;
#pragma unroll
    for (int ni = 0; ni < 2; ++ni) {
      int col = bn * 128 + wn * 32 + ni * 16 + (lane & 15);
#pragma unroll
      for (int r = 0; r < 4; ++r)
        C[(long)(rbase + r) * N + col] = (OutT)acc[mi][ni][r];
    }
  }
}

// ---------------- variant Y: 128x128, 256 thr, 64 KiB LDS => 2 blocks/CU ----------------
// Per K-tile: issue next-tile stage, asm ds_reads, lgkm(0), 32 MFMA, vmcnt(0), barrier.
// Wave-level overlap (2 co-resident blocks) hides the staging drain (m114 mechanism).
template <typename OutT>
__global__ __launch_bounds__(256, 2) void gemm2p_kernel(
    const bf16* __restrict__ A, const bf16* __restrict__ B, OutT* __restrict__ C,
    int M, int N, int K, int ntx) {
  __shared__ __align__(16) bf16 As[2 * 128 * 64];
  __shared__ __align__(16) bf16 Bs[2 * 128 * 64];
  const int tid = threadIdx.x;
  const int lane = tid & 63;
  const int wave = tid >> 6;
  const int wm = wave >> 1, wn = wave & 1;

  const int GM = 8;
  int lid = blockIdx.x;
  {
    int nwg = gridDim.x;
    int xcd = lid & 7;
    int q = nwg >> 3, r = nwg & 7;
    lid = (xcd < r ? xcd * (q + 1) : r * (q + 1) + (xcd - r) * q) + (lid >> 3);
  }
  int group = GM * ntx;
  int gid = lid / group;
  int rem = lid - gid * group;
  int bm = gid * GM + (rem % GM);
  int bn = rem / GM;

  const bf16* Ag = A + (long)bm * 128 * K;
  const bf16* Bg = B + (long)bn * 128 * K;
  const int NT = K >> 6;

  const int fbA = (wm * 64 + (lane & 15)) * 64 + (((lane >> 4) ^ (lane & 7)) << 3);
  const int fbB = (wn * 64 + (lane & 15)) * 64 + (((lane >> 4) ^ (lane & 7)) << 3);

  f32x4 acc[4][4] = {};

  // prologue: tile 0 into buffer 0
  stage_tileY(Ag, As, K, tid);
  stage_tileY(Bg, Bs, K, tid);
  asm volatile("s_waitcnt vmcnt(0)" ::: "memory");
  SBAR();

  for (int t = 0; t < NT; ++t) {
    const int c = t & 1;
    const bf16* At = As + c * 8192;
    const bf16* Bt = Bs + c * 8192;
    if (t + 1 < NT) {   // issue next tile into the other buffer (read at t-1, barrier-cleared)
      stage_tileY(Ag + (t + 1) * 64, As + (c ^ 1) * 8192, K, tid);
      stage_tileY(Bg + (t + 1) * 64, Bs + (c ^ 1) * 8192, K, tid);
    }
    bf16x8 af[4][2], bf_[4][2];
#pragma unroll
    for (int mi = 0; mi < 4; ++mi)
#pragma unroll
      for (int ks = 0; ks < 2; ++ks)
        af[mi][ks] = lds_read_b128(At + ((fbA + mi * 1024) ^ (ks << 5)));
#pragma unroll
    for (int ni = 0; ni < 4; ++ni)
#pragma unroll
      for (int ks = 0; ks < 2; ++ks)
        bf_[ni][ks] = lds_read_b128(Bt + ((fbB + ni * 1024) ^ (ks << 5)));
    asm volatile("s_waitcnt lgkmcnt(0)" ::: "memory");
    __builtin_amdgcn_sched_barrier(0);
    __builtin_amdgcn_s_setprio(1);
#pragma unroll
    for (int mi = 0; mi < 4; ++mi)
#pragma unroll
      for (int ni = 0; ni < 4; ++ni)
#pragma unroll
        for (int ks = 0; ks < 2; ++ks)
          acc[mi][ni] = __builtin_amdgcn_mfma_f32_16x16x32_bf16(af[mi][ks], bf_[ni][ks], acc[mi][ni], 0, 0, 0);
    __builtin_amdgcn_s_setprio(0);
    asm volatile("s_waitcnt vmcnt(0)" ::: "memory");   // next tile resident (had full MFMA window)
    SBAR();
  }

#pragma unroll
  for (int mi = 0; mi < 4; ++mi) {
    int rbase = bm * 128 + wm * 64 + mi * 16 + (lane >> 4) * 4;
#pragma unroll
    for (int ni = 0; ni < 4; ++ni) {
      int col = bn * 128 + wn * 64 + ni * 16 + (lane & 15);
#pragma unroll
      for (int r = 0; r < 4; ++r)
        C[(long)(rbase + r) * N + col] = (OutT)acc[mi][ni][r];
    }
  }
}

// ---------------- prep: conv+SiLU into MFMA-ready tiles + dt ----------------
__global__ __launch_bounds__(256) void prep_kernel(
    const bf16* __restrict__ proj, const float* __restrict__ conv_w,
    const float* __restrict__ conv_b, const float* __restrict__ dt_bias,
    const float* __restrict__ A_log,
    bf16* __restrict__ Qc, bf16* __restrict__ Kc, bf16* __restrict__ Kt,
    bf16* __restrict__ Vt, float* __restrict__ dtb, float* __restrict__ adtb) {
  __shared__ float tile[128][65];
  int blk = blockIdx.x, tid = threadIdx.x;

  if (blk < 1024) {
    int h = blk & 31, c = (blk >> 5) & 15, b = blk >> 9;
    long rowbase = (long)b * LSEQ + c * CHUNK;
    int j = tid >> 1, p0 = (tid & 1) * 32;
    const bf16* cur = proj + (rowbase + j) * NPADN;
    bool hp = (c > 0) || (j > 0);
    int chb = 1024 + h * 64;
    bf16* outb = Qc + (long)blk * 8192 + j * 64;
#pragma unroll
    for (int pp = 0; pp < 32; pp += 4) {
      int p = p0 + pp, ch = chb + p;
      bf16x4 cu = *(const bf16x4*)(cur + ch);
      bf16x4 pv = {};
      if (hp) pv = *(const bf16x4*)(cur + ch - NPADN);
      float4 wa = *(const float4*)(conv_w + 2 * ch);
      float4 wb = *(const float4*)(conv_w + 2 * ch + 4);
      float4 bb = *(const float4*)(conv_b + ch);
      bf16x4 o;
      o[0] = (bf16)fsilu((float)pv[0] * wa.x + (float)cu[0] * wa.y + bb.x);
      o[1] = (bf16)fsilu((float)pv[1] * wa.z + (float)cu[1] * wa.w + bb.y);
      o[2] = (bf16)fsilu((float)pv[2] * wb.x + (float)cu[2] * wb.y + bb.z);
      o[3] = (bf16)fsilu((float)pv[3] * wb.z + (float)cu[3] * wb.w + bb.w);
      *(bf16x4*)(outb + p) = o;
    }
  } else if (blk < 1536) {
    int r = blk - 1024;
    bool isK = r < 256;
    int rr = isK ? r : r - 256;
    int kvh = rr & 7, c = (rr >> 3) & 15, b = rr >> 7;
    long rowbase = (long)b * LSEQ + c * CHUNK;
    int chb = (isK ? 512 : 0) + kvh * 64;
    int j = tid >> 1, p0 = (tid & 1) * 32;
    const bf16* cur = proj + (rowbase + j) * NPADN;
    bool hp = (c > 0) || (j > 0);
#pragma unroll
    for (int pp = 0; pp < 32; pp += 4) {
      int p = p0 + pp, ch = chb + p;
      bf16x4 cu = *(const bf16x4*)(cur + ch);
      bf16x4 pv = {};
      if (hp) pv = *(const bf16x4*)(cur + ch - NPADN);
      float4 wa = *(const float4*)(conv_w + 2 * ch);
      float4 wb = *(const float4*)(conv_w + 2 * ch + 4);
      float4 bb = *(const float4*)(conv_b + ch);
      tile[j][p + 0] = fsilu((float)pv[0] * wa.x + (float)cu[0] * wa.y + bb.x);
      tile[j][p + 1] = fsilu((float)pv[1] * wa.z + (float)cu[1] * wa.w + bb.y);
      tile[j][p + 2] = fsilu((float)pv[2] * wb.x + (float)cu[2] * wb.y + bb.z);
      tile[j][p + 3] = fsilu((float)pv[3] * wb.z + (float)cu[3] * wb.w + bb.w);
    }
    __syncthreads();
    long tb = (long)rr * 8192;
    if (isK) {
#pragma unroll
      for (int it = 0; it < 8; ++it) {
        int e = it * 1024 + tid * 4;
        int jj = e >> 6, n = e & 63;
        bf16x4 o = {(bf16)tile[jj][n], (bf16)tile[jj][n + 1], (bf16)tile[jj][n + 2], (bf16)tile[jj][n + 3]};
        *(bf16x4*)(Kc + tb + e) = o;
      }
#pragma unroll
      for (int it = 0; it < 8; ++it) {
        int e = it * 1024 + tid * 4;
        int n = e >> 7, jj = e & 127;
        bf16x4 o = {(bf16)tile[jj][n], (bf16)tile[jj + 1][n], (bf16)tile[jj + 2][n], (bf16)tile[jj + 3][n]};
        *(bf16x4*)(Kt + tb + e) = o;
      }
    } else {
#pragma unroll
      for (int it = 0; it < 8; ++it) {
        int e = it * 1024 + tid * 4;
        int n = e >> 7, jj = e & 127;
        bf16x4 o = {(bf16)tile[jj][n], (bf16)tile[jj + 1][n], (bf16)tile[jj + 2][n], (bf16)tile[jj + 3][n]};
        *(bf16x4*)(Vt + tb + e) = o;
      }
    }
  } else {
    int r = blk - 1536;
    int c = r & 15, b = r >> 4;
    long rowbase = (long)b * LSEQ + c * CHUNK;
    int j = tid >> 1, h0 = (tid & 1) * 16;
    const bf16* dr = proj + (rowbase + j) * NPADN + (CONVD + DMODEL);
    int obase = (b * 16 + c) * 32;
#pragma unroll
    for (int u = 0; u < 16; ++u) {
      int h = h0 + u;
      float raw = (float)dr[h] + dt_bias[h];
      float dtv = fsoftplus(raw);
      dtb[(long)(obase + h) * 128 + j] = dtv;
      adtb[(long)(obase + h) * 128 + j] = -__expf(A_log[h]) * dtv;
    }
  }
}

// ---------------- SSD phase A ----------------
__global__ __launch_bounds__(256) void ssd_states_kernel(
    const bf16* __restrict__ Kt, const bf16* __restrict__ Vt,
    const float* __restrict__ dtb, const float* __restrict__ adtb,
    float* __restrict__ states, float* __restrict__ asum) {
  __shared__ __align__(16) bf16 Vs[64 * 128];
  __shared__ __align__(16) bf16 Ks[64 * 128];
  __shared__ float w[CHUNK];
  int bid = blockIdx.x;
  int h = bid & 31, c = (bid >> 5) & 15, b = bid >> 9;
  int kvh = h >> 2;
  int tid = threadIdx.x;
  int lane = tid & 63, wave = tid >> 6;
  long kvb = (long)(((b * 16 + c) * 8) + kvh) * 8192;

  stage128(Vt + kvb, Vs, tid, 8192);
  stage128(Kt + kvb, Ks, tid, 8192);

  float a0 = adtb[(long)bid * 128 + lane];
  float a1 = adtb[(long)bid * 128 + 64 + lane];
  float d0 = dtb[(long)bid * 128 + lane];
  float d1 = dtb[(long)bid * 128 + 64 + lane];
  wave_scan128(a0, a1, lane);
  float atot = __shfl(a1, 63);
  if (wave == 0) {
    w[lane] = d0 * __expf(atot - a0);
    w[64 + lane] = d1 * __expf(atot - a1);
  }
  __syncthreads();

#pragma unroll
  for (int it = 0; it < 4; ++it) {
    int e = it * 2048 + tid * 8;
    int row = e >> 7;
    int j0 = (((tid & 15) ^ (row & 7))) << 3;
    f32x4 wa = *(const f32x4*)(w + j0);
    f32x4 wb = *(const f32x4*)(w + j0 + 4);
    bf16x8 kv = *(const bf16x8*)(Ks + e);
    kv[0] = (bf16)((float)kv[0] * wa[0]); kv[1] = (bf16)((float)kv[1] * wa[1]);
    kv[2] = (bf16)((float)kv[2] * wa[2]); kv[3] = (bf16)((float)kv[3] * wa[3]);
    kv[4] = (bf16)((float)kv[4] * wb[0]); kv[5] = (bf16)((float)kv[5] * wb[1]);
    kv[6] = (bf16)((float)kv[6] * wb[2]); kv[7] = (bf16)((float)kv[7] * wb[3]);
    *(bf16x8*)(Ks + e) = kv;
  }
  __syncthreads();

  f32x4 sacc[4] = {};
#pragma unroll
  for (int ks = 0; ks < CHUNK; ks += 32) {
    bf16x8 af = *(const bf16x8*)(Vs + swz128(wave * 16 + (lane & 15), ks + (lane >> 4) * 8));
    bf16x8 bf_[4];
#pragma unroll
    for (int ni = 0; ni < 4; ++ni)
      bf_[ni] = *(const bf16x8*)(Ks + swz128(ni * 16 + (lane & 15), ks + (lane >> 4) * 8));
#pragma unroll
    for (int ni = 0; ni < 4; ++ni)
      sacc[ni] = __builtin_amdgcn_mfma_f32_16x16x32_bf16(af, bf_[ni], sacc[ni], 0, 0, 0);
  }
  float* sout = states + (long)bid * (HD * HD);
#pragma unroll
  for (int ni = 0; ni < 4; ++ni) {
    int n = ni * 16 + (lane & 15);
#pragma unroll
    for (int r = 0; r < 4; ++r) {
      int p = wave * 16 + (lane >> 4) * 4 + r;
      sout[p * HD + n] = sacc[ni][r];
    }
  }
  if (tid == 0) asum[(b * NH + h) * NCHUNK + c] = atot;
}

// ---------------- SSD phase B ----------------
__global__ __launch_bounds__(256) void ssd_scan_kernel(
    const float* __restrict__ states, const float* __restrict__ asum,
    bf16* __restrict__ sprevb) {
  int bid = blockIdx.x;
  int s = bid & 7, h = (bid >> 3) & 31, b = bid >> 8;
  int e0 = s * 512 + threadIdx.x;
  int e1 = e0 + 256;
  float S0 = 0.f, S1 = 0.f;
  const float* as = asum + (b * NH + h) * NCHUNK;
  for (int c = 0; c < NCHUNK; ++c) {
    long off = ((long)((b * NCHUNK + c) * NH + h)) * (HD * HD);
    float g = __expf(as[c]);
    sprevb[off + e0] = (bf16)S0;
    sprevb[off + e1] = (bf16)S1;
    S0 = S0 * g + states[off + e0];
    S1 = S1 * g + states[off + e1];
  }
}

// ---------------- SSD phase C ----------------
__global__ __launch_bounds__(256) void ssd_out_kernel(
    const bf16* __restrict__ Qc, const bf16* __restrict__ Kc, const bf16* __restrict__ Vt,
    const bf16* __restrict__ sprevb, const float* __restrict__ dtb,
    const float* __restrict__ adtb, const bf16* __restrict__ proj,
    const float* __restrict__ gnw, bf16* __restrict__ yg) {
  __shared__ __align__(16) bf16 Qs[128 * 64];
  __shared__ __align__(16) bf16 KVs[128 * 64];
  __shared__ __align__(16) bf16 G[128 * 128];
  __shared__ __align__(16) bf16 Sps[64 * 64];
  __shared__ float acs[CHUNK];
  __shared__ float dts[CHUNK];
  __shared__ float part[CHUNK][2];
  __shared__ float rs_l[CHUNK];

  int bid = blockIdx.x;
  int h = bid & 31, c = (bid >> 5) & 15, b = bid >> 9;
  int kvh = h >> 2;
  int tid = threadIdx.x;
  int lane = tid & 63, wave = tid >> 6;
  int wm = wave >> 1, wn = wave & 1;
  long rowbase = (long)b * LSEQ + c * CHUNK;
  long kvb = (long)(((b * 16 + c) * 8) + kvh) * 8192;

  stage64(Qc + (long)bid * 8192, Qs, tid, 8192);
  stage64(Kc + kvb, KVs, tid, 8192);
  stage64(sprevb + (long)bid * 4096, Sps, tid, 4096);

  float a0 = adtb[(long)bid * 128 + lane];
  float a1 = adtb[(long)bid * 128 + 64 + lane];
  float d0 = dtb[(long)bid * 128 + lane];
  float d1 = dtb[(long)bid * 128 + 64 + lane];
  wave_scan128(a0, a1, lane);
  if (wave == 0) {
    acs[lane] = a0; acs[64 + lane] = a1;
    dts[lane] = d0; dts[64 + lane] = d1;
  }
  __syncthreads();

  {
    f32x4 gacc[4][4] = {};
#pragma unroll
    for (int ks = 0; ks < HD; ks += 32) {
      bf16x8 af[4], bf_[4];
#pragma unroll
      for (int mi = 0; mi < 4; ++mi)
        af[mi] = *(const bf16x8*)(Qs + swz64(wm * 64 + mi * 16 + (lane & 15), ks + (lane >> 4) * 8));
#pragma unroll
      for (int ni = 0; ni < 4; ++ni)
        bf_[ni] = *(const bf16x8*)(KVs + swz64(wn * 64 + ni * 16 + (lane & 15), ks + (lane >> 4) * 8));
#pragma unroll
      for (int mi = 0; mi < 4; ++mi)
#pragma unroll
        for (int ni = 0; ni < 4; ++ni)
          gacc[mi][ni] = __builtin_amdgcn_mfma_f32_16x16x32_bf16(af[mi], bf_[ni], gacc[mi][ni], 0, 0, 0);
    }
    float aj[4], dj[4];
#pragma unroll
    for (int ni = 0; ni < 4; ++ni) {
      int j = wn * 64 + ni * 16 + (lane & 15);
      aj[ni] = acs[j];
      dj[ni] = dts[j];
    }
#pragma unroll
    for (int mi = 0; mi < 4; ++mi) {
#pragma unroll
      for (int r = 0; r < 4; ++r) {
        int i = wm * 64 + mi * 16 + (lane >> 4) * 4 + r;
        float ai = acs[i];
#pragma unroll
        for (int ni = 0; ni < 4; ++ni) {
          int j = wn * 64 + ni * 16 + (lane & 15);
          float gv = (j <= i) ? gacc[mi][ni][r] * __expf(ai - aj[ni]) * dj[ni] : 0.f;
          G[swz128(i, j)] = (bf16)gv;
        }
      }
    }
  }
  __syncthreads();

  stage128(Vt + kvb, KVs, tid, 8192);
  __syncthreads();

  f32x4 yacc[4][2] = {};
  f32x4 oacc[4][2] = {};
#pragma unroll
  for (int ks = 0; ks < CHUNK; ks += 32) {
    bf16x8 af[4], bf_[2];
#pragma unroll
    for (int mi = 0; mi < 4; ++mi)
      af[mi] = *(const bf16x8*)(G + swz128(wm * 64 + mi * 16 + (lane & 15), ks + (lane >> 4) * 8));
#pragma unroll
    for (int ni = 0; ni < 2; ++ni)
      bf_[ni] = *(const bf16x8*)(KVs + swz128(wn * 32 + ni * 16 + (lane & 15), ks + (lane >> 4) * 8));
#pragma unroll
    for (int mi = 0; mi < 4; ++mi)
#pragma unroll
      for (int ni = 0; ni < 2; ++ni)
        yacc[mi][ni] = __builtin_amdgcn_mfma_f32_16x16x32_bf16(af[mi], bf_[ni], yacc[mi][ni], 0, 0, 0);
  }
#pragma unroll
  for (int ks = 0; ks < HD; ks += 32) {
    bf16x8 af[4], bf_[2];
#pragma unroll
    for (int mi = 0; mi < 4; ++mi)
      af[mi] = *(const bf16x8*)(Qs + swz64(wm * 64 + mi * 16 + (lane & 15), ks + (lane >> 4) * 8));
#pragma unroll
    for (int ni = 0; ni < 2; ++ni)
      bf_[ni] = *(const bf16x8*)(Sps + swz64(wn * 32 + ni * 16 + (lane & 15), ks + (lane >> 4) * 8));
#pragma unroll
    for (int mi = 0; mi < 4; ++mi)
#pragma unroll
      for (int ni = 0; ni < 2; ++ni)
        oacc[mi][ni] = __builtin_amdgcn_mfma_f32_16x16x32_bf16(af[mi], bf_[ni], oacc[mi][ni], 0, 0, 0);
  }

  float yv[4][2][4];
#pragma unroll
  for (int mi = 0; mi < 4; ++mi) {
#pragma unroll
    for (int r = 0; r < 4; ++r) {
      int i = wm * 64 + mi * 16 + (lane >> 4) * 4 + r;
      float ei = __expf(acs[i]);
      float s = 0.f;
#pragma unroll
      for (int ni = 0; ni < 2; ++ni) {
        float v = yacc[mi][ni][r] + ei * oacc[mi][ni][r];
        yv[mi][ni][r] = v;
        s += v * v;
      }
      s += __shfl_xor(s, 1, 64);
      s += __shfl_xor(s, 2, 64);
      s += __shfl_xor(s, 4, 64);
      s += __shfl_xor(s, 8, 64);
      if ((lane & 15) == 0) part[i][wn] = s;
    }
  }
  __syncthreads();

  for (int i0 = 0; i0 < 8192; i0 += 2048) {
    int e = i0 + tid * 8;
    int row = e >> 6;
    int sc = ((tid & 7) ^ (row & 7)) << 3;
    gld_lds16((const void*)(proj + (rowbase + row) * NPADN + CONVD + h * 64 + sc),
              (void*)(KVs + e));
  }
  if (tid < CHUNK) rs_l[tid] = rsqrtf((part[tid][0] + part[tid][1]) * (1.0f / HD) + EPSF);
  __syncthreads();

#pragma unroll
  for (int mi = 0; mi < 4; ++mi) {
#pragma unroll
    for (int r = 0; r < 4; ++r) {
      int i = wm * 64 + mi * 16 + (lane >> 4) * 4 + r;
      long row = rowbase + i;
      float rs = rs_l[i];
#pragma unroll
      for (int ni = 0; ni < 2; ++ni) {
        int p = wn * 32 + ni * 16 + (lane & 15);
        float gval = (float)KVs[swz64(i, p)];
        float val = yv[mi][ni][r] * rs * gnw[p] * fsilu(gval);
        yg[row * (long)DMODEL + h * HD + p] = (bf16)val;
      }
    }
  }
}

// ---------------- launch ----------------
extern "C" void kernel_launch(void* const* d_in, const int* in_sizes, int n_in,
                              void* d_out, int out_size, void* d_ws, size_t ws_size,
                              hipStream_t stream) {
  const float* hs      = (const float*)d_in[0];
  const float* W1      = (const float*)d_in[1];
  const float* conv_w  = (const float*)d_in[2];
  const float* conv_b  = (const float*)d_in[3];
  const float* dt_bias = (const float*)d_in[4];
  const float* A_log   = (const float*)d_in[5];
  const float* gnw     = (const float*)d_in[6];
  const float* Wo      = (const float*)d_in[7];

  char* p = (char*)d_ws;
  bf16* hs_b   = (bf16*)p;  p += (long)ROWS * DMODEL * 2;
  bf16* w1_b   = (bf16*)p;  p += (long)NPADN * DMODEL * 2;
  bf16* wo_b   = (bf16*)p;  p += (long)DMODEL * DMODEL * 2;
  bf16* proj   = (bf16*)p;  p += (long)ROWS * NPADN * 2;
  bf16* Qc     = (bf16*)p;  p += (long)1024 * 8192 * 2;
  bf16* Kc     = (bf16*)p;  p += (long)256 * 8192 * 2;
  bf16* Kt     = (bf16*)p;  p += (long)256 * 8192 * 2;
  bf16* Vt     = (bf16*)p;  p += (long)256 * 8192 * 2;
  float* dtb   = (float*)p; p += (long)ROWS * NH * 4;
  float* adtb  = (float*)p; p += (long)ROWS * NH * 4;
  float* st    = (float*)p; p += (long)NB * NCHUNK * NH * HD * HD * 4;
  bf16* sprevb = (bf16*)p;  p += (long)NB * NCHUNK * NH * HD * HD * 2;
  float* asum  = (float*)p; p += (long)NB * NH * NCHUNK * 4;
  bf16* yg     = (bf16*)p;  p += (long)ROWS * DMODEL * 2;

  cast_all_kernel<<<4096, 256, 0, stream>>>(hs, W1, Wo, hs_b, w1_b, wo_b);

  // GEMM1 A/B split: rows 0..2047 via X (deep pipeline), rows 2048..4095 via Y (2 blocks/CU)
  gemm8_kernel<bf16><<<(2048 / 256) * (NPADN / 128), 512, 0, stream>>>(
      hs_b, w1_b, proj, 2048, NPADN, DMODEL, NPADN / 128);
  gemm2p_kernel<bf16><<<(2048 / 128) * (NPADN / 128), 256, 0, stream>>>(
      hs_b + (long)2048 * DMODEL, w1_b, proj + (long)2048 * NPADN, 2048, NPADN, DMODEL, NPADN / 128);

  prep_kernel<<<1568, 256, 0, stream>>>(proj, conv_w, conv_b, dt_bias, A_log,
                                        Qc, Kc, Kt, Vt, dtb, adtb);

  ssd_states_kernel<<<NB * NCHUNK * NH, 256, 0, stream>>>(Kt, Vt, dtb, adtb, st, asum);
  ssd_scan_kernel<<<NB * NH * 8, 256, 0, stream>>>(st, asum, sprevb);
  ssd_out_kernel<<<NB * NCHUNK * NH, 256, 0, stream>>>(
      Qc, Kc, Vt, sprevb, dtb, adtb, proj, gnw, yg);

  gemm8_kernel<float><<<(ROWS / 256) * (DMODEL / 128), 512, 0, stream>>>(
      yg, wo_b, (float*)d_out, ROWS, DMODEL, DMODEL, DMODEL / 128);
}

// Round 6
// 370.122 us; speedup vs baseline: 1.0316x; 1.0316x over previous
//
#include <hip/hip_runtime.h>
#include <hip/hip_bf16.h>
#include <math.h>

typedef __bf16 bf16;
typedef __bf16 bf16x4 __attribute__((ext_vector_type(4)));
typedef __bf16 bf16x8 __attribute__((ext_vector_type(8)));
typedef float f32x4 __attribute__((ext_vector_type(4)));

#define NB 2
#define LSEQ 2048
#define NH 32
#define NKVH 8
#define HD 64
#define DMODEL 2048
#define CONVD 3072
#define NPROJ 5152
#define NPADN 5248
#define NCHUNK 16
#define CHUNK 128
#define ROWS 4096
#define EPSF 1e-5f

__device__ __forceinline__ float fsilu(float x) { return x / (1.0f + __expf(-x)); }
__device__ __forceinline__ float fsoftplus(float raw) {
  return (raw > 20.0f) ? raw : log1pf(__expf(raw));
}

__device__ __forceinline__ void gld_lds16(const void* g, void* l) {
  __builtin_amdgcn_global_load_lds(
      (const __attribute__((address_space(1))) void*)g,
      (__attribute__((address_space(3))) void*)l, 16, 0, 0);
}

// inline-asm ds_read_b128: opaque to the compiler's hazard/waitcnt insertion.
// Caller MUST pair with explicit s_waitcnt lgkmcnt + sched_barrier (rule #18).
__device__ __forceinline__ bf16x8 lds_read_b128(const bf16* p) {
  bf16x8 r;
  unsigned off = (unsigned)(unsigned long)(__attribute__((address_space(3))) bf16*)p;
  asm volatile("ds_read_b128 %0, %1" : "=v"(r) : "v"(off));
  return r;
}
// inline-asm barrier: bypasses compiler-inserted full waitcnt at S_BARRIER.
#define SBAR() asm volatile("s_barrier" ::: "memory")

// xor-chunk swizzle address maps (LDS side). Global tiles are plain row-major;
// the DMA staging permutes the per-lane SOURCE chunk so the LDS image matches.
__device__ __forceinline__ int swz64(int row, int col) {
  return row * 64 + ((((col >> 3) ^ row) & 7) << 3) + (col & 7);
}
__device__ __forceinline__ int swz128(int row, int col) {
  return row * 128 + (((col >> 3) ^ (row & 7)) << 3) + (col & 7);
}

// stage a row-major tile with 64 cols (bf16) into LDS with xor-chunk swizzle
__device__ __forceinline__ void stage64(const bf16* gsrc, bf16* lds, int tid, int nelem) {
  for (int i0 = 0; i0 < nelem; i0 += 2048) {
    int e = i0 + tid * 8;
    int row = e >> 6;
    int sc = ((tid & 7) ^ (row & 7)) << 3;
    gld_lds16((const void*)(gsrc + (row << 6) + sc), (void*)(lds + e));
  }
}
// 128-col variant
__device__ __forceinline__ void stage128(const bf16* gsrc, bf16* lds, int tid, int nelem) {
  for (int i0 = 0; i0 < nelem; i0 += 2048) {
    int e = i0 + tid * 8;
    int row = e >> 7;
    int sc = (((tid & 15) ^ (row & 7))) << 3;
    gld_lds16((const void*)(gsrc + (row << 7) + sc), (void*)(lds + e));
  }
}

// stage one 128row x 64col unit (8192 elems) with 512 threads: 2 gld_lds per thread
__device__ __forceinline__ void stage_unit(const bf16* g, bf16* l, int row0, int ldg, int tid) {
#pragma unroll
  for (int it = 0; it < 2; ++it) {
    int e = it * 4096 + tid * 8;
    int r = row0 + (e >> 6);
    int sc = ((tid & 7) ^ (r & 7)) << 3;
    gld_lds16((const void*)(g + (long)r * ldg + sc), (void*)(l + row0 * 64 + e));
  }
}

// stage one 128row x 64col tile with 256 threads: 4 gld_lds per thread
__device__ __forceinline__ void stage_tileY(const bf16* g, bf16* l, int ldg, int tid) {
#pragma unroll
  for (int it = 0; it < 4; ++it) {
    int e = it * 2048 + tid * 8;
    int r = e >> 6;
    int sc = ((tid & 7) ^ (r & 7)) << 3;
    gld_lds16((const void*)(g + (long)r * ldg + sc), (void*)(l + e));
  }
}

// barrier-free inclusive scan of 128 values (each wave redundantly): a0=scan[lane], a1=scan[64+lane]
__device__ __forceinline__ void wave_scan128(float& a0, float& a1, int lane) {
#pragma unroll
  for (int off = 1; off < 64; off <<= 1) {
    float t0 = __shfl_up(a0, off);
    float t1 = __shfl_up(a1, off);
    if (lane >= off) { a0 += t0; a1 += t1; }
  }
  a1 += __shfl(a0, 63);
}

// ---------------- fused casts: hs, W1 (zero-padded to NPADN rows), Wo ----------------
__global__ __launch_bounds__(256) void cast_all_kernel(
    const float* __restrict__ hs, const float* __restrict__ w1, const float* __restrict__ wo,
    bf16* __restrict__ hs_b, bf16* __restrict__ w1_b, bf16* __restrict__ wo_b) {
  const long n1 = (long)ROWS * DMODEL / 4;
  const long n2 = (long)NPADN * DMODEL / 4;
  const long n3 = (long)DMODEL * DMODEL / 4;
  long total = n1 + n2 + n3;
  long stride = (long)gridDim.x * blockDim.x;
  for (long i = blockIdx.x * (long)blockDim.x + threadIdx.x; i < total; i += stride) {
    if (i < n1) {
      float4 v = ((const float4*)hs)[i];
      ((bf16x4*)hs_b)[i] = bf16x4{(bf16)v.x, (bf16)v.y, (bf16)v.z, (bf16)v.w};
    } else if (i < n1 + n2) {
      long j = i - n1;
      int n = (int)((j * 4) >> 11);
      bf16x4 o = {};
      if (n < NPROJ) {
        float4 v = ((const float4*)w1)[j];
        o = bf16x4{(bf16)v.x, (bf16)v.y, (bf16)v.z, (bf16)v.w};
      }
      ((bf16x4*)w1_b)[j] = o;
    } else {
      long j = i - n1 - n2;
      float4 v = ((const float4*)wo)[j];
      ((bf16x4*)wo_b)[j] = bf16x4{(bf16)v.x, (bf16)v.y, (bf16)v.z, (bf16)v.w};
    }
  }
}

// ---------------- variant X: deep-pipelined GEMM (BM=256, BN=128, 1 block/CU) ----------------
// Best on A-class toolchains (compiles to 168 VGPR, MfmaUtil ~50%).
template <typename OutT>
__global__ __launch_bounds__(512, 2) void gemm8_kernel(
    const bf16* __restrict__ A, const bf16* __restrict__ B, OutT* __restrict__ C,
    int M, int N, int K, int ntx) {
  __shared__ __align__(16) bf16 As[3 * 256 * 64];
  __shared__ __align__(16) bf16 Bs[2 * 128 * 64];
  const int tid = threadIdx.x;
  const int lane = tid & 63;
  const int wave = tid >> 6;
  const int wm = wave >> 2, wn = wave & 3;

  const int GM = 8;
  int lid = blockIdx.x;
  {  // bijective XCD-chunk swizzle: XCD x owns contiguous tile-ids
    int nwg = gridDim.x;
    int xcd = lid & 7;
    int q = nwg >> 3, r = nwg & 7;
    lid = (xcd < r ? xcd * (q + 1) : r * (q + 1) + (xcd - r) * q) + (lid >> 3);
  }
  int group = GM * ntx;
  int gid = lid / group;
  int rem = lid - gid * group;
  int bm = gid * GM + (rem % GM);
  int bn = rem / GM;

  const bf16* Ag = A + (long)bm * 256 * K;
  const bf16* Bg = B + (long)bn * 128 * K;
  const int NT = K >> 6;

  // prologue: stage tiles 0 and 1 fully (12 vmem ops)
  stage_unit(Ag, As, 0, K, tid);
  stage_unit(Ag, As, 128, K, tid);
  stage_unit(Bg, Bs, 0, K, tid);
  stage_unit(Ag + 64, As + 16384, 0, K, tid);
  stage_unit(Ag + 64, As + 16384, 128, K, tid);
  stage_unit(Bg + 64, Bs + 8192, 0, K, tid);

  const int fbA = (wm * 128 + (lane & 15)) * 64 + (((lane >> 4) ^ (lane & 7)) << 3);
  const int fbB = (wn * 32 + (lane & 15)) * 64 + (((lane >> 4) ^ (lane & 7)) << 3);

  f32x4 acc[8][2] = {};

  asm volatile("s_waitcnt vmcnt(6)" ::: "memory");   // tile 0 resident; tile 1 in flight
  SBAR();

  int ab = 0;  // A buffer index for tile t (t % 3)
  for (int t = 0; t < NT; ++t) {
    const bf16* At = As + ab * 16384;
    const bf16* Bt = Bs + (t & 1) * 8192;
    int ab2 = ab + 2; if (ab2 >= 3) ab2 -= 3;
    const bool pf = (t + 2) < NT;
    const bf16* Agn = Ag + (t + 2) * 64;
    const bf16* Bgn = Bg + (t + 2) * 64;

    // ---- phase 1: M-half 0 ----
    bf16x8 a0[4][2], bb[2][2];
#pragma unroll
    for (int mi = 0; mi < 4; ++mi)
#pragma unroll
      for (int ks = 0; ks < 2; ++ks)
        a0[mi][ks] = lds_read_b128(At + ((fbA + mi * 1024) ^ (ks << 5)));
#pragma unroll
    for (int ni = 0; ni < 2; ++ni)
#pragma unroll
      for (int ks = 0; ks < 2; ++ks)
        bb[ni][ks] = lds_read_b128(Bt + ((fbB + ni * 1024) ^ (ks << 5)));
    if (pf) stage_unit(Agn, As + ab2 * 16384, 0, K, tid);   // (t+2) A half0
    SBAR();
    asm volatile("s_waitcnt lgkmcnt(0)" ::: "memory");
    __builtin_amdgcn_sched_barrier(0);
    __builtin_amdgcn_s_setprio(1);
#pragma unroll
    for (int mi = 0; mi < 4; ++mi)
#pragma unroll
      for (int ni = 0; ni < 2; ++ni)
#pragma unroll
        for (int ks = 0; ks < 2; ++ks)
          acc[mi][ni] = __builtin_amdgcn_mfma_f32_16x16x32_bf16(a0[mi][ks], bb[ni][ks], acc[mi][ni], 0, 0, 0);
    __builtin_amdgcn_s_setprio(0);
    SBAR();

    // ---- phase 2: M-half 1 ----
    bf16x8 a1[4][2];
#pragma unroll
    for (int mi = 0; mi < 4; ++mi)
#pragma unroll
      for (int ks = 0; ks < 2; ++ks)
        a1[mi][ks] = lds_read_b128(At + ((fbA + 4096 + mi * 1024) ^ (ks << 5)));
    if (pf) {
      stage_unit(Agn, As + ab2 * 16384, 128, K, tid);       // (t+2) A half1
      stage_unit(Bgn, Bs + (t & 1) * 8192, 0, K, tid);      // (t+2) B
    }
    SBAR();
    asm volatile("s_waitcnt lgkmcnt(0)" ::: "memory");
    __builtin_amdgcn_sched_barrier(0);
    __builtin_amdgcn_s_setprio(1);
#pragma unroll
    for (int mi = 0; mi < 4; ++mi)
#pragma unroll
      for (int ni = 0; ni < 2; ++ni)
#pragma unroll
        for (int ks = 0; ks < 2; ++ks)
          acc[4 + mi][ni] = __builtin_amdgcn_mfma_f32_16x16x32_bf16(a1[mi][ks], bb[ni][ks], acc[4 + mi][ni], 0, 0, 0);
    __builtin_amdgcn_s_setprio(0);
    if (pf) asm volatile("s_waitcnt vmcnt(6)" ::: "memory");
    else    asm volatile("s_waitcnt vmcnt(0)" ::: "memory");
    SBAR();

    ab = (ab + 1 == 3) ? 0 : ab + 1;
  }

#pragma unroll
  for (int mi = 0; mi < 8; ++mi) {
    int rbase = bm * 256 + wm * 128 + mi * 16 + (lane >> 4) * 4;
#pragma unroll
    for (int ni = 0; ni < 2; ++ni) {
      int col = bn * 128 + wn * 32 + ni * 16 + (lane & 15);
#pragma unroll
      for (int r = 0; r < 4; ++r)
        C[(long)(rbase + r) * N + col] = (OutT)acc[mi][ni][r];
    }
  }
}

// ---------------- variant Y: 128x128, 256 thr, 64 KiB LDS => 2 blocks/CU ----------------
// Per K-tile: issue next-tile stage, asm ds_reads, lgkm(0), 32 MFMA, vmcnt(0), barrier.
// Wave-level overlap (2 co-resident blocks) hides the staging drain (m114 mechanism).
// Round-5 A/B: 1.47x faster than X per-work on B-class toolchains (88-VGPR codegen).
template <typename OutT>
__global__ __launch_bounds__(256, 2) void gemm2p_kernel(
    const bf16* __restrict__ A, const bf16* __restrict__ B, OutT* __restrict__ C,
    int M, int N, int K, int ntx) {
  __shared__ __align__(16) bf16 As[2 * 128 * 64];
  __shared__ __align__(16) bf16 Bs[2 * 128 * 64];
  const int tid = threadIdx.x;
  const int lane = tid & 63;
  const int wave = tid >> 6;
  const int wm = wave >> 1, wn = wave & 1;

  const int GM = 8;
  int lid = blockIdx.x;
  {
    int nwg = gridDim.x;
    int xcd = lid & 7;
    int q = nwg >> 3, r = nwg & 7;
    lid = (xcd < r ? xcd * (q + 1) : r * (q + 1) + (xcd - r) * q) + (lid >> 3);
  }
  int group = GM * ntx;
  int gid = lid / group;
  int rem = lid - gid * group;
  int bm = gid * GM + (rem % GM);
  int bn = rem / GM;

  const bf16* Ag = A + (long)bm * 128 * K;
  const bf16* Bg = B + (long)bn * 128 * K;
  const int NT = K >> 6;

  const int fbA = (wm * 64 + (lane & 15)) * 64 + (((lane >> 4) ^ (lane & 7)) << 3);
  const int fbB = (wn * 64 + (lane & 15)) * 64 + (((lane >> 4) ^ (lane & 7)) << 3);

  f32x4 acc[4][4] = {};

  // prologue: tile 0 into buffer 0
  stage_tileY(Ag, As, K, tid);
  stage_tileY(Bg, Bs, K, tid);
  asm volatile("s_waitcnt vmcnt(0)" ::: "memory");
  SBAR();

  for (int t = 0; t < NT; ++t) {
    const int c = t & 1;
    const bf16* At = As + c * 8192;
    const bf16* Bt = Bs + c * 8192;
    if (t + 1 < NT) {   // issue next tile into the other buffer (read at t-1, barrier-cleared)
      stage_tileY(Ag + (t + 1) * 64, As + (c ^ 1) * 8192, K, tid);
      stage_tileY(Bg + (t + 1) * 64, Bs + (c ^ 1) * 8192, K, tid);
    }
    bf16x8 af[4][2], bf_[4][2];
#pragma unroll
    for (int mi = 0; mi < 4; ++mi)
#pragma unroll
      for (int ks = 0; ks < 2; ++ks)
        af[mi][ks] = lds_read_b128(At + ((fbA + mi * 1024) ^ (ks << 5)));
#pragma unroll
    for (int ni = 0; ni < 4; ++ni)
#pragma unroll
      for (int ks = 0; ks < 2; ++ks)
        bf_[ni][ks] = lds_read_b128(Bt + ((fbB + ni * 1024) ^ (ks << 5)));
    asm volatile("s_waitcnt lgkmcnt(0)" ::: "memory");
    __builtin_amdgcn_sched_barrier(0);
    __builtin_amdgcn_s_setprio(1);
#pragma unroll
    for (int mi = 0; mi < 4; ++mi)
#pragma unroll
      for (int ni = 0; ni < 4; ++ni)
#pragma unroll
        for (int ks = 0; ks < 2; ++ks)
          acc[mi][ni] = __builtin_amdgcn_mfma_f32_16x16x32_bf16(af[mi][ks], bf_[ni][ks], acc[mi][ni], 0, 0, 0);
    __builtin_amdgcn_s_setprio(0);
    asm volatile("s_waitcnt vmcnt(0)" ::: "memory");   // next tile resident (had full MFMA window)
    SBAR();
  }

#pragma unroll
  for (int mi = 0; mi < 4; ++mi) {
    int rbase = bm * 128 + wm * 64 + mi * 16 + (lane >> 4) * 4;
#pragma unroll
    for (int ni = 0; ni < 4; ++ni) {
      int col = bn * 128 + wn * 64 + ni * 16 + (lane & 15);
#pragma unroll
      for (int r = 0; r < 4; ++r)
        C[(long)(rbase + r) * N + col] = (OutT)acc[mi][ni][r];
    }
  }
}

// ---------------- prep: conv+SiLU into MFMA-ready tiles + dt ----------------
__global__ __launch_bounds__(256) void prep_kernel(
    const bf16* __restrict__ proj, const float* __restrict__ conv_w,
    const float* __restrict__ conv_b, const float* __restrict__ dt_bias,
    const float* __restrict__ A_log,
    bf16* __restrict__ Qc, bf16* __restrict__ Kc, bf16* __restrict__ Kt,
    bf16* __restrict__ Vt, float* __restrict__ dtb, float* __restrict__ adtb) {
  __shared__ float tile[128][65];
  int blk = blockIdx.x, tid = threadIdx.x;

  if (blk < 1024) {
    int h = blk & 31, c = (blk >> 5) & 15, b = blk >> 9;
    long rowbase = (long)b * LSEQ + c * CHUNK;
    int j = tid >> 1, p0 = (tid & 1) * 32;
    const bf16* cur = proj + (rowbase + j) * NPADN;
    bool hp = (c > 0) || (j > 0);
    int chb = 1024 + h * 64;
    bf16* outb = Qc + (long)blk * 8192 + j * 64;
#pragma unroll
    for (int pp = 0; pp < 32; pp += 4) {
      int p = p0 + pp, ch = chb + p;
      bf16x4 cu = *(const bf16x4*)(cur + ch);
      bf16x4 pv = {};
      if (hp) pv = *(const bf16x4*)(cur + ch - NPADN);
      float4 wa = *(const float4*)(conv_w + 2 * ch);
      float4 wb = *(const float4*)(conv_w + 2 * ch + 4);
      float4 bb = *(const float4*)(conv_b + ch);
      bf16x4 o;
      o[0] = (bf16)fsilu((float)pv[0] * wa.x + (float)cu[0] * wa.y + bb.x);
      o[1] = (bf16)fsilu((float)pv[1] * wa.z + (float)cu[1] * wa.w + bb.y);
      o[2] = (bf16)fsilu((float)pv[2] * wb.x + (float)cu[2] * wb.y + bb.z);
      o[3] = (bf16)fsilu((float)pv[3] * wb.z + (float)cu[3] * wb.w + bb.w);
      *(bf16x4*)(outb + p) = o;
    }
  } else if (blk < 1536) {
    int r = blk - 1024;
    bool isK = r < 256;
    int rr = isK ? r : r - 256;
    int kvh = rr & 7, c = (rr >> 3) & 15, b = rr >> 7;
    long rowbase = (long)b * LSEQ + c * CHUNK;
    int chb = (isK ? 512 : 0) + kvh * 64;
    int j = tid >> 1, p0 = (tid & 1) * 32;
    const bf16* cur = proj + (rowbase + j) * NPADN;
    bool hp = (c > 0) || (j > 0);
#pragma unroll
    for (int pp = 0; pp < 32; pp += 4) {
      int p = p0 + pp, ch = chb + p;
      bf16x4 cu = *(const bf16x4*)(cur + ch);
      bf16x4 pv = {};
      if (hp) pv = *(const bf16x4*)(cur + ch - NPADN);
      float4 wa = *(const float4*)(conv_w + 2 * ch);
      float4 wb = *(const float4*)(conv_w + 2 * ch + 4);
      float4 bb = *(const float4*)(conv_b + ch);
      tile[j][p + 0] = fsilu((float)pv[0] * wa.x + (float)cu[0] * wa.y + bb.x);
      tile[j][p + 1] = fsilu((float)pv[1] * wa.z + (float)cu[1] * wa.w + bb.y);
      tile[j][p + 2] = fsilu((float)pv[2] * wb.x + (float)cu[2] * wb.y + bb.z);
      tile[j][p + 3] = fsilu((float)pv[3] * wb.z + (float)cu[3] * wb.w + bb.w);
    }
    __syncthreads();
    long tb = (long)rr * 8192;
    if (isK) {
#pragma unroll
      for (int it = 0; it < 8; ++it) {
        int e = it * 1024 + tid * 4;
        int jj = e >> 6, n = e & 63;
        bf16x4 o = {(bf16)tile[jj][n], (bf16)tile[jj][n + 1], (bf16)tile[jj][n + 2], (bf16)tile[jj][n + 3]};
        *(bf16x4*)(Kc + tb + e) = o;
      }
#pragma unroll
      for (int it = 0; it < 8; ++it) {
        int e = it * 1024 + tid * 4;
        int n = e >> 7, jj = e & 127;
        bf16x4 o = {(bf16)tile[jj][n], (bf16)tile[jj + 1][n], (bf16)tile[jj + 2][n], (bf16)tile[jj + 3][n]};
        *(bf16x4*)(Kt + tb + e) = o;
      }
    } else {
#pragma unroll
      for (int it = 0; it < 8; ++it) {
        int e = it * 1024 + tid * 4;
        int n = e >> 7, jj = e & 127;
        bf16x4 o = {(bf16)tile[jj][n], (bf16)tile[jj + 1][n], (bf16)tile[jj + 2][n], (bf16)tile[jj + 3][n]};
        *(bf16x4*)(Vt + tb + e) = o;
      }
    }
  } else {
    int r = blk - 1536;
    int c = r & 15, b = r >> 4;
    long rowbase = (long)b * LSEQ + c * CHUNK;
    int j = tid >> 1, h0 = (tid & 1) * 16;
    const bf16* dr = proj + (rowbase + j) * NPADN + (CONVD + DMODEL);
    int obase = (b * 16 + c) * 32;
#pragma unroll
    for (int u = 0; u < 16; ++u) {
      int h = h0 + u;
      float raw = (float)dr[h] + dt_bias[h];
      float dtv = fsoftplus(raw);
      dtb[(long)(obase + h) * 128 + j] = dtv;
      adtb[(long)(obase + h) * 128 + j] = -__expf(A_log[h]) * dtv;
    }
  }
}

// ---------------- SSD phase A ----------------
__global__ __launch_bounds__(256) void ssd_states_kernel(
    const bf16* __restrict__ Kt, const bf16* __restrict__ Vt,
    const float* __restrict__ dtb, const float* __restrict__ adtb,
    float* __restrict__ states, float* __restrict__ asum) {
  __shared__ __align__(16) bf16 Vs[64 * 128];
  __shared__ __align__(16) bf16 Ks[64 * 128];
  __shared__ float w[CHUNK];
  int bid = blockIdx.x;
  int h = bid & 31, c = (bid >> 5) & 15, b = bid >> 9;
  int kvh = h >> 2;
  int tid = threadIdx.x;
  int lane = tid & 63, wave = tid >> 6;
  long kvb = (long)(((b * 16 + c) * 8) + kvh) * 8192;

  stage128(Vt + kvb, Vs, tid, 8192);
  stage128(Kt + kvb, Ks, tid, 8192);

  float a0 = adtb[(long)bid * 128 + lane];
  float a1 = adtb[(long)bid * 128 + 64 + lane];
  float d0 = dtb[(long)bid * 128 + lane];
  float d1 = dtb[(long)bid * 128 + 64 + lane];
  wave_scan128(a0, a1, lane);
  float atot = __shfl(a1, 63);
  if (wave == 0) {
    w[lane] = d0 * __expf(atot - a0);
    w[64 + lane] = d1 * __expf(atot - a1);
  }
  __syncthreads();

#pragma unroll
  for (int it = 0; it < 4; ++it) {
    int e = it * 2048 + tid * 8;
    int row = e >> 7;
    int j0 = (((tid & 15) ^ (row & 7))) << 3;
    f32x4 wa = *(const f32x4*)(w + j0);
    f32x4 wb = *(const f32x4*)(w + j0 + 4);
    bf16x8 kv = *(const bf16x8*)(Ks + e);
    kv[0] = (bf16)((float)kv[0] * wa[0]); kv[1] = (bf16)((float)kv[1] * wa[1]);
    kv[2] = (bf16)((float)kv[2] * wa[2]); kv[3] = (bf16)((float)kv[3] * wa[3]);
    kv[4] = (bf16)((float)kv[4] * wb[0]); kv[5] = (bf16)((float)kv[5] * wb[1]);
    kv[6] = (bf16)((float)kv[6] * wb[2]); kv[7] = (bf16)((float)kv[7] * wb[3]);
    *(bf16x8*)(Ks + e) = kv;
  }
  __syncthreads();

  f32x4 sacc[4] = {};
#pragma unroll
  for (int ks = 0; ks < CHUNK; ks += 32) {
    bf16x8 af = *(const bf16x8*)(Vs + swz128(wave * 16 + (lane & 15), ks + (lane >> 4) * 8));
    bf16x8 bf_[4];
#pragma unroll
    for (int ni = 0; ni < 4; ++ni)
      bf_[ni] = *(const bf16x8*)(Ks + swz128(ni * 16 + (lane & 15), ks + (lane >> 4) * 8));
#pragma unroll
    for (int ni = 0; ni < 4; ++ni)
      sacc[ni] = __builtin_amdgcn_mfma_f32_16x16x32_bf16(af, bf_[ni], sacc[ni], 0, 0, 0);
  }
  float* sout = states + (long)bid * (HD * HD);
#pragma unroll
  for (int ni = 0; ni < 4; ++ni) {
    int n = ni * 16 + (lane & 15);
#pragma unroll
    for (int r = 0; r < 4; ++r) {
      int p = wave * 16 + (lane >> 4) * 4 + r;
      sout[p * HD + n] = sacc[ni][r];
    }
  }
  if (tid == 0) asum[(b * NH + h) * NCHUNK + c] = atot;
}

// ---------------- SSD phase B ----------------
__global__ __launch_bounds__(256) void ssd_scan_kernel(
    const float* __restrict__ states, const float* __restrict__ asum,
    bf16* __restrict__ sprevb) {
  int bid = blockIdx.x;
  int s = bid & 7, h = (bid >> 3) & 31, b = bid >> 8;
  int e0 = s * 512 + threadIdx.x;
  int e1 = e0 + 256;
  float S0 = 0.f, S1 = 0.f;
  const float* as = asum + (b * NH + h) * NCHUNK;
  for (int c = 0; c < NCHUNK; ++c) {
    long off = ((long)((b * NCHUNK + c) * NH + h)) * (HD * HD);
    float g = __expf(as[c]);
    sprevb[off + e0] = (bf16)S0;
    sprevb[off + e1] = (bf16)S1;
    S0 = S0 * g + states[off + e0];
    S1 = S1 * g + states[off + e1];
  }
}

// ---------------- SSD phase C ----------------
__global__ __launch_bounds__(256) void ssd_out_kernel(
    const bf16* __restrict__ Qc, const bf16* __restrict__ Kc, const bf16* __restrict__ Vt,
    const bf16* __restrict__ sprevb, const float* __restrict__ dtb,
    const float* __restrict__ adtb, const bf16* __restrict__ proj,
    const float* __restrict__ gnw, bf16* __restrict__ yg) {
  __shared__ __align__(16) bf16 Qs[128 * 64];
  __shared__ __align__(16) bf16 KVs[128 * 64];
  __shared__ __align__(16) bf16 G[128 * 128];
  __shared__ __align__(16) bf16 Sps[64 * 64];
  __shared__ float acs[CHUNK];
  __shared__ float dts[CHUNK];
  __shared__ float part[CHUNK][2];
  __shared__ float rs_l[CHUNK];

  int bid = blockIdx.x;
  int h = bid & 31, c = (bid >> 5) & 15, b = bid >> 9;
  int kvh = h >> 2;
  int tid = threadIdx.x;
  int lane = tid & 63, wave = tid >> 6;
  int wm = wave >> 1, wn = wave & 1;
  long rowbase = (long)b * LSEQ + c * CHUNK;
  long kvb = (long)(((b * 16 + c) * 8) + kvh) * 8192;

  stage64(Qc + (long)bid * 8192, Qs, tid, 8192);
  stage64(Kc + kvb, KVs, tid, 8192);
  stage64(sprevb + (long)bid * 4096, Sps, tid, 4096);

  float a0 = adtb[(long)bid * 128 + lane];
  float a1 = adtb[(long)bid * 128 + 64 + lane];
  float d0 = dtb[(long)bid * 128 + lane];
  float d1 = dtb[(long)bid * 128 + 64 + lane];
  wave_scan128(a0, a1, lane);
  if (wave == 0) {
    acs[lane] = a0; acs[64 + lane] = a1;
    dts[lane] = d0; dts[64 + lane] = d1;
  }
  __syncthreads();

  {
    f32x4 gacc[4][4] = {};
#pragma unroll
    for (int ks = 0; ks < HD; ks += 32) {
      bf16x8 af[4], bf_[4];
#pragma unroll
      for (int mi = 0; mi < 4; ++mi)
        af[mi] = *(const bf16x8*)(Qs + swz64(wm * 64 + mi * 16 + (lane & 15), ks + (lane >> 4) * 8));
#pragma unroll
      for (int ni = 0; ni < 4; ++ni)
        bf_[ni] = *(const bf16x8*)(KVs + swz64(wn * 64 + ni * 16 + (lane & 15), ks + (lane >> 4) * 8));
#pragma unroll
      for (int mi = 0; mi < 4; ++mi)
#pragma unroll
        for (int ni = 0; ni < 4; ++ni)
          gacc[mi][ni] = __builtin_amdgcn_mfma_f32_16x16x32_bf16(af[mi], bf_[ni], gacc[mi][ni], 0, 0, 0);
    }
    float aj[4], dj[4];
#pragma unroll
    for (int ni = 0; ni < 4; ++ni) {
      int j = wn * 64 + ni * 16 + (lane & 15);
      aj[ni] = acs[j];
      dj[ni] = dts[j];
    }
#pragma unroll
    for (int mi = 0; mi < 4; ++mi) {
#pragma unroll
      for (int r = 0; r < 4; ++r) {
        int i = wm * 64 + mi * 16 + (lane >> 4) * 4 + r;
        float ai = acs[i];
#pragma unroll
        for (int ni = 0; ni < 4; ++ni) {
          int j = wn * 64 + ni * 16 + (lane & 15);
          float gv = (j <= i) ? gacc[mi][ni][r] * __expf(ai - aj[ni]) * dj[ni] : 0.f;
          G[swz128(i, j)] = (bf16)gv;
        }
      }
    }
  }
  __syncthreads();

  stage128(Vt + kvb, KVs, tid, 8192);
  __syncthreads();

  f32x4 yacc[4][2] = {};
  f32x4 oacc[4][2] = {};
#pragma unroll
  for (int ks = 0; ks < CHUNK; ks += 32) {
    bf16x8 af[4], bf_[2];
#pragma unroll
    for (int mi = 0; mi < 4; ++mi)
      af[mi] = *(const bf16x8*)(G + swz128(wm * 64 + mi * 16 + (lane & 15), ks + (lane >> 4) * 8));
#pragma unroll
    for (int ni = 0; ni < 2; ++ni)
      bf_[ni] = *(const bf16x8*)(KVs + swz128(wn * 32 + ni * 16 + (lane & 15), ks + (lane >> 4) * 8));
#pragma unroll
    for (int mi = 0; mi < 4; ++mi)
#pragma unroll
      for (int ni = 0; ni < 2; ++ni)
        yacc[mi][ni] = __builtin_amdgcn_mfma_f32_16x16x32_bf16(af[mi], bf_[ni], yacc[mi][ni], 0, 0, 0);
  }
#pragma unroll
  for (int ks = 0; ks < HD; ks += 32) {
    bf16x8 af[4], bf_[2];
#pragma unroll
    for (int mi = 0; mi < 4; ++mi)
      af[mi] = *(const bf16x8*)(Qs + swz64(wm * 64 + mi * 16 + (lane & 15), ks + (lane >> 4) * 8));
#pragma unroll
    for (int ni = 0; ni < 2; ++ni)
      bf_[ni] = *(const bf16x8*)(Sps + swz64(wn * 32 + ni * 16 + (lane & 15), ks + (lane >> 4) * 8));
#pragma unroll
    for (int mi = 0; mi < 4; ++mi)
#pragma unroll
      for (int ni = 0; ni < 2; ++ni)
        oacc[mi][ni] = __builtin_amdgcn_mfma_f32_16x16x32_bf16(af[mi], bf_[ni], oacc[mi][ni], 0, 0, 0);
  }

  float yv[4][2][4];
#pragma unroll
  for (int mi = 0; mi < 4; ++mi) {
#pragma unroll
    for (int r = 0; r < 4; ++r) {
      int i = wm * 64 + mi * 16 + (lane >> 4) * 4 + r;
      float ei = __expf(acs[i]);
      float s = 0.f;
#pragma unroll
      for (int ni = 0; ni < 2; ++ni) {
        float v = yacc[mi][ni][r] + ei * oacc[mi][ni][r];
        yv[mi][ni][r] = v;
        s += v * v;
      }
      s += __shfl_xor(s, 1, 64);
      s += __shfl_xor(s, 2, 64);
      s += __shfl_xor(s, 4, 64);
      s += __shfl_xor(s, 8, 64);
      if ((lane & 15) == 0) part[i][wn] = s;
    }
  }
  __syncthreads();

  for (int i0 = 0; i0 < 8192; i0 += 2048) {
    int e = i0 + tid * 8;
    int row = e >> 6;
    int sc = ((tid & 7) ^ (row & 7)) << 3;
    gld_lds16((const void*)(proj + (rowbase + row) * NPADN + CONVD + h * 64 + sc),
              (void*)(KVs + e));
  }
  if (tid < CHUNK) rs_l[tid] = rsqrtf((part[tid][0] + part[tid][1]) * (1.0f / HD) + EPSF);
  __syncthreads();

#pragma unroll
  for (int mi = 0; mi < 4; ++mi) {
#pragma unroll
    for (int r = 0; r < 4; ++r) {
      int i = wm * 64 + mi * 16 + (lane >> 4) * 4 + r;
      long row = rowbase + i;
      float rs = rs_l[i];
#pragma unroll
      for (int ni = 0; ni < 2; ++ni) {
        int p = wn * 32 + ni * 16 + (lane & 15);
        float gval = (float)KVs[swz64(i, p)];
        float val = yv[mi][ni][r] * rs * gnw[p] * fsilu(gval);
        yg[row * (long)DMODEL + h * HD + p] = (bf16)val;
      }
    }
  }
}

// ---------------- launch ----------------
extern "C" void kernel_launch(void* const* d_in, const int* in_sizes, int n_in,
                              void* d_out, int out_size, void* d_ws, size_t ws_size,
                              hipStream_t stream) {
  const float* hs      = (const float*)d_in[0];
  const float* W1      = (const float*)d_in[1];
  const float* conv_w  = (const float*)d_in[2];
  const float* conv_b  = (const float*)d_in[3];
  const float* dt_bias = (const float*)d_in[4];
  const float* A_log   = (const float*)d_in[5];
  const float* gnw     = (const float*)d_in[6];
  const float* Wo      = (const float*)d_in[7];

  char* p = (char*)d_ws;
  bf16* hs_b   = (bf16*)p;  p += (long)ROWS * DMODEL * 2;
  bf16* w1_b   = (bf16*)p;  p += (long)NPADN * DMODEL * 2;
  bf16* wo_b   = (bf16*)p;  p += (long)DMODEL * DMODEL * 2;
  bf16* proj   = (bf16*)p;  p += (long)ROWS * NPADN * 2;
  bf16* Qc     = (bf16*)p;  p += (long)1024 * 8192 * 2;
  bf16* Kc     = (bf16*)p;  p += (long)256 * 8192 * 2;
  bf16* Kt     = (bf16*)p;  p += (long)256 * 8192 * 2;
  bf16* Vt     = (bf16*)p;  p += (long)256 * 8192 * 2;
  float* dtb   = (float*)p; p += (long)ROWS * NH * 4;
  float* adtb  = (float*)p; p += (long)ROWS * NH * 4;
  float* st    = (float*)p; p += (long)NB * NCHUNK * NH * HD * HD * 4;
  bf16* sprevb = (bf16*)p;  p += (long)NB * NCHUNK * NH * HD * HD * 2;
  float* asum  = (float*)p; p += (long)NB * NH * NCHUNK * 4;
  bf16* yg     = (bf16*)p;  p += (long)ROWS * DMODEL * 2;

  // Toolchain-class dispatch (host-side query; graph-capture-safe):
  // A-class hipcc compiles gemm8 to ~168 VGPR (deep pipeline fills, X wins);
  // B-class compiles to ~88 VGPR (AGPR-copy codegen, pipeline stalls -> Y wins).
  static int use_x = -1;
  if (use_x < 0) {
    hipFuncAttributes attr{};
    use_x = 0;
    if (hipFuncGetAttributes(&attr,
          reinterpret_cast<const void*>(&gemm8_kernel<bf16>)) == hipSuccess &&
        attr.numRegs >= 128)
      use_x = 1;
  }

  cast_all_kernel<<<4096, 256, 0, stream>>>(hs, W1, Wo, hs_b, w1_b, wo_b);

  if (use_x) {
    gemm8_kernel<bf16><<<(ROWS / 256) * (NPADN / 128), 512, 0, stream>>>(
        hs_b, w1_b, proj, ROWS, NPADN, DMODEL, NPADN / 128);
  } else {
    gemm2p_kernel<bf16><<<(ROWS / 128) * (NPADN / 128), 256, 0, stream>>>(
        hs_b, w1_b, proj, ROWS, NPADN, DMODEL, NPADN / 128);
  }

  prep_kernel<<<1568, 256, 0, stream>>>(proj, conv_w, conv_b, dt_bias, A_log,
                                        Qc, Kc, Kt, Vt, dtb, adtb);

  ssd_states_kernel<<<NB * NCHUNK * NH, 256, 0, stream>>>(Kt, Vt, dtb, adtb, st, asum);
  ssd_scan_kernel<<<NB * NH * 8, 256, 0, stream>>>(st, asum, sprevb);
  ssd_out_kernel<<<NB * NCHUNK * NH, 256, 0, stream>>>(
      Qc, Kc, Vt, sprevb, dtb, adtb, proj, gnw, yg);

  if (use_x) {
    gemm8_kernel<float><<<(ROWS / 256) * (DMODEL / 128), 512, 0, stream>>>(
        yg, wo_b, (float*)d_out, ROWS, DMODEL, DMODEL, DMODEL / 128);
  } else {
    gemm2p_kernel<float><<<(ROWS / 128) * (DMODEL / 128), 256, 0, stream>>>(
        yg, wo_b, (float*)d_out, ROWS, DMODEL, DMODEL, DMODEL / 128);
  }
}

// Round 7
// 353.201 us; speedup vs baseline: 1.0810x; 1.0479x over previous
//
#include <hip/hip_runtime.h>
#include <hip/hip_bf16.h>
#include <math.h>

typedef __bf16 bf16;
typedef __bf16 bf16x4 __attribute__((ext_vector_type(4)));
typedef __bf16 bf16x8 __attribute__((ext_vector_type(8)));
typedef float f32x4 __attribute__((ext_vector_type(4)));

#define NB 2
#define LSEQ 2048
#define NH 32
#define NKVH 8
#define HD 64
#define DMODEL 2048
#define CONVD 3072
#define NPROJ 5152
#define NPADN 5248
#define NCHUNK 16
#define CHUNK 128
#define ROWS 4096
#define EPSF 1e-5f

__device__ __forceinline__ float fsilu(float x) { return x / (1.0f + __expf(-x)); }
__device__ __forceinline__ float fsoftplus(float raw) {
  return (raw > 20.0f) ? raw : log1pf(__expf(raw));
}

__device__ __forceinline__ void gld_lds16(const void* g, void* l) {
  __builtin_amdgcn_global_load_lds(
      (const __attribute__((address_space(1))) void*)g,
      (__attribute__((address_space(3))) void*)l, 16, 0, 0);
}

// inline-asm ds_read_b128: opaque to the compiler's hazard/waitcnt insertion.
// Caller MUST pair with explicit s_waitcnt lgkmcnt + sched_barrier (rule #18).
__device__ __forceinline__ bf16x8 lds_read_b128(const bf16* p) {
  bf16x8 r;
  unsigned off = (unsigned)(unsigned long)(__attribute__((address_space(3))) bf16*)p;
  asm volatile("ds_read_b128 %0, %1" : "=v"(r) : "v"(off));
  return r;
}
// inline-asm barrier: bypasses compiler-inserted full waitcnt at S_BARRIER.
#define SBAR() asm volatile("s_barrier" ::: "memory")

// xor-chunk swizzle address maps (LDS side). Global tiles are plain row-major;
// the DMA staging permutes the per-lane SOURCE chunk so the LDS image matches.
__device__ __forceinline__ int swz64(int row, int col) {
  return row * 64 + ((((col >> 3) ^ row) & 7) << 3) + (col & 7);
}
__device__ __forceinline__ int swz128(int row, int col) {
  return row * 128 + (((col >> 3) ^ (row & 7)) << 3) + (col & 7);
}

// stage a row-major tile with 64 cols (bf16) into LDS with xor-chunk swizzle
__device__ __forceinline__ void stage64(const bf16* gsrc, bf16* lds, int tid, int nelem) {
  for (int i0 = 0; i0 < nelem; i0 += 2048) {
    int e = i0 + tid * 8;
    int row = e >> 6;
    int sc = ((tid & 7) ^ (row & 7)) << 3;
    gld_lds16((const void*)(gsrc + (row << 6) + sc), (void*)(lds + e));
  }
}
// 128-col variant
__device__ __forceinline__ void stage128(const bf16* gsrc, bf16* lds, int tid, int nelem) {
  for (int i0 = 0; i0 < nelem; i0 += 2048) {
    int e = i0 + tid * 8;
    int row = e >> 7;
    int sc = (((tid & 15) ^ (row & 7))) << 3;
    gld_lds16((const void*)(gsrc + (row << 7) + sc), (void*)(lds + e));
  }
}

// stage one 128row x 64col tile with 256 threads: 4 gld_lds per thread
__device__ __forceinline__ void stage_tileY(const bf16* g, bf16* l, int ldg, int tid) {
#pragma unroll
  for (int it = 0; it < 4; ++it) {
    int e = it * 2048 + tid * 8;
    int r = e >> 6;
    int sc = ((tid & 7) ^ (r & 7)) << 3;
    gld_lds16((const void*)(g + (long)r * ldg + sc), (void*)(l + e));
  }
}

// barrier-free inclusive scan of 128 values (each wave redundantly): a0=scan[lane], a1=scan[64+lane]
__device__ __forceinline__ void wave_scan128(float& a0, float& a1, int lane) {
#pragma unroll
  for (int off = 1; off < 64; off <<= 1) {
    float t0 = __shfl_up(a0, off);
    float t1 = __shfl_up(a1, off);
    if (lane >= off) { a0 += t0; a1 += t1; }
  }
  a1 += __shfl(a0, 63);
}

// ---------------- fused casts: hs, W1 (zero-padded to NPADN rows), Wo ----------------
__global__ __launch_bounds__(256) void cast_all_kernel(
    const float* __restrict__ hs, const float* __restrict__ w1, const float* __restrict__ wo,
    bf16* __restrict__ hs_b, bf16* __restrict__ w1_b, bf16* __restrict__ wo_b) {
  const long n1 = (long)ROWS * DMODEL / 4;
  const long n2 = (long)NPADN * DMODEL / 4;
  const long n3 = (long)DMODEL * DMODEL / 4;
  long total = n1 + n2 + n3;
  long stride = (long)gridDim.x * blockDim.x;
  for (long i = blockIdx.x * (long)blockDim.x + threadIdx.x; i < total; i += stride) {
    if (i < n1) {
      float4 v = ((const float4*)hs)[i];
      ((bf16x4*)hs_b)[i] = bf16x4{(bf16)v.x, (bf16)v.y, (bf16)v.z, (bf16)v.w};
    } else if (i < n1 + n2) {
      long j = i - n1;
      int n = (int)((j * 4) >> 11);
      bf16x4 o = {};
      if (n < NPROJ) {
        float4 v = ((const float4*)w1)[j];
        o = bf16x4{(bf16)v.x, (bf16)v.y, (bf16)v.z, (bf16)v.w};
      }
      ((bf16x4*)w1_b)[j] = o;
    } else {
      long j = i - n1 - n2;
      float4 v = ((const float4*)wo)[j];
      ((bf16x4*)wo_b)[j] = bf16x4{(bf16)v.x, (bf16)v.y, (bf16)v.z, (bf16)v.w};
    }
  }
}

// ---------------- GEMM: 128x128 tile, 256 thr, 64 KiB LDS => 2 blocks/CU ----------------
// Per K-tile: issue next-tile stage, asm ds_reads, lgkm(0), 32 MFMA, vmcnt(0), barrier.
// Wave-level overlap (2 co-resident blocks) hides the staging drain (m114 mechanism).
// Round-5 within-run A/B: 1.47x faster per-work than the 256x128 deep-pipeline variant
// on the common (88-VGPR codegen) toolchain; chosen unconditionally (round-6 lesson:
// hipFuncGetAttributes numRegs counts unified VGPR+AGPR and cannot separate toolchains).
template <typename OutT>
__global__ __launch_bounds__(256, 2) void gemm2p_kernel(
    const bf16* __restrict__ A, const bf16* __restrict__ B, OutT* __restrict__ C,
    int M, int N, int K, int ntx) {
  __shared__ __align__(16) bf16 As[2 * 128 * 64];
  __shared__ __align__(16) bf16 Bs[2 * 128 * 64];
  const int tid = threadIdx.x;
  const int lane = tid & 63;
  const int wave = tid >> 6;
  const int wm = wave >> 1, wn = wave & 1;

  const int GM = 8;
  int lid = blockIdx.x;
  {  // bijective XCD-chunk swizzle: XCD x owns contiguous tile-ids
    int nwg = gridDim.x;
    int xcd = lid & 7;
    int q = nwg >> 3, r = nwg & 7;
    lid = (xcd < r ? xcd * (q + 1) : r * (q + 1) + (xcd - r) * q) + (lid >> 3);
  }
  int group = GM * ntx;
  int gid = lid / group;
  int rem = lid - gid * group;
  int bm = gid * GM + (rem % GM);
  int bn = rem / GM;

  const bf16* Ag = A + (long)bm * 128 * K;
  const bf16* Bg = B + (long)bn * 128 * K;
  const int NT = K >> 6;

  const int fbA = (wm * 64 + (lane & 15)) * 64 + (((lane >> 4) ^ (lane & 7)) << 3);
  const int fbB = (wn * 64 + (lane & 15)) * 64 + (((lane >> 4) ^ (lane & 7)) << 3);

  f32x4 acc[4][4] = {};

  // prologue: tile 0 into buffer 0
  stage_tileY(Ag, As, K, tid);
  stage_tileY(Bg, Bs, K, tid);
  asm volatile("s_waitcnt vmcnt(0)" ::: "memory");
  SBAR();

  for (int t = 0; t < NT; ++t) {
    const int c = t & 1;
    const bf16* At = As + c * 8192;
    const bf16* Bt = Bs + c * 8192;
    if (t + 1 < NT) {   // issue next tile into the other buffer (read at t-1, barrier-cleared)
      stage_tileY(Ag + (t + 1) * 64, As + (c ^ 1) * 8192, K, tid);
      stage_tileY(Bg + (t + 1) * 64, Bs + (c ^ 1) * 8192, K, tid);
    }
    bf16x8 af[4][2], bf_[4][2];
#pragma unroll
    for (int mi = 0; mi < 4; ++mi)
#pragma unroll
      for (int ks = 0; ks < 2; ++ks)
        af[mi][ks] = lds_read_b128(At + ((fbA + mi * 1024) ^ (ks << 5)));
#pragma unroll
    for (int ni = 0; ni < 4; ++ni)
#pragma unroll
      for (int ks = 0; ks < 2; ++ks)
        bf_[ni][ks] = lds_read_b128(Bt + ((fbB + ni * 1024) ^ (ks << 5)));
    asm volatile("s_waitcnt lgkmcnt(0)" ::: "memory");
    __builtin_amdgcn_sched_barrier(0);
    __builtin_amdgcn_s_setprio(1);
#pragma unroll
    for (int mi = 0; mi < 4; ++mi)
#pragma unroll
      for (int ni = 0; ni < 4; ++ni)
#pragma unroll
        for (int ks = 0; ks < 2; ++ks)
          acc[mi][ni] = __builtin_amdgcn_mfma_f32_16x16x32_bf16(af[mi][ks], bf_[ni][ks], acc[mi][ni], 0, 0, 0);
    __builtin_amdgcn_s_setprio(0);
    asm volatile("s_waitcnt vmcnt(0)" ::: "memory");   // next tile resident (had full MFMA window)
    SBAR();
  }

#pragma unroll
  for (int mi = 0; mi < 4; ++mi) {
    int rbase = bm * 128 + wm * 64 + mi * 16 + (lane >> 4) * 4;
#pragma unroll
    for (int ni = 0; ni < 4; ++ni) {
      int col = bn * 128 + wn * 64 + ni * 16 + (lane & 15);
#pragma unroll
      for (int r = 0; r < 4; ++r)
        C[(long)(rbase + r) * N + col] = (OutT)acc[mi][ni][r];
    }
  }
}

// ---------------- prep: conv+SiLU into MFMA-ready tiles + dt ----------------
__global__ __launch_bounds__(256) void prep_kernel(
    const bf16* __restrict__ proj, const float* __restrict__ conv_w,
    const float* __restrict__ conv_b, const float* __restrict__ dt_bias,
    const float* __restrict__ A_log,
    bf16* __restrict__ Qc, bf16* __restrict__ Kc, bf16* __restrict__ Kt,
    bf16* __restrict__ Vt, float* __restrict__ dtb, float* __restrict__ adtb) {
  __shared__ float tile[128][65];
  int blk = blockIdx.x, tid = threadIdx.x;

  if (blk < 1024) {
    int h = blk & 31, c = (blk >> 5) & 15, b = blk >> 9;
    long rowbase = (long)b * LSEQ + c * CHUNK;
    int j = tid >> 1, p0 = (tid & 1) * 32;
    const bf16* cur = proj + (rowbase + j) * NPADN;
    bool hp = (c > 0) || (j > 0);
    int chb = 1024 + h * 64;
    bf16* outb = Qc + (long)blk * 8192 + j * 64;
#pragma unroll
    for (int pp = 0; pp < 32; pp += 4) {
      int p = p0 + pp, ch = chb + p;
      bf16x4 cu = *(const bf16x4*)(cur + ch);
      bf16x4 pv = {};
      if (hp) pv = *(const bf16x4*)(cur + ch - NPADN);
      float4 wa = *(const float4*)(conv_w + 2 * ch);
      float4 wb = *(const float4*)(conv_w + 2 * ch + 4);
      float4 bb = *(const float4*)(conv_b + ch);
      bf16x4 o;
      o[0] = (bf16)fsilu((float)pv[0] * wa.x + (float)cu[0] * wa.y + bb.x);
      o[1] = (bf16)fsilu((float)pv[1] * wa.z + (float)cu[1] * wa.w + bb.y);
      o[2] = (bf16)fsilu((float)pv[2] * wb.x + (float)cu[2] * wb.y + bb.z);
      o[3] = (bf16)fsilu((float)pv[3] * wb.z + (float)cu[3] * wb.w + bb.w);
      *(bf16x4*)(outb + p) = o;
    }
  } else if (blk < 1536) {
    int r = blk - 1024;
    bool isK = r < 256;
    int rr = isK ? r : r - 256;
    int kvh = rr & 7, c = (rr >> 3) & 15, b = rr >> 7;
    long rowbase = (long)b * LSEQ + c * CHUNK;
    int chb = (isK ? 512 : 0) + kvh * 64;
    int j = tid >> 1, p0 = (tid & 1) * 32;
    const bf16* cur = proj + (rowbase + j) * NPADN;
    bool hp = (c > 0) || (j > 0);
#pragma unroll
    for (int pp = 0; pp < 32; pp += 4) {
      int p = p0 + pp, ch = chb + p;
      bf16x4 cu = *(const bf16x4*)(cur + ch);
      bf16x4 pv = {};
      if (hp) pv = *(const bf16x4*)(cur + ch - NPADN);
      float4 wa = *(const float4*)(conv_w + 2 * ch);
      float4 wb = *(const float4*)(conv_w + 2 * ch + 4);
      float4 bb = *(const float4*)(conv_b + ch);
      tile[j][p + 0] = fsilu((float)pv[0] * wa.x + (float)cu[0] * wa.y + bb.x);
      tile[j][p + 1] = fsilu((float)pv[1] * wa.z + (float)cu[1] * wa.w + bb.y);
      tile[j][p + 2] = fsilu((float)pv[2] * wb.x + (float)cu[2] * wb.y + bb.z);
      tile[j][p + 3] = fsilu((float)pv[3] * wb.z + (float)cu[3] * wb.w + bb.w);
    }
    __syncthreads();
    long tb = (long)rr * 8192;
    if (isK) {
#pragma unroll
      for (int it = 0; it < 8; ++it) {
        int e = it * 1024 + tid * 4;
        int jj = e >> 6, n = e & 63;
        bf16x4 o = {(bf16)tile[jj][n], (bf16)tile[jj][n + 1], (bf16)tile[jj][n + 2], (bf16)tile[jj][n + 3]};
        *(bf16x4*)(Kc + tb + e) = o;
      }
#pragma unroll
      for (int it = 0; it < 8; ++it) {
        int e = it * 1024 + tid * 4;
        int n = e >> 7, jj = e & 127;
        bf16x4 o = {(bf16)tile[jj][n], (bf16)tile[jj + 1][n], (bf16)tile[jj + 2][n], (bf16)tile[jj + 3][n]};
        *(bf16x4*)(Kt + tb + e) = o;
      }
    } else {
#pragma unroll
      for (int it = 0; it < 8; ++it) {
        int e = it * 1024 + tid * 4;
        int n = e >> 7, jj = e & 127;
        bf16x4 o = {(bf16)tile[jj][n], (bf16)tile[jj + 1][n], (bf16)tile[jj + 2][n], (bf16)tile[jj + 3][n]};
        *(bf16x4*)(Vt + tb + e) = o;
      }
    }
  } else {
    int r = blk - 1536;
    int c = r & 15, b = r >> 4;
    long rowbase = (long)b * LSEQ + c * CHUNK;
    int j = tid >> 1, h0 = (tid & 1) * 16;
    const bf16* dr = proj + (rowbase + j) * NPADN + (CONVD + DMODEL);
    int obase = (b * 16 + c) * 32;
#pragma unroll
    for (int u = 0; u < 16; ++u) {
      int h = h0 + u;
      float raw = (float)dr[h] + dt_bias[h];
      float dtv = fsoftplus(raw);
      dtb[(long)(obase + h) * 128 + j] = dtv;
      adtb[(long)(obase + h) * 128 + j] = -__expf(A_log[h]) * dtv;
    }
  }
}

// ---------------- SSD phase A ----------------
__global__ __launch_bounds__(256) void ssd_states_kernel(
    const bf16* __restrict__ Kt, const bf16* __restrict__ Vt,
    const float* __restrict__ dtb, const float* __restrict__ adtb,
    float* __restrict__ states, float* __restrict__ asum) {
  __shared__ __align__(16) bf16 Vs[64 * 128];
  __shared__ __align__(16) bf16 Ks[64 * 128];
  __shared__ float w[CHUNK];
  int bid = blockIdx.x;
  int h = bid & 31, c = (bid >> 5) & 15, b = bid >> 9;
  int kvh = h >> 2;
  int tid = threadIdx.x;
  int lane = tid & 63, wave = tid >> 6;
  long kvb = (long)(((b * 16 + c) * 8) + kvh) * 8192;

  stage128(Vt + kvb, Vs, tid, 8192);
  stage128(Kt + kvb, Ks, tid, 8192);

  float a0 = adtb[(long)bid * 128 + lane];
  float a1 = adtb[(long)bid * 128 + 64 + lane];
  float d0 = dtb[(long)bid * 128 + lane];
  float d1 = dtb[(long)bid * 128 + 64 + lane];
  wave_scan128(a0, a1, lane);
  float atot = __shfl(a1, 63);
  if (wave == 0) {
    w[lane] = d0 * __expf(atot - a0);
    w[64 + lane] = d1 * __expf(atot - a1);
  }
  __syncthreads();

#pragma unroll
  for (int it = 0; it < 4; ++it) {
    int e = it * 2048 + tid * 8;
    int row = e >> 7;
    int j0 = (((tid & 15) ^ (row & 7))) << 3;
    f32x4 wa = *(const f32x4*)(w + j0);
    f32x4 wb = *(const f32x4*)(w + j0 + 4);
    bf16x8 kv = *(const bf16x8*)(Ks + e);
    kv[0] = (bf16)((float)kv[0] * wa[0]); kv[1] = (bf16)((float)kv[1] * wa[1]);
    kv[2] = (bf16)((float)kv[2] * wa[2]); kv[3] = (bf16)((float)kv[3] * wa[3]);
    kv[4] = (bf16)((float)kv[4] * wb[0]); kv[5] = (bf16)((float)kv[5] * wb[1]);
    kv[6] = (bf16)((float)kv[6] * wb[2]); kv[7] = (bf16)((float)kv[7] * wb[3]);
    *(bf16x8*)(Ks + e) = kv;
  }
  __syncthreads();

  f32x4 sacc[4] = {};
#pragma unroll
  for (int ks = 0; ks < CHUNK; ks += 32) {
    bf16x8 af = *(const bf16x8*)(Vs + swz128(wave * 16 + (lane & 15), ks + (lane >> 4) * 8));
    bf16x8 bf_[4];
#pragma unroll
    for (int ni = 0; ni < 4; ++ni)
      bf_[ni] = *(const bf16x8*)(Ks + swz128(ni * 16 + (lane & 15), ks + (lane >> 4) * 8));
#pragma unroll
    for (int ni = 0; ni < 4; ++ni)
      sacc[ni] = __builtin_amdgcn_mfma_f32_16x16x32_bf16(af, bf_[ni], sacc[ni], 0, 0, 0);
  }
  float* sout = states + (long)bid * (HD * HD);
#pragma unroll
  for (int ni = 0; ni < 4; ++ni) {
    int n = ni * 16 + (lane & 15);
#pragma unroll
    for (int r = 0; r < 4; ++r) {
      int p = wave * 16 + (lane >> 4) * 4 + r;
      sout[p * HD + n] = sacc[ni][r];
    }
  }
  if (tid == 0) asum[(b * NH + h) * NCHUNK + c] = atot;
}

// ---------------- SSD phase B ----------------
__global__ __launch_bounds__(256) void ssd_scan_kernel(
    const float* __restrict__ states, const float* __restrict__ asum,
    bf16* __restrict__ sprevb) {
  int bid = blockIdx.x;
  int s = bid & 7, h = (bid >> 3) & 31, b = bid >> 8;
  int e0 = s * 512 + threadIdx.x;
  int e1 = e0 + 256;
  float S0 = 0.f, S1 = 0.f;
  const float* as = asum + (b * NH + h) * NCHUNK;
  for (int c = 0; c < NCHUNK; ++c) {
    long off = ((long)((b * NCHUNK + c) * NH + h)) * (HD * HD);
    float g = __expf(as[c]);
    sprevb[off + e0] = (bf16)S0;
    sprevb[off + e1] = (bf16)S1;
    S0 = S0 * g + states[off + e0];
    S1 = S1 * g + states[off + e1];
  }
}

// ---------------- SSD phase C ----------------
__global__ __launch_bounds__(256) void ssd_out_kernel(
    const bf16* __restrict__ Qc, const bf16* __restrict__ Kc, const bf16* __restrict__ Vt,
    const bf16* __restrict__ sprevb, const float* __restrict__ dtb,
    const float* __restrict__ adtb, const bf16* __restrict__ proj,
    const float* __restrict__ gnw, bf16* __restrict__ yg) {
  __shared__ __align__(16) bf16 Qs[128 * 64];
  __shared__ __align__(16) bf16 KVs[128 * 64];
  __shared__ __align__(16) bf16 G[128 * 128];
  __shared__ __align__(16) bf16 Sps[64 * 64];
  __shared__ float acs[CHUNK];
  __shared__ float dts[CHUNK];
  __shared__ float part[CHUNK][2];
  __shared__ float rs_l[CHUNK];

  int bid = blockIdx.x;
  int h = bid & 31, c = (bid >> 5) & 15, b = bid >> 9;
  int kvh = h >> 2;
  int tid = threadIdx.x;
  int lane = tid & 63, wave = tid >> 6;
  int wm = wave >> 1, wn = wave & 1;
  long rowbase = (long)b * LSEQ + c * CHUNK;
  long kvb = (long)(((b * 16 + c) * 8) + kvh) * 8192;

  stage64(Qc + (long)bid * 8192, Qs, tid, 8192);
  stage64(Kc + kvb, KVs, tid, 8192);
  stage64(sprevb + (long)bid * 4096, Sps, tid, 4096);

  float a0 = adtb[(long)bid * 128 + lane];
  float a1 = adtb[(long)bid * 128 + 64 + lane];
  float d0 = dtb[(long)bid * 128 + lane];
  float d1 = dtb[(long)bid * 128 + 64 + lane];
  wave_scan128(a0, a1, lane);
  if (wave == 0) {
    acs[lane] = a0; acs[64 + lane] = a1;
    dts[lane] = d0; dts[64 + lane] = d1;
  }
  __syncthreads();

  {
    f32x4 gacc[4][4] = {};
#pragma unroll
    for (int ks = 0; ks < HD; ks += 32) {
      bf16x8 af[4], bf_[4];
#pragma unroll
      for (int mi = 0; mi < 4; ++mi)
        af[mi] = *(const bf16x8*)(Qs + swz64(wm * 64 + mi * 16 + (lane & 15), ks + (lane >> 4) * 8));
#pragma unroll
      for (int ni = 0; ni < 4; ++ni)
        bf_[ni] = *(const bf16x8*)(KVs + swz64(wn * 64 + ni * 16 + (lane & 15), ks + (lane >> 4) * 8));
#pragma unroll
      for (int mi = 0; mi < 4; ++mi)
#pragma unroll
        for (int ni = 0; ni < 4; ++ni)
          gacc[mi][ni] = __builtin_amdgcn_mfma_f32_16x16x32_bf16(af[mi], bf_[ni], gacc[mi][ni], 0, 0, 0);
    }
    float aj[4], dj[4];
#pragma unroll
    for (int ni = 0; ni < 4; ++ni) {
      int j = wn * 64 + ni * 16 + (lane & 15);
      aj[ni] = acs[j];
      dj[ni] = dts[j];
    }
#pragma unroll
    for (int mi = 0; mi < 4; ++mi) {
#pragma unroll
      for (int r = 0; r < 4; ++r) {
        int i = wm * 64 + mi * 16 + (lane >> 4) * 4 + r;
        float ai = acs[i];
#pragma unroll
        for (int ni = 0; ni < 4; ++ni) {
          int j = wn * 64 + ni * 16 + (lane & 15);
          float gv = (j <= i) ? gacc[mi][ni][r] * __expf(ai - aj[ni]) * dj[ni] : 0.f;
          G[swz128(i, j)] = (bf16)gv;
        }
      }
    }
  }
  __syncthreads();

  stage128(Vt + kvb, KVs, tid, 8192);
  __syncthreads();

  f32x4 yacc[4][2] = {};
  f32x4 oacc[4][2] = {};
#pragma unroll
  for (int ks = 0; ks < CHUNK; ks += 32) {
    bf16x8 af[4], bf_[2];
#pragma unroll
    for (int mi = 0; mi < 4; ++mi)
      af[mi] = *(const bf16x8*)(G + swz128(wm * 64 + mi * 16 + (lane & 15), ks + (lane >> 4) * 8));
#pragma unroll
    for (int ni = 0; ni < 2; ++ni)
      bf_[ni] = *(const bf16x8*)(KVs + swz128(wn * 32 + ni * 16 + (lane & 15), ks + (lane >> 4) * 8));
#pragma unroll
    for (int mi = 0; mi < 4; ++mi)
#pragma unroll
      for (int ni = 0; ni < 2; ++ni)
        yacc[mi][ni] = __builtin_amdgcn_mfma_f32_16x16x32_bf16(af[mi], bf_[ni], yacc[mi][ni], 0, 0, 0);
  }
#pragma unroll
  for (int ks = 0; ks < HD; ks += 32) {
    bf16x8 af[4], bf_[2];
#pragma unroll
    for (int mi = 0; mi < 4; ++mi)
      af[mi] = *(const bf16x8*)(Qs + swz64(wm * 64 + mi * 16 + (lane & 15), ks + (lane >> 4) * 8));
#pragma unroll
    for (int ni = 0; ni < 2; ++ni)
      bf_[ni] = *(const bf16x8*)(Sps + swz64(wn * 32 + ni * 16 + (lane & 15), ks + (lane >> 4) * 8));
#pragma unroll
    for (int mi = 0; mi < 4; ++mi)
#pragma unroll
      for (int ni = 0; ni < 2; ++ni)
        oacc[mi][ni] = __builtin_amdgcn_mfma_f32_16x16x32_bf16(af[mi], bf_[ni], oacc[mi][ni], 0, 0, 0);
  }

  float yv[4][2][4];
#pragma unroll
  for (int mi = 0; mi < 4; ++mi) {
#pragma unroll
    for (int r = 0; r < 4; ++r) {
      int i = wm * 64 + mi * 16 + (lane >> 4) * 4 + r;
      float ei = __expf(acs[i]);
      float s = 0.f;
#pragma unroll
      for (int ni = 0; ni < 2; ++ni) {
        float v = yacc[mi][ni][r] + ei * oacc[mi][ni][r];
        yv[mi][ni][r] = v;
        s += v * v;
      }
      s += __shfl_xor(s, 1, 64);
      s += __shfl_xor(s, 2, 64);
      s += __shfl_xor(s, 4, 64);
      s += __shfl_xor(s, 8, 64);
      if ((lane & 15) == 0) part[i][wn] = s;
    }
  }
  __syncthreads();

  for (int i0 = 0; i0 < 8192; i0 += 2048) {
    int e = i0 + tid * 8;
    int row = e >> 6;
    int sc = ((tid & 7) ^ (row & 7)) << 3;
    gld_lds16((const void*)(proj + (rowbase + row) * NPADN + CONVD + h * 64 + sc),
              (void*)(KVs + e));
  }
  if (tid < CHUNK) rs_l[tid] = rsqrtf((part[tid][0] + part[tid][1]) * (1.0f / HD) + EPSF);
  __syncthreads();

#pragma unroll
  for (int mi = 0; mi < 4; ++mi) {
#pragma unroll
    for (int r = 0; r < 4; ++r) {
      int i = wm * 64 + mi * 16 + (lane >> 4) * 4 + r;
      long row = rowbase + i;
      float rs = rs_l[i];
#pragma unroll
      for (int ni = 0; ni < 2; ++ni) {
        int p = wn * 32 + ni * 16 + (lane & 15);
        float gval = (float)KVs[swz64(i, p)];
        float val = yv[mi][ni][r] * rs * gnw[p] * fsilu(gval);
        yg[row * (long)DMODEL + h * HD + p] = (bf16)val;
      }
    }
  }
}

// ---------------- launch ----------------
extern "C" void kernel_launch(void* const* d_in, const int* in_sizes, int n_in,
                              void* d_out, int out_size, void* d_ws, size_t ws_size,
                              hipStream_t stream) {
  const float* hs      = (const float*)d_in[0];
  const float* W1      = (const float*)d_in[1];
  const float* conv_w  = (const float*)d_in[2];
  const float* conv_b  = (const float*)d_in[3];
  const float* dt_bias = (const float*)d_in[4];
  const float* A_log   = (const float*)d_in[5];
  const float* gnw     = (const float*)d_in[6];
  const float* Wo      = (const float*)d_in[7];

  char* p = (char*)d_ws;
  bf16* hs_b   = (bf16*)p;  p += (long)ROWS * DMODEL * 2;
  bf16* w1_b   = (bf16*)p;  p += (long)NPADN * DMODEL * 2;
  bf16* wo_b   = (bf16*)p;  p += (long)DMODEL * DMODEL * 2;
  bf16* proj   = (bf16*)p;  p += (long)ROWS * NPADN * 2;
  bf16* Qc     = (bf16*)p;  p += (long)1024 * 8192 * 2;
  bf16* Kc     = (bf16*)p;  p += (long)256 * 8192 * 2;
  bf16* Kt     = (bf16*)p;  p += (long)256 * 8192 * 2;
  bf16* Vt     = (bf16*)p;  p += (long)256 * 8192 * 2;
  float* dtb   = (float*)p; p += (long)ROWS * NH * 4;
  float* adtb  = (float*)p; p += (long)ROWS * NH * 4;
  float* st    = (float*)p; p += (long)NB * NCHUNK * NH * HD * HD * 4;
  bf16* sprevb = (bf16*)p;  p += (long)NB * NCHUNK * NH * HD * HD * 2;
  float* asum  = (float*)p; p += (long)NB * NH * NCHUNK * 4;
  bf16* yg     = (bf16*)p;  p += (long)ROWS * DMODEL * 2;

  cast_all_kernel<<<4096, 256, 0, stream>>>(hs, W1, Wo, hs_b, w1_b, wo_b);

  gemm2p_kernel<bf16><<<(ROWS / 128) * (NPADN / 128), 256, 0, stream>>>(
      hs_b, w1_b, proj, ROWS, NPADN, DMODEL, NPADN / 128);

  prep_kernel<<<1568, 256, 0, stream>>>(proj, conv_w, conv_b, dt_bias, A_log,
                                        Qc, Kc, Kt, Vt, dtb, adtb);

  ssd_states_kernel<<<NB * NCHUNK * NH, 256, 0, stream>>>(Kt, Vt, dtb, adtb, st, asum);
  ssd_scan_kernel<<<NB * NH * 8, 256, 0, stream>>>(st, asum, sprevb);
  ssd_out_kernel<<<NB * NCHUNK * NH, 256, 0, stream>>>(
      Qc, Kc, Vt, sprevb, dtb, adtb, proj, gnw, yg);

  gemm2p_kernel<float><<<(ROWS / 128) * (DMODEL / 128), 256, 0, stream>>>(
      yg, wo_b, (float*)d_out, ROWS, DMODEL, DMODEL, DMODEL / 128);
}

// Round 8
// 337.313 us; speedup vs baseline: 1.1319x; 1.0471x over previous
//
#include <hip/hip_runtime.h>
#include <hip/hip_bf16.h>
#include <math.h>

typedef __bf16 bf16;
typedef __bf16 bf16x4 __attribute__((ext_vector_type(4)));
typedef __bf16 bf16x8 __attribute__((ext_vector_type(8)));
typedef float f32x4 __attribute__((ext_vector_type(4)));

#define NB 2
#define LSEQ 2048
#define NH 32
#define NKVH 8
#define HD 64
#define DMODEL 2048
#define CONVD 3072
#define NPROJ 5152
#define NPADN 5248
#define NCHUNK 16
#define CHUNK 128
#define ROWS 4096
#define EPSF 1e-5f

__device__ __forceinline__ float fsilu(float x) { return x / (1.0f + __expf(-x)); }
__device__ __forceinline__ float fsoftplus(float raw) {
  return (raw > 20.0f) ? raw : log1pf(__expf(raw));
}

__device__ __forceinline__ void gld_lds16(const void* g, void* l) {
  __builtin_amdgcn_global_load_lds(
      (const __attribute__((address_space(1))) void*)g,
      (__attribute__((address_space(3))) void*)l, 16, 0, 0);
}

// inline-asm ds_read_b128: opaque to the compiler's hazard/waitcnt insertion.
// Caller MUST pair with explicit s_waitcnt lgkmcnt + sched_barrier (rule #18).
__device__ __forceinline__ bf16x8 lds_read_b128(const bf16* p) {
  bf16x8 r;
  unsigned off = (unsigned)(unsigned long)(__attribute__((address_space(3))) bf16*)p;
  asm volatile("ds_read_b128 %0, %1" : "=v"(r) : "v"(off));
  return r;
}
// inline-asm barrier: bypasses compiler-inserted full waitcnt at S_BARRIER.
#define SBAR() asm volatile("s_barrier" ::: "memory")

// xor-chunk swizzle address maps (LDS side). Global tiles are plain row-major;
// the DMA staging permutes the per-lane SOURCE chunk so the LDS image matches:
// LDS[swz64(row,col)] = G[row][col].
__device__ __forceinline__ int swz64(int row, int col) {
  return row * 64 + ((((col >> 3) ^ row) & 7) << 3) + (col & 7);
}
__device__ __forceinline__ int swz128(int row, int col) {
  return row * 128 + (((col >> 3) ^ (row & 7)) << 3) + (col & 7);
}

// stage a row-major tile with 64 cols (bf16) into LDS with xor-chunk swizzle
__device__ __forceinline__ void stage64(const bf16* gsrc, bf16* lds, int tid, int nelem) {
  for (int i0 = 0; i0 < nelem; i0 += 2048) {
    int e = i0 + tid * 8;
    int row = e >> 6;
    int sc = ((tid & 7) ^ (row & 7)) << 3;
    gld_lds16((const void*)(gsrc + (row << 6) + sc), (void*)(lds + e));
  }
}
// 128-col variant
__device__ __forceinline__ void stage128(const bf16* gsrc, bf16* lds, int tid, int nelem) {
  for (int i0 = 0; i0 < nelem; i0 += 2048) {
    int e = i0 + tid * 8;
    int row = e >> 7;
    int sc = (((tid & 15) ^ (row & 7))) << 3;
    gld_lds16((const void*)(gsrc + (row << 7) + sc), (void*)(lds + e));
  }
}

// stage one 128row x 64col tile with 256 threads: 4 gld_lds per thread
__device__ __forceinline__ void stage_tileY(const bf16* g, bf16* l, int ldg, int tid) {
#pragma unroll
  for (int it = 0; it < 4; ++it) {
    int e = it * 2048 + tid * 8;
    int r = e >> 6;
    int sc = ((tid & 7) ^ (r & 7)) << 3;
    gld_lds16((const void*)(g + (long)r * ldg + sc), (void*)(l + e));
  }
}

// barrier-free inclusive scan of 128 values (each wave redundantly): a0=scan[lane], a1=scan[64+lane]
__device__ __forceinline__ void wave_scan128(float& a0, float& a1, int lane) {
#pragma unroll
  for (int off = 1; off < 64; off <<= 1) {
    float t0 = __shfl_up(a0, off);
    float t1 = __shfl_up(a1, off);
    if (lane >= off) { a0 += t0; a1 += t1; }
  }
  a1 += __shfl(a0, 63);
}

// ---------------- fused casts: hs, W1 (zero-padded to NPADN rows), Wo ----------------
// 8-elem chunks: 2x float4 in, 1x bf16x8 (16B) out.
__global__ __launch_bounds__(256) void cast_all_kernel(
    const float* __restrict__ hs, const float* __restrict__ w1, const float* __restrict__ wo,
    bf16* __restrict__ hs_b, bf16* __restrict__ w1_b, bf16* __restrict__ wo_b) {
  const long n1 = (long)ROWS * DMODEL / 8;
  const long n2 = (long)NPADN * DMODEL / 8;
  const long n3 = (long)DMODEL * DMODEL / 8;
  long total = n1 + n2 + n3;
  long stride = (long)gridDim.x * blockDim.x;
  for (long i = blockIdx.x * (long)blockDim.x + threadIdx.x; i < total; i += stride) {
    if (i < n1) {
      float4 v0 = ((const float4*)hs)[2 * i];
      float4 v1 = ((const float4*)hs)[2 * i + 1];
      ((bf16x8*)hs_b)[i] = bf16x8{(bf16)v0.x, (bf16)v0.y, (bf16)v0.z, (bf16)v0.w,
                                  (bf16)v1.x, (bf16)v1.y, (bf16)v1.z, (bf16)v1.w};
    } else if (i < n1 + n2) {
      long j = i - n1;
      int n = (int)((j * 8) >> 11);   // row of padded W1
      bf16x8 o = {};
      if (n < NPROJ) {
        float4 v0 = ((const float4*)w1)[2 * j];
        float4 v1 = ((const float4*)w1)[2 * j + 1];
        o = bf16x8{(bf16)v0.x, (bf16)v0.y, (bf16)v0.z, (bf16)v0.w,
                   (bf16)v1.x, (bf16)v1.y, (bf16)v1.z, (bf16)v1.w};
      }
      ((bf16x8*)w1_b)[j] = o;
    } else {
      long j = i - n1 - n2;
      float4 v0 = ((const float4*)wo)[2 * j];
      float4 v1 = ((const float4*)wo)[2 * j + 1];
      ((bf16x8*)wo_b)[j] = bf16x8{(bf16)v0.x, (bf16)v0.y, (bf16)v0.z, (bf16)v0.w,
                                  (bf16)v1.x, (bf16)v1.y, (bf16)v1.z, (bf16)v1.w};
    }
  }
}

// ---------------- GEMM: 128x128 tile, 256 thr, 64 KiB LDS => 2 blocks/CU ----------------
// Per K-tile: issue next-tile stage, asm ds_reads, lgkm(0), 32 MFMA, vmcnt(0), barrier.
// Wave-level overlap (2 co-resident blocks) hides the staging drain (m114 mechanism).
// At 4096x5248x2048: 92.4 us = 953 TF (round 7) — at the 128^2-structure ceiling.
template <typename OutT>
__global__ __launch_bounds__(256, 2) void gemm2p_kernel(
    const bf16* __restrict__ A, const bf16* __restrict__ B, OutT* __restrict__ C,
    int M, int N, int K, int ntx) {
  __shared__ __align__(16) bf16 As[2 * 128 * 64];
  __shared__ __align__(16) bf16 Bs[2 * 128 * 64];
  const int tid = threadIdx.x;
  const int lane = tid & 63;
  const int wave = tid >> 6;
  const int wm = wave >> 1, wn = wave & 1;

  const int GM = 8;
  int lid = blockIdx.x;
  {  // bijective XCD-chunk swizzle: XCD x owns contiguous tile-ids
    int nwg = gridDim.x;
    int xcd = lid & 7;
    int q = nwg >> 3, r = nwg & 7;
    lid = (xcd < r ? xcd * (q + 1) : r * (q + 1) + (xcd - r) * q) + (lid >> 3);
  }
  int group = GM * ntx;
  int gid = lid / group;
  int rem = lid - gid * group;
  int bm = gid * GM + (rem % GM);
  int bn = rem / GM;

  const bf16* Ag = A + (long)bm * 128 * K;
  const bf16* Bg = B + (long)bn * 128 * K;
  const int NT = K >> 6;

  const int fbA = (wm * 64 + (lane & 15)) * 64 + (((lane >> 4) ^ (lane & 7)) << 3);
  const int fbB = (wn * 64 + (lane & 15)) * 64 + (((lane >> 4) ^ (lane & 7)) << 3);

  f32x4 acc[4][4] = {};

  // prologue: tile 0 into buffer 0
  stage_tileY(Ag, As, K, tid);
  stage_tileY(Bg, Bs, K, tid);
  asm volatile("s_waitcnt vmcnt(0)" ::: "memory");
  SBAR();

  for (int t = 0; t < NT; ++t) {
    const int c = t & 1;
    const bf16* At = As + c * 8192;
    const bf16* Bt = Bs + c * 8192;
    if (t + 1 < NT) {   // issue next tile into the other buffer (read at t-1, barrier-cleared)
      stage_tileY(Ag + (t + 1) * 64, As + (c ^ 1) * 8192, K, tid);
      stage_tileY(Bg + (t + 1) * 64, Bs + (c ^ 1) * 8192, K, tid);
    }
    bf16x8 af[4][2], bf_[4][2];
#pragma unroll
    for (int mi = 0; mi < 4; ++mi)
#pragma unroll
      for (int ks = 0; ks < 2; ++ks)
        af[mi][ks] = lds_read_b128(At + ((fbA + mi * 1024) ^ (ks << 5)));
#pragma unroll
    for (int ni = 0; ni < 4; ++ni)
#pragma unroll
      for (int ks = 0; ks < 2; ++ks)
        bf_[ni][ks] = lds_read_b128(Bt + ((fbB + ni * 1024) ^ (ks << 5)));
    asm volatile("s_waitcnt lgkmcnt(0)" ::: "memory");
    __builtin_amdgcn_sched_barrier(0);
    __builtin_amdgcn_s_setprio(1);
#pragma unroll
    for (int mi = 0; mi < 4; ++mi)
#pragma unroll
      for (int ni = 0; ni < 4; ++ni)
#pragma unroll
        for (int ks = 0; ks < 2; ++ks)
          acc[mi][ni] = __builtin_amdgcn_mfma_f32_16x16x32_bf16(af[mi][ks], bf_[ni][ks], acc[mi][ni], 0, 0, 0);
    __builtin_amdgcn_s_setprio(0);
    asm volatile("s_waitcnt vmcnt(0)" ::: "memory");   // next tile resident (had full MFMA window)
    SBAR();
  }

#pragma unroll
  for (int mi = 0; mi < 4; ++mi) {
    int rbase = bm * 128 + wm * 64 + mi * 16 + (lane >> 4) * 4;
#pragma unroll
    for (int ni = 0; ni < 4; ++ni) {
      int col = bn * 128 + wn * 64 + ni * 16 + (lane & 15);
#pragma unroll
      for (int r = 0; r < 4; ++r)
        C[(long)(rbase + r) * N + col] = (OutT)acc[mi][ni][r];
    }
  }
}

// ---------------- prep: conv+SiLU K/V tiles + dt (Q is fused into ssd_out) ----------------
// blocks 0..255:   K (b,c,kvh)-> Kc[j][n] and Kt[n][j]
// blocks 256..511: V (b,c,kvh)-> Vt[p][j]
// blocks 512..543: D (b,c)    -> dtb/adtb[(b,c,h)][j]
__global__ __launch_bounds__(256) void prep_kernel(
    const bf16* __restrict__ proj, const float* __restrict__ conv_w,
    const float* __restrict__ conv_b, const float* __restrict__ dt_bias,
    const float* __restrict__ A_log,
    bf16* __restrict__ Kc, bf16* __restrict__ Kt,
    bf16* __restrict__ Vt, float* __restrict__ dtb, float* __restrict__ adtb) {
  __shared__ float tile[128][65];
  int blk = blockIdx.x, tid = threadIdx.x;

  if (blk < 512) {
    int r = blk;
    bool isK = r < 256;
    int rr = isK ? r : r - 256;
    int kvh = rr & 7, c = (rr >> 3) & 15, b = rr >> 7;
    long rowbase = (long)b * LSEQ + c * CHUNK;
    int chb = (isK ? 512 : 0) + kvh * 64;
    int j = tid >> 1, p0 = (tid & 1) * 32;
    const bf16* cur = proj + (rowbase + j) * NPADN;
    bool hp = (c > 0) || (j > 0);
#pragma unroll
    for (int pp = 0; pp < 32; pp += 4) {
      int p = p0 + pp, ch = chb + p;
      bf16x4 cu = *(const bf16x4*)(cur + ch);
      bf16x4 pv = {};
      if (hp) pv = *(const bf16x4*)(cur + ch - NPADN);
      float4 wa = *(const float4*)(conv_w + 2 * ch);
      float4 wb = *(const float4*)(conv_w + 2 * ch + 4);
      float4 bb = *(const float4*)(conv_b + ch);
      tile[j][p + 0] = fsilu((float)pv[0] * wa.x + (float)cu[0] * wa.y + bb.x);
      tile[j][p + 1] = fsilu((float)pv[1] * wa.z + (float)cu[1] * wa.w + bb.y);
      tile[j][p + 2] = fsilu((float)pv[2] * wb.x + (float)cu[2] * wb.y + bb.z);
      tile[j][p + 3] = fsilu((float)pv[3] * wb.z + (float)cu[3] * wb.w + bb.w);
    }
    __syncthreads();
    long tb = (long)rr * 8192;
    if (isK) {
#pragma unroll
      for (int it = 0; it < 8; ++it) {
        int e = it * 1024 + tid * 4;
        int jj = e >> 6, n = e & 63;
        bf16x4 o = {(bf16)tile[jj][n], (bf16)tile[jj][n + 1], (bf16)tile[jj][n + 2], (bf16)tile[jj][n + 3]};
        *(bf16x4*)(Kc + tb + e) = o;
      }
#pragma unroll
      for (int it = 0; it < 8; ++it) {
        int e = it * 1024 + tid * 4;
        int n = e >> 7, jj = e & 127;
        bf16x4 o = {(bf16)tile[jj][n], (bf16)tile[jj + 1][n], (bf16)tile[jj + 2][n], (bf16)tile[jj + 3][n]};
        *(bf16x4*)(Kt + tb + e) = o;
      }
    } else {
#pragma unroll
      for (int it = 0; it < 8; ++it) {
        int e = it * 1024 + tid * 4;
        int n = e >> 7, jj = e & 127;
        bf16x4 o = {(bf16)tile[jj][n], (bf16)tile[jj + 1][n], (bf16)tile[jj + 2][n], (bf16)tile[jj + 3][n]};
        *(bf16x4*)(Vt + tb + e) = o;
      }
    }
  } else {
    int r = blk - 512;
    int c = r & 15, b = r >> 4;
    long rowbase = (long)b * LSEQ + c * CHUNK;
    int j = tid >> 1, h0 = (tid & 1) * 16;
    const bf16* dr = proj + (rowbase + j) * NPADN + (CONVD + DMODEL);
    int obase = (b * 16 + c) * 32;
#pragma unroll
    for (int u = 0; u < 16; ++u) {
      int h = h0 + u;
      float raw = (float)dr[h] + dt_bias[h];
      float dtv = fsoftplus(raw);
      dtb[(long)(obase + h) * 128 + j] = dtv;
      adtb[(long)(obase + h) * 128 + j] = -__expf(A_log[h]) * dtv;
    }
  }
}

// ---------------- SSD phase A ----------------
__global__ __launch_bounds__(256) void ssd_states_kernel(
    const bf16* __restrict__ Kt, const bf16* __restrict__ Vt,
    const float* __restrict__ dtb, const float* __restrict__ adtb,
    float* __restrict__ states, float* __restrict__ asum) {
  __shared__ __align__(16) bf16 Vs[64 * 128];
  __shared__ __align__(16) bf16 Ks[64 * 128];
  __shared__ float w[CHUNK];
  int bid = blockIdx.x;
  int h = bid & 31, c = (bid >> 5) & 15, b = bid >> 9;
  int kvh = h >> 2;
  int tid = threadIdx.x;
  int lane = tid & 63, wave = tid >> 6;
  long kvb = (long)(((b * 16 + c) * 8) + kvh) * 8192;

  stage128(Vt + kvb, Vs, tid, 8192);
  stage128(Kt + kvb, Ks, tid, 8192);

  float a0 = adtb[(long)bid * 128 + lane];
  float a1 = adtb[(long)bid * 128 + 64 + lane];
  float d0 = dtb[(long)bid * 128 + lane];
  float d1 = dtb[(long)bid * 128 + 64 + lane];
  wave_scan128(a0, a1, lane);
  float atot = __shfl(a1, 63);
  if (wave == 0) {
    w[lane] = d0 * __expf(atot - a0);
    w[64 + lane] = d1 * __expf(atot - a1);
  }
  __syncthreads();

#pragma unroll
  for (int it = 0; it < 4; ++it) {
    int e = it * 2048 + tid * 8;
    int row = e >> 7;
    int j0 = (((tid & 15) ^ (row & 7))) << 3;
    f32x4 wa = *(const f32x4*)(w + j0);
    f32x4 wb = *(const f32x4*)(w + j0 + 4);
    bf16x8 kv = *(const bf16x8*)(Ks + e);
    kv[0] = (bf16)((float)kv[0] * wa[0]); kv[1] = (bf16)((float)kv[1] * wa[1]);
    kv[2] = (bf16)((float)kv[2] * wa[2]); kv[3] = (bf16)((float)kv[3] * wa[3]);
    kv[4] = (bf16)((float)kv[4] * wb[0]); kv[5] = (bf16)((float)kv[5] * wb[1]);
    kv[6] = (bf16)((float)kv[6] * wb[2]); kv[7] = (bf16)((float)kv[7] * wb[3]);
    *(bf16x8*)(Ks + e) = kv;
  }
  __syncthreads();

  f32x4 sacc[4] = {};
#pragma unroll
  for (int ks = 0; ks < CHUNK; ks += 32) {
    bf16x8 af = *(const bf16x8*)(Vs + swz128(wave * 16 + (lane & 15), ks + (lane >> 4) * 8));
    bf16x8 bf_[4];
#pragma unroll
    for (int ni = 0; ni < 4; ++ni)
      bf_[ni] = *(const bf16x8*)(Ks + swz128(ni * 16 + (lane & 15), ks + (lane >> 4) * 8));
#pragma unroll
    for (int ni = 0; ni < 4; ++ni)
      sacc[ni] = __builtin_amdgcn_mfma_f32_16x16x32_bf16(af, bf_[ni], sacc[ni], 0, 0, 0);
  }
  float* sout = states + (long)bid * (HD * HD);
#pragma unroll
  for (int ni = 0; ni < 4; ++ni) {
    int n = ni * 16 + (lane & 15);
#pragma unroll
    for (int r = 0; r < 4; ++r) {
      int p = wave * 16 + (lane >> 4) * 4 + r;
      sout[p * HD + n] = sacc[ni][r];
    }
  }
  if (tid == 0) asum[(b * NH + h) * NCHUNK + c] = atot;
}

// ---------------- SSD phase B ----------------
__global__ __launch_bounds__(256) void ssd_scan_kernel(
    const float* __restrict__ states, const float* __restrict__ asum,
    bf16* __restrict__ sprevb) {
  int bid = blockIdx.x;
  int s = bid & 7, h = (bid >> 3) & 31, b = bid >> 8;
  int e0 = s * 512 + threadIdx.x;
  int e1 = e0 + 256;
  float S0 = 0.f, S1 = 0.f;
  const float* as = asum + (b * NH + h) * NCHUNK;
  for (int c = 0; c < NCHUNK; ++c) {
    long off = ((long)((b * NCHUNK + c) * NH + h)) * (HD * HD);
    float g = __expf(as[c]);
    sprevb[off + e0] = (bf16)S0;
    sprevb[off + e1] = (bf16)S1;
    S0 = S0 * g + states[off + e0];
    S1 = S1 * g + states[off + e1];
  }
}

// ---------------- SSD phase C (Q-conv fused in) ----------------
__global__ __launch_bounds__(256) void ssd_out_kernel(
    const bf16* __restrict__ Kc, const bf16* __restrict__ Vt,
    const bf16* __restrict__ sprevb, const float* __restrict__ dtb,
    const float* __restrict__ adtb, const bf16* __restrict__ proj,
    const float* __restrict__ conv_w, const float* __restrict__ conv_b,
    const float* __restrict__ gnw, bf16* __restrict__ yg) {
  __shared__ __align__(16) bf16 Qs[128 * 64];
  __shared__ __align__(16) bf16 KVs[128 * 64];
  __shared__ __align__(16) bf16 G[128 * 128];
  __shared__ __align__(16) bf16 Sps[64 * 64];
  __shared__ float acs[CHUNK];
  __shared__ float dts[CHUNK];
  __shared__ float part[CHUNK][2];
  __shared__ float rs_l[CHUNK];

  int bid = blockIdx.x;
  int h = bid & 31, c = (bid >> 5) & 15, b = bid >> 9;
  int kvh = h >> 2;
  int tid = threadIdx.x;
  int lane = tid & 63, wave = tid >> 6;
  int wm = wave >> 1, wn = wave & 1;
  long rowbase = (long)b * LSEQ + c * CHUNK;
  long kvb = (long)(((b * 16 + c) * 8) + kvh) * 8192;

  // issue DMA stages first so they overlap the Q-conv VALU below
  stage64(Kc + kvb, KVs, tid, 8192);
  stage64(sprevb + (long)bid * 4096, Sps, tid, 4096);

  // --- inline Q build: Qs[swz64(j,col)] = silu(conv(proj Q-slice)) ---
  {
    int j = tid >> 1, p0 = (tid & 1) * 32;
    const bf16* cur = proj + (rowbase + j) * NPADN;
    bool hp = (c > 0) || (j > 0);
    int chb = 1024 + h * 64;
    bf16* qrow = Qs + j * 64;
#pragma unroll
    for (int pp = 0; pp < 32; pp += 4) {
      int p = p0 + pp, ch = chb + p;
      bf16x4 cu = *(const bf16x4*)(cur + ch);
      bf16x4 pv = {};
      if (hp) pv = *(const bf16x4*)(cur + ch - NPADN);
      float4 wa = *(const float4*)(conv_w + 2 * ch);
      float4 wb = *(const float4*)(conv_w + 2 * ch + 4);
      float4 bb = *(const float4*)(conv_b + ch);
      bf16x4 o;
      o[0] = (bf16)fsilu((float)pv[0] * wa.x + (float)cu[0] * wa.y + bb.x);
      o[1] = (bf16)fsilu((float)pv[1] * wa.z + (float)cu[1] * wa.w + bb.y);
      o[2] = (bf16)fsilu((float)pv[2] * wb.x + (float)cu[2] * wb.y + bb.z);
      o[3] = (bf16)fsilu((float)pv[3] * wb.z + (float)cu[3] * wb.w + bb.w);
      *(bf16x4*)(qrow + ((((p >> 3) ^ j) & 7) << 3) + (p & 7)) = o;
    }
  }

  float a0 = adtb[(long)bid * 128 + lane];
  float a1 = adtb[(long)bid * 128 + 64 + lane];
  float d0 = dtb[(long)bid * 128 + lane];
  float d1 = dtb[(long)bid * 128 + 64 + lane];
  wave_scan128(a0, a1, lane);
  if (wave == 0) {
    acs[lane] = a0; acs[64 + lane] = a1;
    dts[lane] = d0; dts[64 + lane] = d1;
  }
  __syncthreads();   // DMA drained + Q writes + scan visible

  {
    f32x4 gacc[4][4] = {};
#pragma unroll
    for (int ks = 0; ks < HD; ks += 32) {
      bf16x8 af[4], bf_[4];
#pragma unroll
      for (int mi = 0; mi < 4; ++mi)
        af[mi] = *(const bf16x8*)(Qs + swz64(wm * 64 + mi * 16 + (lane & 15), ks + (lane >> 4) * 8));
#pragma unroll
      for (int ni = 0; ni < 4; ++ni)
        bf_[ni] = *(const bf16x8*)(KVs + swz64(wn * 64 + ni * 16 + (lane & 15), ks + (lane >> 4) * 8));
#pragma unroll
      for (int mi = 0; mi < 4; ++mi)
#pragma unroll
        for (int ni = 0; ni < 4; ++ni)
          gacc[mi][ni] = __builtin_amdgcn_mfma_f32_16x16x32_bf16(af[mi], bf_[ni], gacc[mi][ni], 0, 0, 0);
    }
    float aj[4], dj[4];
#pragma unroll
    for (int ni = 0; ni < 4; ++ni) {
      int j = wn * 64 + ni * 16 + (lane & 15);
      aj[ni] = acs[j];
      dj[ni] = dts[j];
    }
#pragma unroll
    for (int mi = 0; mi < 4; ++mi) {
#pragma unroll
      for (int r = 0; r < 4; ++r) {
        int i = wm * 64 + mi * 16 + (lane >> 4) * 4 + r;
        float ai = acs[i];
#pragma unroll
        for (int ni = 0; ni < 4; ++ni) {
          int j = wn * 64 + ni * 16 + (lane & 15);
          float gv = (j <= i) ? gacc[mi][ni][r] * __expf(ai - aj[ni]) * dj[ni] : 0.f;
          G[swz128(i, j)] = (bf16)gv;
        }
      }
    }
  }
  __syncthreads();

  stage128(Vt + kvb, KVs, tid, 8192);
  __syncthreads();

  f32x4 yacc[4][2] = {};
  f32x4 oacc[4][2] = {};
#pragma unroll
  for (int ks = 0; ks < CHUNK; ks += 32) {
    bf16x8 af[4], bf_[2];
#pragma unroll
    for (int mi = 0; mi < 4; ++mi)
      af[mi] = *(const bf16x8*)(G + swz128(wm * 64 + mi * 16 + (lane & 15), ks + (lane >> 4) * 8));
#pragma unroll
    for (int ni = 0; ni < 2; ++ni)
      bf_[ni] = *(const bf16x8*)(KVs + swz128(wn * 32 + ni * 16 + (lane & 15), ks + (lane >> 4) * 8));
#pragma unroll
    for (int mi = 0; mi < 4; ++mi)
#pragma unroll
      for (int ni = 0; ni < 2; ++ni)
        yacc[mi][ni] = __builtin_amdgcn_mfma_f32_16x16x32_bf16(af[mi], bf_[ni], yacc[mi][ni], 0, 0, 0);
  }
#pragma unroll
  for (int ks = 0; ks < HD; ks += 32) {
    bf16x8 af[4], bf_[2];
#pragma unroll
    for (int mi = 0; mi < 4; ++mi)
      af[mi] = *(const bf16x8*)(Qs + swz64(wm * 64 + mi * 16 + (lane & 15), ks + (lane >> 4) * 8));
#pragma unroll
    for (int ni = 0; ni < 2; ++ni)
      bf_[ni] = *(const bf16x8*)(Sps + swz64(wn * 32 + ni * 16 + (lane & 15), ks + (lane >> 4) * 8));
#pragma unroll
    for (int mi = 0; mi < 4; ++mi)
#pragma unroll
      for (int ni = 0; ni < 2; ++ni)
        oacc[mi][ni] = __builtin_amdgcn_mfma_f32_16x16x32_bf16(af[mi], bf_[ni], oacc[mi][ni], 0, 0, 0);
  }

  float yv[4][2][4];
#pragma unroll
  for (int mi = 0; mi < 4; ++mi) {
#pragma unroll
    for (int r = 0; r < 4; ++r) {
      int i = wm * 64 + mi * 16 + (lane >> 4) * 4 + r;
      float ei = __expf(acs[i]);
      float s = 0.f;
#pragma unroll
      for (int ni = 0; ni < 2; ++ni) {
        float v = yacc[mi][ni][r] + ei * oacc[mi][ni][r];
        yv[mi][ni][r] = v;
        s += v * v;
      }
      s += __shfl_xor(s, 1, 64);
      s += __shfl_xor(s, 2, 64);
      s += __shfl_xor(s, 4, 64);
      s += __shfl_xor(s, 8, 64);
      if ((lane & 15) == 0) part[i][wn] = s;
    }
  }
  __syncthreads();

  for (int i0 = 0; i0 < 8192; i0 += 2048) {
    int e = i0 + tid * 8;
    int row = e >> 6;
    int sc = ((tid & 7) ^ (row & 7)) << 3;
    gld_lds16((const void*)(proj + (rowbase + row) * NPADN + CONVD + h * 64 + sc),
              (void*)(KVs + e));
  }
  if (tid < CHUNK) rs_l[tid] = rsqrtf((part[tid][0] + part[tid][1]) * (1.0f / HD) + EPSF);
  __syncthreads();

#pragma unroll
  for (int mi = 0; mi < 4; ++mi) {
#pragma unroll
    for (int r = 0; r < 4; ++r) {
      int i = wm * 64 + mi * 16 + (lane >> 4) * 4 + r;
      long row = rowbase + i;
      float rs = rs_l[i];
#pragma unroll
      for (int ni = 0; ni < 2; ++ni) {
        int p = wn * 32 + ni * 16 + (lane & 15);
        float gval = (float)KVs[swz64(i, p)];
        float val = yv[mi][ni][r] * rs * gnw[p] * fsilu(gval);
        yg[row * (long)DMODEL + h * HD + p] = (bf16)val;
      }
    }
  }
}

// ---------------- launch ----------------
extern "C" void kernel_launch(void* const* d_in, const int* in_sizes, int n_in,
                              void* d_out, int out_size, void* d_ws, size_t ws_size,
                              hipStream_t stream) {
  const float* hs      = (const float*)d_in[0];
  const float* W1      = (const float*)d_in[1];
  const float* conv_w  = (const float*)d_in[2];
  const float* conv_b  = (const float*)d_in[3];
  const float* dt_bias = (const float*)d_in[4];
  const float* A_log   = (const float*)d_in[5];
  const float* gnw     = (const float*)d_in[6];
  const float* Wo      = (const float*)d_in[7];

  char* p = (char*)d_ws;
  bf16* hs_b   = (bf16*)p;  p += (long)ROWS * DMODEL * 2;
  bf16* w1_b   = (bf16*)p;  p += (long)NPADN * DMODEL * 2;
  bf16* wo_b   = (bf16*)p;  p += (long)DMODEL * DMODEL * 2;
  bf16* proj   = (bf16*)p;  p += (long)ROWS * NPADN * 2;
  bf16* Kc     = (bf16*)p;  p += (long)256 * 8192 * 2;
  bf16* Kt     = (bf16*)p;  p += (long)256 * 8192 * 2;
  bf16* Vt     = (bf16*)p;  p += (long)256 * 8192 * 2;
  float* dtb   = (float*)p; p += (long)ROWS * NH * 4;
  float* adtb  = (float*)p; p += (long)ROWS * NH * 4;
  float* st    = (float*)p; p += (long)NB * NCHUNK * NH * HD * HD * 4;
  bf16* sprevb = (bf16*)p;  p += (long)NB * NCHUNK * NH * HD * HD * 2;
  float* asum  = (float*)p; p += (long)NB * NH * NCHUNK * 4;
  bf16* yg     = (bf16*)p;  p += (long)ROWS * DMODEL * 2;

  cast_all_kernel<<<4096, 256, 0, stream>>>(hs, W1, Wo, hs_b, w1_b, wo_b);

  gemm2p_kernel<bf16><<<(ROWS / 128) * (NPADN / 128), 256, 0, stream>>>(
      hs_b, w1_b, proj, ROWS, NPADN, DMODEL, NPADN / 128);

  prep_kernel<<<544, 256, 0, stream>>>(proj, conv_w, conv_b, dt_bias, A_log,
                                       Kc, Kt, Vt, dtb, adtb);

  ssd_states_kernel<<<NB * NCHUNK * NH, 256, 0, stream>>>(Kt, Vt, dtb, adtb, st, asum);
  ssd_scan_kernel<<<NB * NH * 8, 256, 0, stream>>>(st, asum, sprevb);
  ssd_out_kernel<<<NB * NCHUNK * NH, 256, 0, stream>>>(
      Kc, Vt, sprevb, dtb, adtb, proj, conv_w, conv_b, gnw, yg);

  gemm2p_kernel<float><<<(ROWS / 128) * (DMODEL / 128), 256, 0, stream>>>(
      yg, wo_b, (float*)d_out, ROWS, DMODEL, DMODEL, DMODEL / 128);
}

// Round 9
// 327.005 us; speedup vs baseline: 1.1676x; 1.0315x over previous
//
#include <hip/hip_runtime.h>
#include <hip/hip_bf16.h>
#include <math.h>

typedef __bf16 bf16;
typedef __bf16 bf16x4 __attribute__((ext_vector_type(4)));
typedef __bf16 bf16x8 __attribute__((ext_vector_type(8)));
typedef float f32x4 __attribute__((ext_vector_type(4)));

#define NB 2
#define LSEQ 2048
#define NH 32
#define NKVH 8
#define HD 64
#define DMODEL 2048
#define CONVD 3072
#define NPROJ 5152
#define NPADN 5248
#define NCHUNK 16
#define CHUNK 128
#define ROWS 4096
#define EPSF 1e-5f

__device__ __forceinline__ float fsilu(float x) { return x / (1.0f + __expf(-x)); }
__device__ __forceinline__ float fsoftplus(float raw) {
  return (raw > 20.0f) ? raw : log1pf(__expf(raw));
}

__device__ __forceinline__ void gld_lds16(const void* g, void* l) {
  __builtin_amdgcn_global_load_lds(
      (const __attribute__((address_space(1))) void*)g,
      (__attribute__((address_space(3))) void*)l, 16, 0, 0);
}

// inline-asm ds_read_b128: opaque to the compiler's hazard/waitcnt insertion.
// Caller MUST pair with explicit s_waitcnt lgkmcnt + sched_barrier (rule #18).
__device__ __forceinline__ bf16x8 lds_read_b128(const bf16* p) {
  bf16x8 r;
  unsigned off = (unsigned)(unsigned long)(__attribute__((address_space(3))) bf16*)p;
  asm volatile("ds_read_b128 %0, %1" : "=v"(r) : "v"(off));
  return r;
}
// inline-asm barrier: bypasses compiler-inserted full waitcnt at S_BARRIER.
#define SBAR() asm volatile("s_barrier" ::: "memory")

// xor-chunk swizzle address maps (LDS side). Global tiles are plain row-major;
// the DMA staging permutes the per-lane SOURCE chunk so the LDS image matches:
// LDS[swz64(row,col)] = G[row][col].
__device__ __forceinline__ int swz64(int row, int col) {
  return row * 64 + ((((col >> 3) ^ row) & 7) << 3) + (col & 7);
}
__device__ __forceinline__ int swz128(int row, int col) {
  return row * 128 + (((col >> 3) ^ (row & 7)) << 3) + (col & 7);
}

// stage a row-major tile with 64 cols (bf16) into LDS with xor-chunk swizzle
__device__ __forceinline__ void stage64(const bf16* gsrc, bf16* lds, int tid, int nelem) {
  for (int i0 = 0; i0 < nelem; i0 += 2048) {
    int e = i0 + tid * 8;
    int row = e >> 6;
    int sc = ((tid & 7) ^ (row & 7)) << 3;
    gld_lds16((const void*)(gsrc + (row << 6) + sc), (void*)(lds + e));
  }
}
// 128-col variant
__device__ __forceinline__ void stage128(const bf16* gsrc, bf16* lds, int tid, int nelem) {
  for (int i0 = 0; i0 < nelem; i0 += 2048) {
    int e = i0 + tid * 8;
    int row = e >> 7;
    int sc = (((tid & 15) ^ (row & 7))) << 3;
    gld_lds16((const void*)(gsrc + (row << 7) + sc), (void*)(lds + e));
  }
}

// stage one 128row x 64col tile with 256 threads: 4 gld_lds per thread
__device__ __forceinline__ void stage_tileY(const bf16* g, bf16* l, int ldg, int tid) {
#pragma unroll
  for (int it = 0; it < 4; ++it) {
    int e = it * 2048 + tid * 8;
    int r = e >> 6;
    int sc = ((tid & 7) ^ (r & 7)) << 3;
    gld_lds16((const void*)(g + (long)r * ldg + sc), (void*)(l + e));
  }
}

// barrier-free inclusive scan of 128 values (each wave redundantly): a0=scan[lane], a1=scan[64+lane]
__device__ __forceinline__ void wave_scan128(float& a0, float& a1, int lane) {
#pragma unroll
  for (int off = 1; off < 64; off <<= 1) {
    float t0 = __shfl_up(a0, off);
    float t1 = __shfl_up(a1, off);
    if (lane >= off) { a0 += t0; a1 += t1; }
  }
  a1 += __shfl(a0, 63);
}

// ---------------- fused casts: hs, W1 (zero-padded to NPADN rows), Wo ----------------
// 8-elem chunks: 2x float4 in, 1x bf16x8 (16B) out.
__global__ __launch_bounds__(256) void cast_all_kernel(
    const float* __restrict__ hs, const float* __restrict__ w1, const float* __restrict__ wo,
    bf16* __restrict__ hs_b, bf16* __restrict__ w1_b, bf16* __restrict__ wo_b) {
  const long n1 = (long)ROWS * DMODEL / 8;
  const long n2 = (long)NPADN * DMODEL / 8;
  const long n3 = (long)DMODEL * DMODEL / 8;
  long total = n1 + n2 + n3;
  long stride = (long)gridDim.x * blockDim.x;
  for (long i = blockIdx.x * (long)blockDim.x + threadIdx.x; i < total; i += stride) {
    if (i < n1) {
      float4 v0 = ((const float4*)hs)[2 * i];
      float4 v1 = ((const float4*)hs)[2 * i + 1];
      ((bf16x8*)hs_b)[i] = bf16x8{(bf16)v0.x, (bf16)v0.y, (bf16)v0.z, (bf16)v0.w,
                                  (bf16)v1.x, (bf16)v1.y, (bf16)v1.z, (bf16)v1.w};
    } else if (i < n1 + n2) {
      long j = i - n1;
      int n = (int)((j * 8) >> 11);   // row of padded W1
      bf16x8 o = {};
      if (n < NPROJ) {
        float4 v0 = ((const float4*)w1)[2 * j];
        float4 v1 = ((const float4*)w1)[2 * j + 1];
        o = bf16x8{(bf16)v0.x, (bf16)v0.y, (bf16)v0.z, (bf16)v0.w,
                   (bf16)v1.x, (bf16)v1.y, (bf16)v1.z, (bf16)v1.w};
      }
      ((bf16x8*)w1_b)[j] = o;
    } else {
      long j = i - n1 - n2;
      float4 v0 = ((const float4*)wo)[2 * j];
      float4 v1 = ((const float4*)wo)[2 * j + 1];
      ((bf16x8*)wo_b)[j] = bf16x8{(bf16)v0.x, (bf16)v0.y, (bf16)v0.z, (bf16)v0.w,
                                  (bf16)v1.x, (bf16)v1.y, (bf16)v1.z, (bf16)v1.w};
    }
  }
}

// ---------------- GEMM: 128x128 tile, 256 thr, 64 KiB LDS => 2 blocks/CU ----------------
// Per K-tile: issue next-tile stage, asm ds_reads, lgkm(0), 32 MFMA, vmcnt(0), barrier.
// Wave-level overlap (2 co-resident blocks) hides the staging drain (m114 mechanism).
// At 4096x5248x2048: 92.4 us = 953 TF (round 7) — at the 128^2-structure ceiling.
template <typename OutT>
__global__ __launch_bounds__(256, 2) void gemm2p_kernel(
    const bf16* __restrict__ A, const bf16* __restrict__ B, OutT* __restrict__ C,
    int M, int N, int K, int ntx) {
  __shared__ __align__(16) bf16 As[2 * 128 * 64];
  __shared__ __align__(16) bf16 Bs[2 * 128 * 64];
  const int tid = threadIdx.x;
  const int lane = tid & 63;
  const int wave = tid >> 6;
  const int wm = wave >> 1, wn = wave & 1;

  const int GM = 8;
  int lid = blockIdx.x;
  {  // bijective XCD-chunk swizzle: XCD x owns contiguous tile-ids
    int nwg = gridDim.x;
    int xcd = lid & 7;
    int q = nwg >> 3, r = nwg & 7;
    lid = (xcd < r ? xcd * (q + 1) : r * (q + 1) + (xcd - r) * q) + (lid >> 3);
  }
  int group = GM * ntx;
  int gid = lid / group;
  int rem = lid - gid * group;
  int bm = gid * GM + (rem % GM);
  int bn = rem / GM;

  const bf16* Ag = A + (long)bm * 128 * K;
  const bf16* Bg = B + (long)bn * 128 * K;
  const int NT = K >> 6;

  const int fbA = (wm * 64 + (lane & 15)) * 64 + (((lane >> 4) ^ (lane & 7)) << 3);
  const int fbB = (wn * 64 + (lane & 15)) * 64 + (((lane >> 4) ^ (lane & 7)) << 3);

  f32x4 acc[4][4] = {};

  // prologue: tile 0 into buffer 0
  stage_tileY(Ag, As, K, tid);
  stage_tileY(Bg, Bs, K, tid);
  asm volatile("s_waitcnt vmcnt(0)" ::: "memory");
  SBAR();

  for (int t = 0; t < NT; ++t) {
    const int c = t & 1;
    const bf16* At = As + c * 8192;
    const bf16* Bt = Bs + c * 8192;
    if (t + 1 < NT) {   // issue next tile into the other buffer (read at t-1, barrier-cleared)
      stage_tileY(Ag + (t + 1) * 64, As + (c ^ 1) * 8192, K, tid);
      stage_tileY(Bg + (t + 1) * 64, Bs + (c ^ 1) * 8192, K, tid);
    }
    bf16x8 af[4][2], bf_[4][2];
#pragma unroll
    for (int mi = 0; mi < 4; ++mi)
#pragma unroll
      for (int ks = 0; ks < 2; ++ks)
        af[mi][ks] = lds_read_b128(At + ((fbA + mi * 1024) ^ (ks << 5)));
#pragma unroll
    for (int ni = 0; ni < 4; ++ni)
#pragma unroll
      for (int ks = 0; ks < 2; ++ks)
        bf_[ni][ks] = lds_read_b128(Bt + ((fbB + ni * 1024) ^ (ks << 5)));
    asm volatile("s_waitcnt lgkmcnt(0)" ::: "memory");
    __builtin_amdgcn_sched_barrier(0);
    __builtin_amdgcn_s_setprio(1);
#pragma unroll
    for (int mi = 0; mi < 4; ++mi)
#pragma unroll
      for (int ni = 0; ni < 4; ++ni)
#pragma unroll
        for (int ks = 0; ks < 2; ++ks)
          acc[mi][ni] = __builtin_amdgcn_mfma_f32_16x16x32_bf16(af[mi][ks], bf_[ni][ks], acc[mi][ni], 0, 0, 0);
    __builtin_amdgcn_s_setprio(0);
    asm volatile("s_waitcnt vmcnt(0)" ::: "memory");   // next tile resident (had full MFMA window)
    SBAR();
  }

#pragma unroll
  for (int mi = 0; mi < 4; ++mi) {
    int rbase = bm * 128 + wm * 64 + mi * 16 + (lane >> 4) * 4;
#pragma unroll
    for (int ni = 0; ni < 4; ++ni) {
      int col = bn * 128 + wn * 64 + ni * 16 + (lane & 15);
#pragma unroll
      for (int r = 0; r < 4; ++r)
        C[(long)(rbase + r) * N + col] = (OutT)acc[mi][ni][r];
    }
  }
}

// ---------------- fused conv K/V + dt + chunk-states (replaces prep + ssd_states) ----------------
// One block per (b, c, kvh), 256 threads = 4 waves; wave w owns head h = kvh*4 + w.
// Builds Ks/Vs LDS images directly (no Kt round-trip), writes Kc/Vt/dtb/adtb/asum for
// the downstream kernels, and computes states S_h[p][n] for its 4 heads via MFMA with
// the K-fragment scaled by w_h[j] = dt*exp(atot-acs) — bitwise the same rounding as
// the old in-LDS Ks scaling.
__global__ __launch_bounds__(256) void fused_kvs_kernel(
    const bf16* __restrict__ proj, const float* __restrict__ conv_w,
    const float* __restrict__ conv_b, const float* __restrict__ dt_bias,
    const float* __restrict__ A_log,
    bf16* __restrict__ Kc, bf16* __restrict__ Vt,
    float* __restrict__ dtb, float* __restrict__ adtb,
    float* __restrict__ states, float* __restrict__ asum) {
  __shared__ float tile[128][65];
  __shared__ __align__(16) bf16 Ks[64 * 128];
  __shared__ __align__(16) bf16 Vs[64 * 128];
  __shared__ float w4[4][128];

  int blk = blockIdx.x, tid = threadIdx.x;
  int kvh = blk & 7, c = (blk >> 3) & 15, b = blk >> 7;
  int lane = tid & 63, wave = tid >> 6;
  long rowbase = (long)b * LSEQ + c * CHUNK;
  long tb = (long)((b * 16 + c) * 8 + kvh) * 8192;

  int j = tid >> 1, p0 = (tid & 1) * 32;
  const bf16* cur = proj + (rowbase + j) * NPADN;
  bool hp = (c > 0) || (j > 0);

  // ---- K conv+SiLU -> tile[j][n] ----
  {
    int chb = 512 + kvh * 64;
#pragma unroll
    for (int pp = 0; pp < 32; pp += 4) {
      int p = p0 + pp, ch = chb + p;
      bf16x4 cu = *(const bf16x4*)(cur + ch);
      bf16x4 pv = {};
      if (hp) pv = *(const bf16x4*)(cur + ch - NPADN);
      float4 wa = *(const float4*)(conv_w + 2 * ch);
      float4 wb = *(const float4*)(conv_w + 2 * ch + 4);
      float4 bb = *(const float4*)(conv_b + ch);
      tile[j][p + 0] = fsilu((float)pv[0] * wa.x + (float)cu[0] * wa.y + bb.x);
      tile[j][p + 1] = fsilu((float)pv[1] * wa.z + (float)cu[1] * wa.w + bb.y);
      tile[j][p + 2] = fsilu((float)pv[2] * wb.x + (float)cu[2] * wb.y + bb.z);
      tile[j][p + 3] = fsilu((float)pv[3] * wb.z + (float)cu[3] * wb.w + bb.w);
    }
  }
  __syncthreads();
  // Kc (row-major [j][n]) to HBM + Ks swz128 image ([n][j]) in LDS
#pragma unroll
  for (int it = 0; it < 8; ++it) {
    int e = it * 1024 + tid * 4;
    int jj = e >> 6, n = e & 63;
    bf16x4 o = {(bf16)tile[jj][n], (bf16)tile[jj][n + 1], (bf16)tile[jj][n + 2], (bf16)tile[jj][n + 3]};
    *(bf16x4*)(Kc + tb + e) = o;
  }
#pragma unroll
  for (int it = 0; it < 8; ++it) {
    int e = it * 1024 + tid * 4;
    int n = e >> 7, jj = e & 127;
    bf16x4 o = {(bf16)tile[jj][n], (bf16)tile[jj + 1][n], (bf16)tile[jj + 2][n], (bf16)tile[jj + 3][n]};
    *(bf16x4*)(Ks + n * 128 + (((jj >> 3) ^ (n & 7)) << 3) + (jj & 7)) = o;
  }
  __syncthreads();   // tile fully consumed

  // ---- V conv+SiLU -> tile[j][p] ----
  {
    int chb = kvh * 64;
#pragma unroll
    for (int pp = 0; pp < 32; pp += 4) {
      int p = p0 + pp, ch = chb + p;
      bf16x4 cu = *(const bf16x4*)(cur + ch);
      bf16x4 pv = {};
      if (hp) pv = *(const bf16x4*)(cur + ch - NPADN);
      float4 wa = *(const float4*)(conv_w + 2 * ch);
      float4 wb = *(const float4*)(conv_w + 2 * ch + 4);
      float4 bb = *(const float4*)(conv_b + ch);
      tile[j][p + 0] = fsilu((float)pv[0] * wa.x + (float)cu[0] * wa.y + bb.x);
      tile[j][p + 1] = fsilu((float)pv[1] * wa.z + (float)cu[1] * wa.w + bb.y);
      tile[j][p + 2] = fsilu((float)pv[2] * wb.x + (float)cu[2] * wb.y + bb.z);
      tile[j][p + 3] = fsilu((float)pv[3] * wb.z + (float)cu[3] * wb.w + bb.w);
    }
  }
  __syncthreads();
  // Vt (row-major [p][j]) to HBM + Vs swz128 image in LDS
#pragma unroll
  for (int it = 0; it < 8; ++it) {
    int e = it * 1024 + tid * 4;
    int n = e >> 7, jj = e & 127;
    bf16x4 o = {(bf16)tile[jj][n], (bf16)tile[jj + 1][n], (bf16)tile[jj + 2][n], (bf16)tile[jj + 3][n]};
    *(bf16x4*)(Vt + tb + e) = o;
    *(bf16x4*)(Vs + n * 128 + (((jj >> 3) ^ (n & 7)) << 3) + (jj & 7)) = o;
  }

  // ---- per-wave dt/scan for head h = kvh*4 + wave ----
  int h = kvh * 4 + wave;
  {
    const bf16* dr = proj + (rowbase) * NPADN + (CONVD + DMODEL) + h;
    float raw0 = (float)dr[(long)lane * NPADN] + dt_bias[h];
    float raw1 = (float)dr[(long)(64 + lane) * NPADN] + dt_bias[h];
    float dt0 = fsoftplus(raw0), dt1 = fsoftplus(raw1);
    float mA = -__expf(A_log[h]);
    float a0 = mA * dt0, a1 = mA * dt1;
    long dbase = (long)((b * 16 + c) * 32 + h) * 128;
    dtb[dbase + lane] = dt0; dtb[dbase + 64 + lane] = dt1;
    adtb[dbase + lane] = a0; adtb[dbase + 64 + lane] = a1;
    wave_scan128(a0, a1, lane);
    float atot = __shfl(a1, 63);
    w4[wave][lane] = dt0 * __expf(atot - a0);
    w4[wave][64 + lane] = dt1 * __expf(atot - a1);
    if (lane == 0) asum[(b * NH + h) * NCHUNK + c] = atot;
  }
  __syncthreads();   // Vs/Ks images + w4 visible

  // ---- MFMA: wave computes S_h[p][n] = sum_j V[p][j] * (K[n][j]*w_h[j]) ----
  f32x4 acc[4][4] = {};
#pragma unroll
  for (int ks = 0; ks < CHUNK; ks += 32) {
    int j0 = ks + (lane >> 4) * 8;
    f32x4 wva = *(const f32x4*)&w4[wave][j0];
    f32x4 wvb = *(const f32x4*)&w4[wave][j0 + 4];
    bf16x8 vf[4], kf[4];
#pragma unroll
    for (int pi = 0; pi < 4; ++pi)
      vf[pi] = *(const bf16x8*)(Vs + swz128(pi * 16 + (lane & 15), j0));
#pragma unroll
    for (int ni = 0; ni < 4; ++ni) {
      bf16x8 kv = *(const bf16x8*)(Ks + swz128(ni * 16 + (lane & 15), j0));
      kv[0] = (bf16)((float)kv[0] * wva[0]); kv[1] = (bf16)((float)kv[1] * wva[1]);
      kv[2] = (bf16)((float)kv[2] * wva[2]); kv[3] = (bf16)((float)kv[3] * wva[3]);
      kv[4] = (bf16)((float)kv[4] * wvb[0]); kv[5] = (bf16)((float)kv[5] * wvb[1]);
      kv[6] = (bf16)((float)kv[6] * wvb[2]); kv[7] = (bf16)((float)kv[7] * wvb[3]);
      kf[ni] = kv;
    }
#pragma unroll
    for (int pi = 0; pi < 4; ++pi)
#pragma unroll
      for (int ni = 0; ni < 4; ++ni)
        acc[pi][ni] = __builtin_amdgcn_mfma_f32_16x16x32_bf16(vf[pi], kf[ni], acc[pi][ni], 0, 0, 0);
  }
  float* sout = states + (long)((b * 16 + c) * 32 + h) * (HD * HD);
#pragma unroll
  for (int pi = 0; pi < 4; ++pi)
#pragma unroll
    for (int ni = 0; ni < 4; ++ni) {
      int n = ni * 16 + (lane & 15);
#pragma unroll
      for (int r = 0; r < 4; ++r) {
        int p = pi * 16 + (lane >> 4) * 4 + r;
        sout[p * HD + n] = acc[pi][ni][r];
      }
    }
}

// ---------------- SSD phase B ----------------
__global__ __launch_bounds__(256) void ssd_scan_kernel(
    const float* __restrict__ states, const float* __restrict__ asum,
    bf16* __restrict__ sprevb) {
  int bid = blockIdx.x;
  int s = bid & 7, h = (bid >> 3) & 31, b = bid >> 8;
  int e0 = s * 512 + threadIdx.x;
  int e1 = e0 + 256;
  float S0 = 0.f, S1 = 0.f;
  const float* as = asum + (b * NH + h) * NCHUNK;
  for (int c = 0; c < NCHUNK; ++c) {
    long off = ((long)((b * NCHUNK + c) * NH + h)) * (HD * HD);
    float g = __expf(as[c]);
    sprevb[off + e0] = (bf16)S0;
    sprevb[off + e1] = (bf16)S1;
    S0 = S0 * g + states[off + e0];
    S1 = S1 * g + states[off + e1];
  }
}

// ---------------- SSD phase C (Q-conv fused in) ----------------
__global__ __launch_bounds__(256) void ssd_out_kernel(
    const bf16* __restrict__ Kc, const bf16* __restrict__ Vt,
    const bf16* __restrict__ sprevb, const float* __restrict__ dtb,
    const float* __restrict__ adtb, const bf16* __restrict__ proj,
    const float* __restrict__ conv_w, const float* __restrict__ conv_b,
    const float* __restrict__ gnw, bf16* __restrict__ yg) {
  __shared__ __align__(16) bf16 Qs[128 * 64];
  __shared__ __align__(16) bf16 KVs[128 * 64];
  __shared__ __align__(16) bf16 G[128 * 128];
  __shared__ __align__(16) bf16 Sps[64 * 64];
  __shared__ float acs[CHUNK];
  __shared__ float dts[CHUNK];
  __shared__ float part[CHUNK][2];
  __shared__ float rs_l[CHUNK];

  int bid = blockIdx.x;
  int h = bid & 31, c = (bid >> 5) & 15, b = bid >> 9;
  int kvh = h >> 2;
  int tid = threadIdx.x;
  int lane = tid & 63, wave = tid >> 6;
  int wm = wave >> 1, wn = wave & 1;
  long rowbase = (long)b * LSEQ + c * CHUNK;
  long kvb = (long)(((b * 16 + c) * 8) + kvh) * 8192;

  // issue DMA stages first so they overlap the Q-conv VALU below
  stage64(Kc + kvb, KVs, tid, 8192);
  stage64(sprevb + (long)bid * 4096, Sps, tid, 4096);

  // --- inline Q build: Qs[swz64(j,col)] = silu(conv(proj Q-slice)) ---
  {
    int j = tid >> 1, p0 = (tid & 1) * 32;
    const bf16* cur = proj + (rowbase + j) * NPADN;
    bool hp = (c > 0) || (j > 0);
    int chb = 1024 + h * 64;
    bf16* qrow = Qs + j * 64;
#pragma unroll
    for (int pp = 0; pp < 32; pp += 4) {
      int p = p0 + pp, ch = chb + p;
      bf16x4 cu = *(const bf16x4*)(cur + ch);
      bf16x4 pv = {};
      if (hp) pv = *(const bf16x4*)(cur + ch - NPADN);
      float4 wa = *(const float4*)(conv_w + 2 * ch);
      float4 wb = *(const float4*)(conv_w + 2 * ch + 4);
      float4 bb = *(const float4*)(conv_b + ch);
      bf16x4 o;
      o[0] = (bf16)fsilu((float)pv[0] * wa.x + (float)cu[0] * wa.y + bb.x);
      o[1] = (bf16)fsilu((float)pv[1] * wa.z + (float)cu[1] * wa.w + bb.y);
      o[2] = (bf16)fsilu((float)pv[2] * wb.x + (float)cu[2] * wb.y + bb.z);
      o[3] = (bf16)fsilu((float)pv[3] * wb.z + (float)cu[3] * wb.w + bb.w);
      *(bf16x4*)(qrow + ((((p >> 3) ^ j) & 7) << 3) + (p & 7)) = o;
    }
  }

  float a0 = adtb[(long)bid * 128 + lane];
  float a1 = adtb[(long)bid * 128 + 64 + lane];
  float d0 = dtb[(long)bid * 128 + lane];
  float d1 = dtb[(long)bid * 128 + 64 + lane];
  wave_scan128(a0, a1, lane);
  if (wave == 0) {
    acs[lane] = a0; acs[64 + lane] = a1;
    dts[lane] = d0; dts[64 + lane] = d1;
  }
  __syncthreads();   // DMA drained + Q writes + scan visible

  {
    f32x4 gacc[4][4] = {};
#pragma unroll
    for (int ks = 0; ks < HD; ks += 32) {
      bf16x8 af[4], bf_[4];
#pragma unroll
      for (int mi = 0; mi < 4; ++mi)
        af[mi] = *(const bf16x8*)(Qs + swz64(wm * 64 + mi * 16 + (lane & 15), ks + (lane >> 4) * 8));
#pragma unroll
      for (int ni = 0; ni < 4; ++ni)
        bf_[ni] = *(const bf16x8*)(KVs + swz64(wn * 64 + ni * 16 + (lane & 15), ks + (lane >> 4) * 8));
#pragma unroll
      for (int mi = 0; mi < 4; ++mi)
#pragma unroll
        for (int ni = 0; ni < 4; ++ni)
          gacc[mi][ni] = __builtin_amdgcn_mfma_f32_16x16x32_bf16(af[mi], bf_[ni], gacc[mi][ni], 0, 0, 0);
    }
    float aj[4], dj[4];
#pragma unroll
    for (int ni = 0; ni < 4; ++ni) {
      int j = wn * 64 + ni * 16 + (lane & 15);
      aj[ni] = acs[j];
      dj[ni] = dts[j];
    }
#pragma unroll
    for (int mi = 0; mi < 4; ++mi) {
#pragma unroll
      for (int r = 0; r < 4; ++r) {
        int i = wm * 64 + mi * 16 + (lane >> 4) * 4 + r;
        float ai = acs[i];
#pragma unroll
        for (int ni = 0; ni < 4; ++ni) {
          int j = wn * 64 + ni * 16 + (lane & 15);
          float gv = (j <= i) ? gacc[mi][ni][r] * __expf(ai - aj[ni]) * dj[ni] : 0.f;
          G[swz128(i, j)] = (bf16)gv;
        }
      }
    }
  }
  __syncthreads();

  stage128(Vt + kvb, KVs, tid, 8192);
  __syncthreads();

  f32x4 yacc[4][2] = {};
  f32x4 oacc[4][2] = {};
#pragma unroll
  for (int ks = 0; ks < CHUNK; ks += 32) {
    bf16x8 af[4], bf_[2];
#pragma unroll
    for (int mi = 0; mi < 4; ++mi)
      af[mi] = *(const bf16x8*)(G + swz128(wm * 64 + mi * 16 + (lane & 15), ks + (lane >> 4) * 8));
#pragma unroll
    for (int ni = 0; ni < 2; ++ni)
      bf_[ni] = *(const bf16x8*)(KVs + swz128(wn * 32 + ni * 16 + (lane & 15), ks + (lane >> 4) * 8));
#pragma unroll
    for (int mi = 0; mi < 4; ++mi)
#pragma unroll
      for (int ni = 0; ni < 2; ++ni)
        yacc[mi][ni] = __builtin_amdgcn_mfma_f32_16x16x32_bf16(af[mi], bf_[ni], yacc[mi][ni], 0, 0, 0);
  }
#pragma unroll
  for (int ks = 0; ks < HD; ks += 32) {
    bf16x8 af[4], bf_[2];
#pragma unroll
    for (int mi = 0; mi < 4; ++mi)
      af[mi] = *(const bf16x8*)(Qs + swz64(wm * 64 + mi * 16 + (lane & 15), ks + (lane >> 4) * 8));
#pragma unroll
    for (int ni = 0; ni < 2; ++ni)
      bf_[ni] = *(const bf16x8*)(Sps + swz64(wn * 32 + ni * 16 + (lane & 15), ks + (lane >> 4) * 8));
#pragma unroll
    for (int mi = 0; mi < 4; ++mi)
#pragma unroll
      for (int ni = 0; ni < 2; ++ni)
        oacc[mi][ni] = __builtin_amdgcn_mfma_f32_16x16x32_bf16(af[mi], bf_[ni], oacc[mi][ni], 0, 0, 0);
  }

  float yv[4][2][4];
#pragma unroll
  for (int mi = 0; mi < 4; ++mi) {
#pragma unroll
    for (int r = 0; r < 4; ++r) {
      int i = wm * 64 + mi * 16 + (lane >> 4) * 4 + r;
      float ei = __expf(acs[i]);
      float s = 0.f;
#pragma unroll
      for (int ni = 0; ni < 2; ++ni) {
        float v = yacc[mi][ni][r] + ei * oacc[mi][ni][r];
        yv[mi][ni][r] = v;
        s += v * v;
      }
      s += __shfl_xor(s, 1, 64);
      s += __shfl_xor(s, 2, 64);
      s += __shfl_xor(s, 4, 64);
      s += __shfl_xor(s, 8, 64);
      if ((lane & 15) == 0) part[i][wn] = s;
    }
  }
  __syncthreads();

  for (int i0 = 0; i0 < 8192; i0 += 2048) {
    int e = i0 + tid * 8;
    int row = e >> 6;
    int sc = ((tid & 7) ^ (row & 7)) << 3;
    gld_lds16((const void*)(proj + (rowbase + row) * NPADN + CONVD + h * 64 + sc),
              (void*)(KVs + e));
  }
  if (tid < CHUNK) rs_l[tid] = rsqrtf((part[tid][0] + part[tid][1]) * (1.0f / HD) + EPSF);
  __syncthreads();

#pragma unroll
  for (int mi = 0; mi < 4; ++mi) {
#pragma unroll
    for (int r = 0; r < 4; ++r) {
      int i = wm * 64 + mi * 16 + (lane >> 4) * 4 + r;
      long row = rowbase + i;
      float rs = rs_l[i];
#pragma unroll
      for (int ni = 0; ni < 2; ++ni) {
        int p = wn * 32 + ni * 16 + (lane & 15);
        float gval = (float)KVs[swz64(i, p)];
        float val = yv[mi][ni][r] * rs * gnw[p] * fsilu(gval);
        yg[row * (long)DMODEL + h * HD + p] = (bf16)val;
      }
    }
  }
}

// ---------------- launch ----------------
extern "C" void kernel_launch(void* const* d_in, const int* in_sizes, int n_in,
                              void* d_out, int out_size, void* d_ws, size_t ws_size,
                              hipStream_t stream) {
  const float* hs      = (const float*)d_in[0];
  const float* W1      = (const float*)d_in[1];
  const float* conv_w  = (const float*)d_in[2];
  const float* conv_b  = (const float*)d_in[3];
  const float* dt_bias = (const float*)d_in[4];
  const float* A_log   = (const float*)d_in[5];
  const float* gnw     = (const float*)d_in[6];
  const float* Wo      = (const float*)d_in[7];

  char* p = (char*)d_ws;
  bf16* hs_b   = (bf16*)p;  p += (long)ROWS * DMODEL * 2;
  bf16* w1_b   = (bf16*)p;  p += (long)NPADN * DMODEL * 2;
  bf16* wo_b   = (bf16*)p;  p += (long)DMODEL * DMODEL * 2;
  bf16* proj   = (bf16*)p;  p += (long)ROWS * NPADN * 2;
  bf16* Kc     = (bf16*)p;  p += (long)256 * 8192 * 2;
  bf16* Vt     = (bf16*)p;  p += (long)256 * 8192 * 2;
  float* dtb   = (float*)p; p += (long)ROWS * NH * 4;
  float* adtb  = (float*)p; p += (long)ROWS * NH * 4;
  float* st    = (float*)p; p += (long)NB * NCHUNK * NH * HD * HD * 4;
  bf16* sprevb = (bf16*)p;  p += (long)NB * NCHUNK * NH * HD * HD * 2;
  float* asum  = (float*)p; p += (long)NB * NH * NCHUNK * 4;
  bf16* yg     = (bf16*)p;  p += (long)ROWS * DMODEL * 2;

  cast_all_kernel<<<4096, 256, 0, stream>>>(hs, W1, Wo, hs_b, w1_b, wo_b);

  gemm2p_kernel<bf16><<<(ROWS / 128) * (NPADN / 128), 256, 0, stream>>>(
      hs_b, w1_b, proj, ROWS, NPADN, DMODEL, NPADN / 128);

  fused_kvs_kernel<<<NB * NCHUNK * NKVH, 256, 0, stream>>>(
      proj, conv_w, conv_b, dt_bias, A_log, Kc, Vt, dtb, adtb, st, asum);

  ssd_scan_kernel<<<NB * NH * 8, 256, 0, stream>>>(st, asum, sprevb);
  ssd_out_kernel<<<NB * NCHUNK * NH, 256, 0, stream>>>(
      Kc, Vt, sprevb, dtb, adtb, proj, conv_w, conv_b, gnw, yg);

  gemm2p_kernel<float><<<(ROWS / 128) * (DMODEL / 128), 256, 0, stream>>>(
      yg, wo_b, (float*)d_out, ROWS, DMODEL, DMODEL, DMODEL / 128);
}

// Round 10
// 317.433 us; speedup vs baseline: 1.2028x; 1.0302x over previous
//
#include <hip/hip_runtime.h>
#include <hip/hip_bf16.h>
#include <math.h>

typedef __bf16 bf16;
typedef __bf16 bf16x4 __attribute__((ext_vector_type(4)));
typedef __bf16 bf16x8 __attribute__((ext_vector_type(8)));
typedef float f32x4 __attribute__((ext_vector_type(4)));

#define NB 2
#define LSEQ 2048
#define NH 32
#define NKVH 8
#define HD 64
#define DMODEL 2048
#define CONVD 3072
#define NPROJ 5152
#define NPADN 5248
#define NCHUNK 16
#define CHUNK 128
#define ROWS 4096
#define EPSF 1e-5f

__device__ __forceinline__ float fsilu(float x) { return x / (1.0f + __expf(-x)); }
__device__ __forceinline__ float fsoftplus(float raw) {
  return (raw > 20.0f) ? raw : log1pf(__expf(raw));
}

__device__ __forceinline__ void gld_lds16(const void* g, void* l) {
  __builtin_amdgcn_global_load_lds(
      (const __attribute__((address_space(1))) void*)g,
      (__attribute__((address_space(3))) void*)l, 16, 0, 0);
}

// inline-asm ds_read_b128: opaque to the compiler's hazard/waitcnt insertion.
// Caller MUST pair with explicit s_waitcnt lgkmcnt + sched_barrier (rule #18).
__device__ __forceinline__ bf16x8 lds_read_b128(const bf16* p) {
  bf16x8 r;
  unsigned off = (unsigned)(unsigned long)(__attribute__((address_space(3))) bf16*)p;
  asm volatile("ds_read_b128 %0, %1" : "=v"(r) : "v"(off));
  return r;
}
// inline-asm barrier: bypasses compiler-inserted full waitcnt at S_BARRIER.
#define SBAR() asm volatile("s_barrier" ::: "memory")

// xor-chunk swizzle address maps (LDS side). Global tiles are plain row-major;
// the DMA staging permutes the per-lane SOURCE chunk so the LDS image matches:
// LDS[swz64(row,col)] = G[row][col].
__device__ __forceinline__ int swz64(int row, int col) {
  return row * 64 + ((((col >> 3) ^ row) & 7) << 3) + (col & 7);
}
__device__ __forceinline__ int swz128(int row, int col) {
  return row * 128 + (((col >> 3) ^ (row & 7)) << 3) + (col & 7);
}

// stage a row-major tile with 64 cols (bf16) into LDS with xor-chunk swizzle
__device__ __forceinline__ void stage64(const bf16* gsrc, bf16* lds, int tid, int nelem) {
  for (int i0 = 0; i0 < nelem; i0 += 2048) {
    int e = i0 + tid * 8;
    int row = e >> 6;
    int sc = ((tid & 7) ^ (row & 7)) << 3;
    gld_lds16((const void*)(gsrc + (row << 6) + sc), (void*)(lds + e));
  }
}
// 128-col variant
__device__ __forceinline__ void stage128(const bf16* gsrc, bf16* lds, int tid, int nelem) {
  for (int i0 = 0; i0 < nelem; i0 += 2048) {
    int e = i0 + tid * 8;
    int row = e >> 7;
    int sc = (((tid & 15) ^ (row & 7))) << 3;
    gld_lds16((const void*)(gsrc + (row << 7) + sc), (void*)(lds + e));
  }
}

// stage one 128row x 64col tile with 256 threads: 4 gld_lds per thread
__device__ __forceinline__ void stage_tileY(const bf16* g, bf16* l, int ldg, int tid) {
#pragma unroll
  for (int it = 0; it < 4; ++it) {
    int e = it * 2048 + tid * 8;
    int r = e >> 6;
    int sc = ((tid & 7) ^ (r & 7)) << 3;
    gld_lds16((const void*)(g + (long)r * ldg + sc), (void*)(l + e));
  }
}

// barrier-free inclusive scan of 128 values (each wave redundantly): a0=scan[lane], a1=scan[64+lane]
__device__ __forceinline__ void wave_scan128(float& a0, float& a1, int lane) {
#pragma unroll
  for (int off = 1; off < 64; off <<= 1) {
    float t0 = __shfl_up(a0, off);
    float t1 = __shfl_up(a1, off);
    if (lane >= off) { a0 += t0; a1 += t1; }
  }
  a1 += __shfl(a0, 63);
}

// 8-wide conv+SiLU helper: returns silu(prev*w0 + cur*w1 + b) for 8 channels at ch
// (conv_w layout: [ch][2]; all addresses 16B-aligned for p % 8 == 0)
__device__ __forceinline__ void conv8(const bf16* cur, bool hp, int ch,
                                      const float* conv_w, const float* conv_b,
                                      float out[8]) {
  bf16x8 cu = *(const bf16x8*)(cur + ch);
  bf16x8 pv = {};
  if (hp) pv = *(const bf16x8*)(cur + ch - NPADN);
  float4 w01 = *(const float4*)(conv_w + 2 * ch);
  float4 w23 = *(const float4*)(conv_w + 2 * ch + 4);
  float4 w45 = *(const float4*)(conv_w + 2 * ch + 8);
  float4 w67 = *(const float4*)(conv_w + 2 * ch + 12);
  float4 b03 = *(const float4*)(conv_b + ch);
  float4 b47 = *(const float4*)(conv_b + ch + 4);
  out[0] = fsilu((float)pv[0] * w01.x + (float)cu[0] * w01.y + b03.x);
  out[1] = fsilu((float)pv[1] * w01.z + (float)cu[1] * w01.w + b03.y);
  out[2] = fsilu((float)pv[2] * w23.x + (float)cu[2] * w23.y + b03.z);
  out[3] = fsilu((float)pv[3] * w23.z + (float)cu[3] * w23.w + b03.w);
  out[4] = fsilu((float)pv[4] * w45.x + (float)cu[4] * w45.y + b47.x);
  out[5] = fsilu((float)pv[5] * w45.z + (float)cu[5] * w45.w + b47.y);
  out[6] = fsilu((float)pv[6] * w67.x + (float)cu[6] * w67.y + b47.z);
  out[7] = fsilu((float)pv[7] * w67.z + (float)cu[7] * w67.w + b47.w);
}

// ---------------- fused casts: hs, W1 (zero-padded to NPADN rows), Wo ----------------
// 8-elem chunks: 2x float4 in, 1x bf16x8 (16B) out.
__global__ __launch_bounds__(256) void cast_all_kernel(
    const float* __restrict__ hs, const float* __restrict__ w1, const float* __restrict__ wo,
    bf16* __restrict__ hs_b, bf16* __restrict__ w1_b, bf16* __restrict__ wo_b) {
  const long n1 = (long)ROWS * DMODEL / 8;
  const long n2 = (long)NPADN * DMODEL / 8;
  const long n3 = (long)DMODEL * DMODEL / 8;
  long total = n1 + n2 + n3;
  long stride = (long)gridDim.x * blockDim.x;
  for (long i = blockIdx.x * (long)blockDim.x + threadIdx.x; i < total; i += stride) {
    if (i < n1) {
      float4 v0 = ((const float4*)hs)[2 * i];
      float4 v1 = ((const float4*)hs)[2 * i + 1];
      ((bf16x8*)hs_b)[i] = bf16x8{(bf16)v0.x, (bf16)v0.y, (bf16)v0.z, (bf16)v0.w,
                                  (bf16)v1.x, (bf16)v1.y, (bf16)v1.z, (bf16)v1.w};
    } else if (i < n1 + n2) {
      long j = i - n1;
      int n = (int)((j * 8) >> 11);   // row of padded W1
      bf16x8 o = {};
      if (n < NPROJ) {
        float4 v0 = ((const float4*)w1)[2 * j];
        float4 v1 = ((const float4*)w1)[2 * j + 1];
        o = bf16x8{(bf16)v0.x, (bf16)v0.y, (bf16)v0.z, (bf16)v0.w,
                   (bf16)v1.x, (bf16)v1.y, (bf16)v1.z, (bf16)v1.w};
      }
      ((bf16x8*)w1_b)[j] = o;
    } else {
      long j = i - n1 - n2;
      float4 v0 = ((const float4*)wo)[2 * j];
      float4 v1 = ((const float4*)wo)[2 * j + 1];
      ((bf16x8*)wo_b)[j] = bf16x8{(bf16)v0.x, (bf16)v0.y, (bf16)v0.z, (bf16)v0.w,
                                  (bf16)v1.x, (bf16)v1.y, (bf16)v1.z, (bf16)v1.w};
    }
  }
}

// ---------------- GEMM: 128x128 tile, 256 thr, 64 KiB LDS => 2 blocks/CU ----------------
// Per K-tile: issue next-tile stage, asm ds_reads, lgkm(0), 32 MFMA, vmcnt(0), barrier.
// Wave-level overlap (2 co-resident blocks) hides the staging drain (m114 mechanism).
// At 4096x5248x2048: 92.4 us = 953 TF (round 7) — at the 128^2-structure ceiling.
template <typename OutT>
__global__ __launch_bounds__(256, 2) void gemm2p_kernel(
    const bf16* __restrict__ A, const bf16* __restrict__ B, OutT* __restrict__ C,
    int M, int N, int K, int ntx) {
  __shared__ __align__(16) bf16 As[2 * 128 * 64];
  __shared__ __align__(16) bf16 Bs[2 * 128 * 64];
  const int tid = threadIdx.x;
  const int lane = tid & 63;
  const int wave = tid >> 6;
  const int wm = wave >> 1, wn = wave & 1;

  const int GM = 8;
  int lid = blockIdx.x;
  {  // bijective XCD-chunk swizzle: XCD x owns contiguous tile-ids
    int nwg = gridDim.x;
    int xcd = lid & 7;
    int q = nwg >> 3, r = nwg & 7;
    lid = (xcd < r ? xcd * (q + 1) : r * (q + 1) + (xcd - r) * q) + (lid >> 3);
  }
  int group = GM * ntx;
  int gid = lid / group;
  int rem = lid - gid * group;
  int bm = gid * GM + (rem % GM);
  int bn = rem / GM;

  const bf16* Ag = A + (long)bm * 128 * K;
  const bf16* Bg = B + (long)bn * 128 * K;
  const int NT = K >> 6;

  const int fbA = (wm * 64 + (lane & 15)) * 64 + (((lane >> 4) ^ (lane & 7)) << 3);
  const int fbB = (wn * 64 + (lane & 15)) * 64 + (((lane >> 4) ^ (lane & 7)) << 3);

  f32x4 acc[4][4] = {};

  // prologue: tile 0 into buffer 0
  stage_tileY(Ag, As, K, tid);
  stage_tileY(Bg, Bs, K, tid);
  asm volatile("s_waitcnt vmcnt(0)" ::: "memory");
  SBAR();

  for (int t = 0; t < NT; ++t) {
    const int c = t & 1;
    const bf16* At = As + c * 8192;
    const bf16* Bt = Bs + c * 8192;
    if (t + 1 < NT) {   // issue next tile into the other buffer (read at t-1, barrier-cleared)
      stage_tileY(Ag + (t + 1) * 64, As + (c ^ 1) * 8192, K, tid);
      stage_tileY(Bg + (t + 1) * 64, Bs + (c ^ 1) * 8192, K, tid);
    }
    bf16x8 af[4][2], bf_[4][2];
#pragma unroll
    for (int mi = 0; mi < 4; ++mi)
#pragma unroll
      for (int ks = 0; ks < 2; ++ks)
        af[mi][ks] = lds_read_b128(At + ((fbA + mi * 1024) ^ (ks << 5)));
#pragma unroll
    for (int ni = 0; ni < 4; ++ni)
#pragma unroll
      for (int ks = 0; ks < 2; ++ks)
        bf_[ni][ks] = lds_read_b128(Bt + ((fbB + ni * 1024) ^ (ks << 5)));
    asm volatile("s_waitcnt lgkmcnt(0)" ::: "memory");
    __builtin_amdgcn_sched_barrier(0);
    __builtin_amdgcn_s_setprio(1);
#pragma unroll
    for (int mi = 0; mi < 4; ++mi)
#pragma unroll
      for (int ni = 0; ni < 4; ++ni)
#pragma unroll
        for (int ks = 0; ks < 2; ++ks)
          acc[mi][ni] = __builtin_amdgcn_mfma_f32_16x16x32_bf16(af[mi][ks], bf_[ni][ks], acc[mi][ni], 0, 0, 0);
    __builtin_amdgcn_s_setprio(0);
    asm volatile("s_waitcnt vmcnt(0)" ::: "memory");   // next tile resident (had full MFMA window)
    SBAR();
  }

#pragma unroll
  for (int mi = 0; mi < 4; ++mi) {
    int rbase = bm * 128 + wm * 64 + mi * 16 + (lane >> 4) * 4;
#pragma unroll
    for (int ni = 0; ni < 4; ++ni) {
      int col = bn * 128 + wn * 64 + ni * 16 + (lane & 15);
#pragma unroll
      for (int r = 0; r < 4; ++r)
        C[(long)(rbase + r) * N + col] = (OutT)acc[mi][ni][r];
    }
  }
}

// ---------------- fused conv K/V + dt + chunk-states (replaces prep + ssd_states) ----------------
// One block per (b, c, kvh), 256 threads = 4 waves; wave w owns head h = kvh*4 + w.
__global__ __launch_bounds__(256) void fused_kvs_kernel(
    const bf16* __restrict__ proj, const float* __restrict__ conv_w,
    const float* __restrict__ conv_b, const float* __restrict__ dt_bias,
    const float* __restrict__ A_log,
    bf16* __restrict__ Kc, bf16* __restrict__ Vt,
    float* __restrict__ dtb, float* __restrict__ adtb,
    float* __restrict__ states, float* __restrict__ asum) {
  __shared__ float tile[128][65];
  __shared__ __align__(16) bf16 Ks[64 * 128];
  __shared__ __align__(16) bf16 Vs[64 * 128];
  __shared__ float w4[4][128];

  int blk = blockIdx.x, tid = threadIdx.x;
  int kvh = blk & 7, c = (blk >> 3) & 15, b = blk >> 7;
  int lane = tid & 63, wave = tid >> 6;
  long rowbase = (long)b * LSEQ + c * CHUNK;
  long tb = (long)((b * 16 + c) * 8 + kvh) * 8192;

  int j = tid >> 1, p0 = (tid & 1) * 32;
  const bf16* cur = proj + (rowbase + j) * NPADN;
  bool hp = (c > 0) || (j > 0);

  // ---- K conv+SiLU -> tile[j][n] ----
  {
    int chb = 512 + kvh * 64;
#pragma unroll
    for (int pp = 0; pp < 32; pp += 8) {
      int p = p0 + pp;
      float o[8];
      conv8(cur, hp, chb + p, conv_w, conv_b, o);
#pragma unroll
      for (int u = 0; u < 8; ++u) tile[j][p + u] = o[u];
    }
  }
  __syncthreads();
  // Kc (row-major [j][n]) to HBM + Ks swz128 image ([n][j]) in LDS
#pragma unroll
  for (int it = 0; it < 8; ++it) {
    int e = it * 1024 + tid * 4;
    int jj = e >> 6, n = e & 63;
    bf16x4 o = {(bf16)tile[jj][n], (bf16)tile[jj][n + 1], (bf16)tile[jj][n + 2], (bf16)tile[jj][n + 3]};
    *(bf16x4*)(Kc + tb + e) = o;
  }
#pragma unroll
  for (int it = 0; it < 8; ++it) {
    int e = it * 1024 + tid * 4;
    int n = e >> 7, jj = e & 127;
    bf16x4 o = {(bf16)tile[jj][n], (bf16)tile[jj + 1][n], (bf16)tile[jj + 2][n], (bf16)tile[jj + 3][n]};
    *(bf16x4*)(Ks + n * 128 + (((jj >> 3) ^ (n & 7)) << 3) + (jj & 7)) = o;
  }
  __syncthreads();   // tile fully consumed

  // ---- V conv+SiLU -> tile[j][p] ----
  {
    int chb = kvh * 64;
#pragma unroll
    for (int pp = 0; pp < 32; pp += 8) {
      int p = p0 + pp;
      float o[8];
      conv8(cur, hp, chb + p, conv_w, conv_b, o);
#pragma unroll
      for (int u = 0; u < 8; ++u) tile[j][p + u] = o[u];
    }
  }
  __syncthreads();
  // Vt (row-major [p][j]) to HBM + Vs swz128 image in LDS
#pragma unroll
  for (int it = 0; it < 8; ++it) {
    int e = it * 1024 + tid * 4;
    int n = e >> 7, jj = e & 127;
    bf16x4 o = {(bf16)tile[jj][n], (bf16)tile[jj + 1][n], (bf16)tile[jj + 2][n], (bf16)tile[jj + 3][n]};
    *(bf16x4*)(Vt + tb + e) = o;
    *(bf16x4*)(Vs + n * 128 + (((jj >> 3) ^ (n & 7)) << 3) + (jj & 7)) = o;
  }

  // ---- per-wave dt/scan for head h = kvh*4 + wave ----
  int h = kvh * 4 + wave;
  {
    const bf16* dr = proj + (rowbase) * NPADN + (CONVD + DMODEL) + h;
    float raw0 = (float)dr[(long)lane * NPADN] + dt_bias[h];
    float raw1 = (float)dr[(long)(64 + lane) * NPADN] + dt_bias[h];
    float dt0 = fsoftplus(raw0), dt1 = fsoftplus(raw1);
    float mA = -__expf(A_log[h]);
    float a0 = mA * dt0, a1 = mA * dt1;
    long dbase = (long)((b * 16 + c) * 32 + h) * 128;
    dtb[dbase + lane] = dt0; dtb[dbase + 64 + lane] = dt1;
    adtb[dbase + lane] = a0; adtb[dbase + 64 + lane] = a1;
    wave_scan128(a0, a1, lane);
    float atot = __shfl(a1, 63);
    w4[wave][lane] = dt0 * __expf(atot - a0);
    w4[wave][64 + lane] = dt1 * __expf(atot - a1);
    if (lane == 0) asum[(b * NH + h) * NCHUNK + c] = atot;
  }
  __syncthreads();   // Vs/Ks images + w4 visible

  // ---- MFMA: wave computes S_h[p][n] = sum_j V[p][j] * (K[n][j]*w_h[j]) ----
  f32x4 acc[4][4] = {};
#pragma unroll
  for (int ks = 0; ks < CHUNK; ks += 32) {
    int j0 = ks + (lane >> 4) * 8;
    f32x4 wva = *(const f32x4*)&w4[wave][j0];
    f32x4 wvb = *(const f32x4*)&w4[wave][j0 + 4];
    bf16x8 vf[4], kf[4];
#pragma unroll
    for (int pi = 0; pi < 4; ++pi)
      vf[pi] = *(const bf16x8*)(Vs + swz128(pi * 16 + (lane & 15), j0));
#pragma unroll
    for (int ni = 0; ni < 4; ++ni) {
      bf16x8 kv = *(const bf16x8*)(Ks + swz128(ni * 16 + (lane & 15), j0));
      kv[0] = (bf16)((float)kv[0] * wva[0]); kv[1] = (bf16)((float)kv[1] * wva[1]);
      kv[2] = (bf16)((float)kv[2] * wva[2]); kv[3] = (bf16)((float)kv[3] * wva[3]);
      kv[4] = (bf16)((float)kv[4] * wvb[0]); kv[5] = (bf16)((float)kv[5] * wvb[1]);
      kv[6] = (bf16)((float)kv[6] * wvb[2]); kv[7] = (bf16)((float)kv[7] * wvb[3]);
      kf[ni] = kv;
    }
#pragma unroll
    for (int pi = 0; pi < 4; ++pi)
#pragma unroll
      for (int ni = 0; ni < 4; ++ni)
        acc[pi][ni] = __builtin_amdgcn_mfma_f32_16x16x32_bf16(vf[pi], kf[ni], acc[pi][ni], 0, 0, 0);
  }
  float* sout = states + (long)((b * 16 + c) * 32 + h) * (HD * HD);
#pragma unroll
  for (int pi = 0; pi < 4; ++pi)
#pragma unroll
    for (int ni = 0; ni < 4; ++ni) {
      int n = ni * 16 + (lane & 15);
#pragma unroll
      for (int r = 0; r < 4; ++r) {
        int p = pi * 16 + (lane >> 4) * 4 + r;
        sout[p * HD + n] = acc[pi][ni][r];
      }
    }
}

// ---------------- SSD phase B ----------------
__global__ __launch_bounds__(256) void ssd_scan_kernel(
    const float* __restrict__ states, const float* __restrict__ asum,
    bf16* __restrict__ sprevb) {
  int bid = blockIdx.x;
  int s = bid & 7, h = (bid >> 3) & 31, b = bid >> 8;
  int e0 = s * 512 + threadIdx.x;
  int e1 = e0 + 256;
  float S0 = 0.f, S1 = 0.f;
  const float* as = asum + (b * NH + h) * NCHUNK;
#pragma unroll
  for (int c = 0; c < NCHUNK; ++c) {
    long off = ((long)((b * NCHUNK + c) * NH + h)) * (HD * HD);
    float g = __expf(as[c]);
    sprevb[off + e0] = (bf16)S0;
    sprevb[off + e1] = (bf16)S1;
    S0 = S0 * g + states[off + e0];
    S1 = S1 * g + states[off + e1];
  }
}

// ---------------- SSD phase C (Q-conv fused; XCD-swizzled for Kc/Vt L2 reuse) ----------------
__global__ __launch_bounds__(256) void ssd_out_kernel(
    const bf16* __restrict__ Kc, const bf16* __restrict__ Vt,
    const bf16* __restrict__ sprevb, const float* __restrict__ dtb,
    const float* __restrict__ adtb, const bf16* __restrict__ proj,
    const float* __restrict__ conv_w, const float* __restrict__ conv_b,
    const float* __restrict__ gnw, bf16* __restrict__ yg) {
  __shared__ __align__(16) bf16 Qs[128 * 64];
  __shared__ __align__(16) bf16 KVs[128 * 64];
  __shared__ __align__(16) bf16 G[128 * 128];
  __shared__ __align__(16) bf16 Sps[64 * 64];
  __shared__ float acs[CHUNK];
  __shared__ float dts[CHUNK];
  __shared__ float part[CHUNK][2];
  __shared__ float rs_l[CHUNK];

  int bid = blockIdx.x;
  {  // bijective XCD-chunk swizzle (nwg = 1024, divisible by 8): the 4 heads
     // sharing each (b,c,kvh) Kc/Vt tile land on ONE XCD -> L2 hits (T1).
    int q = gridDim.x >> 3;
    bid = (bid & 7) * q + (bid >> 3);
  }
  int h = bid & 31, c = (bid >> 5) & 15, b = bid >> 9;
  int kvh = h >> 2;
  int tid = threadIdx.x;
  int lane = tid & 63, wave = tid >> 6;
  int wm = wave >> 1, wn = wave & 1;
  long rowbase = (long)b * LSEQ + c * CHUNK;
  long kvb = (long)(((b * 16 + c) * 8) + kvh) * 8192;

  // issue DMA stages first so they overlap the Q-conv VALU below
  stage64(Kc + kvb, KVs, tid, 8192);
  stage64(sprevb + (long)bid * 4096, Sps, tid, 4096);

  // --- inline Q build: Qs[swz64(j,col)] = silu(conv(proj Q-slice)) ---
  {
    int j = tid >> 1, p0 = (tid & 1) * 32;
    const bf16* cur = proj + (rowbase + j) * NPADN;
    bool hp = (c > 0) || (j > 0);
    int chb = 1024 + h * 64;
    bf16* qrow = Qs + j * 64;
#pragma unroll
    for (int pp = 0; pp < 32; pp += 8) {
      int p = p0 + pp;
      float o[8];
      conv8(cur, hp, chb + p, conv_w, conv_b, o);
      bf16x8 ob = {(bf16)o[0], (bf16)o[1], (bf16)o[2], (bf16)o[3],
                   (bf16)o[4], (bf16)o[5], (bf16)o[6], (bf16)o[7]};
      *(bf16x8*)(qrow + ((((p >> 3) ^ j) & 7) << 3)) = ob;
    }
  }

  float a0 = adtb[(long)bid * 128 + lane];
  float a1 = adtb[(long)bid * 128 + 64 + lane];
  float d0 = dtb[(long)bid * 128 + lane];
  float d1 = dtb[(long)bid * 128 + 64 + lane];
  wave_scan128(a0, a1, lane);
  if (wave == 0) {
    acs[lane] = a0; acs[64 + lane] = a1;
    dts[lane] = d0; dts[64 + lane] = d1;
  }
  __syncthreads();   // DMA drained + Q writes + scan visible

  {
    f32x4 gacc[4][4] = {};
#pragma unroll
    for (int ks = 0; ks < HD; ks += 32) {
      bf16x8 af[4], bf_[4];
#pragma unroll
      for (int mi = 0; mi < 4; ++mi)
        af[mi] = *(const bf16x8*)(Qs + swz64(wm * 64 + mi * 16 + (lane & 15), ks + (lane >> 4) * 8));
#pragma unroll
      for (int ni = 0; ni < 4; ++ni)
        bf_[ni] = *(const bf16x8*)(KVs + swz64(wn * 64 + ni * 16 + (lane & 15), ks + (lane >> 4) * 8));
#pragma unroll
      for (int mi = 0; mi < 4; ++mi)
#pragma unroll
        for (int ni = 0; ni < 4; ++ni)
          gacc[mi][ni] = __builtin_amdgcn_mfma_f32_16x16x32_bf16(af[mi], bf_[ni], gacc[mi][ni], 0, 0, 0);
    }
    float aj[4], dj[4];
#pragma unroll
    for (int ni = 0; ni < 4; ++ni) {
      int j = wn * 64 + ni * 16 + (lane & 15);
      aj[ni] = acs[j];
      dj[ni] = dts[j];
    }
#pragma unroll
    for (int mi = 0; mi < 4; ++mi) {
#pragma unroll
      for (int r = 0; r < 4; ++r) {
        int i = wm * 64 + mi * 16 + (lane >> 4) * 4 + r;
        float ai = acs[i];
#pragma unroll
        for (int ni = 0; ni < 4; ++ni) {
          int j = wn * 64 + ni * 16 + (lane & 15);
          float gv = (j <= i) ? gacc[mi][ni][r] * __expf(ai - aj[ni]) * dj[ni] : 0.f;
          G[swz128(i, j)] = (bf16)gv;
        }
      }
    }
  }
  __syncthreads();

  stage128(Vt + kvb, KVs, tid, 8192);
  __syncthreads();

  f32x4 yacc[4][2] = {};
  f32x4 oacc[4][2] = {};
#pragma unroll
  for (int ks = 0; ks < CHUNK; ks += 32) {
    bf16x8 af[4], bf_[2];
#pragma unroll
    for (int mi = 0; mi < 4; ++mi)
      af[mi] = *(const bf16x8*)(G + swz128(wm * 64 + mi * 16 + (lane & 15), ks + (lane >> 4) * 8));
#pragma unroll
    for (int ni = 0; ni < 2; ++ni)
      bf_[ni] = *(const bf16x8*)(KVs + swz128(wn * 32 + ni * 16 + (lane & 15), ks + (lane >> 4) * 8));
#pragma unroll
    for (int mi = 0; mi < 4; ++mi)
#pragma unroll
      for (int ni = 0; ni < 2; ++ni)
        yacc[mi][ni] = __builtin_amdgcn_mfma_f32_16x16x32_bf16(af[mi], bf_[ni], yacc[mi][ni], 0, 0, 0);
  }
#pragma unroll
  for (int ks = 0; ks < HD; ks += 32) {
    bf16x8 af[4], bf_[2];
#pragma unroll
    for (int mi = 0; mi < 4; ++mi)
      af[mi] = *(const bf16x8*)(Qs + swz64(wm * 64 + mi * 16 + (lane & 15), ks + (lane >> 4) * 8));
#pragma unroll
    for (int ni = 0; ni < 2; ++ni)
      bf_[ni] = *(const bf16x8*)(Sps + swz64(wn * 32 + ni * 16 + (lane & 15), ks + (lane >> 4) * 8));
#pragma unroll
    for (int mi = 0; mi < 4; ++mi)
#pragma unroll
      for (int ni = 0; ni < 2; ++ni)
        oacc[mi][ni] = __builtin_amdgcn_mfma_f32_16x16x32_bf16(af[mi], bf_[ni], oacc[mi][ni], 0, 0, 0);
  }
  __syncthreads();   // all waves done with G/KVs reads -> KVs reusable

  // early gate DMA into KVs: overlaps the combine/partials VALU below
  for (int i0 = 0; i0 < 8192; i0 += 2048) {
    int e = i0 + tid * 8;
    int row = e >> 6;
    int sc = ((tid & 7) ^ (row & 7)) << 3;
    gld_lds16((const void*)(proj + (rowbase + row) * NPADN + CONVD + h * 64 + sc),
              (void*)(KVs + e));
  }

  float yv[4][2][4];
#pragma unroll
  for (int mi = 0; mi < 4; ++mi) {
#pragma unroll
    for (int r = 0; r < 4; ++r) {
      int i = wm * 64 + mi * 16 + (lane >> 4) * 4 + r;
      float ei = __expf(acs[i]);
      float s = 0.f;
#pragma unroll
      for (int ni = 0; ni < 2; ++ni) {
        float v = yacc[mi][ni][r] + ei * oacc[mi][ni][r];
        yv[mi][ni][r] = v;
        s += v * v;
      }
      s += __shfl_xor(s, 1, 64);
      s += __shfl_xor(s, 2, 64);
      s += __shfl_xor(s, 4, 64);
      s += __shfl_xor(s, 8, 64);
      if ((lane & 15) == 0) part[i][wn] = s;
    }
  }
  __syncthreads();   // part visible + gate DMA drained

  if (tid < CHUNK) rs_l[tid] = rsqrtf((part[tid][0] + part[tid][1]) * (1.0f / HD) + EPSF);
  __syncthreads();   // rs visible

#pragma unroll
  for (int mi = 0; mi < 4; ++mi) {
#pragma unroll
    for (int r = 0; r < 4; ++r) {
      int i = wm * 64 + mi * 16 + (lane >> 4) * 4 + r;
      long row = rowbase + i;
      float rs = rs_l[i];
#pragma unroll
      for (int ni = 0; ni < 2; ++ni) {
        int p = wn * 32 + ni * 16 + (lane & 15);
        float gval = (float)KVs[swz64(i, p)];
        float val = yv[mi][ni][r] * rs * gnw[p] * fsilu(gval);
        yg[row * (long)DMODEL + h * HD + p] = (bf16)val;
      }
    }
  }
}

// ---------------- launch ----------------
extern "C" void kernel_launch(void* const* d_in, const int* in_sizes, int n_in,
                              void* d_out, int out_size, void* d_ws, size_t ws_size,
                              hipStream_t stream) {
  const float* hs      = (const float*)d_in[0];
  const float* W1      = (const float*)d_in[1];
  const float* conv_w  = (const float*)d_in[2];
  const float* conv_b  = (const float*)d_in[3];
  const float* dt_bias = (const float*)d_in[4];
  const float* A_log   = (const float*)d_in[5];
  const float* gnw     = (const float*)d_in[6];
  const float* Wo      = (const float*)d_in[7];

  char* p = (char*)d_ws;
  bf16* hs_b   = (bf16*)p;  p += (long)ROWS * DMODEL * 2;
  bf16* w1_b   = (bf16*)p;  p += (long)NPADN * DMODEL * 2;
  bf16* wo_b   = (bf16*)p;  p += (long)DMODEL * DMODEL * 2;
  bf16* proj   = (bf16*)p;  p += (long)ROWS * NPADN * 2;
  bf16* Kc     = (bf16*)p;  p += (long)256 * 8192 * 2;
  bf16* Vt     = (bf16*)p;  p += (long)256 * 8192 * 2;
  float* dtb   = (float*)p; p += (long)ROWS * NH * 4;
  float* adtb  = (float*)p; p += (long)ROWS * NH * 4;
  float* st    = (float*)p; p += (long)NB * NCHUNK * NH * HD * HD * 4;
  bf16* sprevb = (bf16*)p;  p += (long)NB * NCHUNK * NH * HD * HD * 2;
  float* asum  = (float*)p; p += (long)NB * NH * NCHUNK * 4;
  bf16* yg     = (bf16*)p;  p += (long)ROWS * DMODEL * 2;

  cast_all_kernel<<<4096, 256, 0, stream>>>(hs, W1, Wo, hs_b, w1_b, wo_b);

  gemm2p_kernel<bf16><<<(ROWS / 128) * (NPADN / 128), 256, 0, stream>>>(
      hs_b, w1_b, proj, ROWS, NPADN, DMODEL, NPADN / 128);

  fused_kvs_kernel<<<NB * NCHUNK * NKVH, 256, 0, stream>>>(
      proj, conv_w, conv_b, dt_bias, A_log, Kc, Vt, dtb, adtb, st, asum);

  ssd_scan_kernel<<<NB * NH * 8, 256, 0, stream>>>(st, asum, sprevb);
  ssd_out_kernel<<<NB * NCHUNK * NH, 256, 0, stream>>>(
      Kc, Vt, sprevb, dtb, adtb, proj, conv_w, conv_b, gnw, yg);

  gemm2p_kernel<float><<<(ROWS / 128) * (DMODEL / 128), 256, 0, stream>>>(
      yg, wo_b, (float*)d_out, ROWS, DMODEL, DMODEL, DMODEL / 128);
}